// Round 11
// baseline (299.218 us; speedup 1.0000x reference)
//
#include <hip/hip_runtime.h>
#include <math.h>

// Problem constants (fixed by setup_inputs)
constexpr int Bb  = 2;
constexpr int Nn  = 1280;
constexpr int Cc  = 1024;
constexpr int Hh  = 16;
constexpr int DH  = 64;
constexpr int Ii  = 4096;
constexpr int Tt  = 256;    // text_len
constexpr int BSz = 128;    // block_size
constexpr int L1  = 4;      // len1
constexpr int Mrows = Bb * Nn;  // 2560

typedef __attribute__((ext_vector_type(8))) short short8v;
typedef __attribute__((ext_vector_type(4))) float f32x4;

__device__ __forceinline__ int segof(int n) {
    return n < Tt ? 0 : (n < Tt + L1 * BSz ? 1 : 2);
}
__device__ __forceinline__ unsigned short f2bf(float f) {
    unsigned int u = __float_as_uint(f);
    u += 0x7fffu + ((u >> 16) & 1u);        // RNE
    return (unsigned short)(u >> 16);
}
__device__ __forceinline__ float bf2f(unsigned short h) {
    return __uint_as_float(((unsigned int)h) << 16);
}
// HW packed fp32->2xbf16 (src0 -> low half)
__device__ __forceinline__ unsigned int cvtpk(float lo, float hi) {
    unsigned int r;
    asm("v_cvt_pk_bf16_f32 %0, %1, %2" : "=v"(r) : "v"(lo), "v"(hi));
    return r;
}
__device__ __forceinline__ uint4 pk8(const float* w) {
    uint4 r;
    r.x = cvtpk(w[0], w[1]); r.y = cvtpk(w[2], w[3]);
    r.z = cvtpk(w[4], w[5]); r.w = cvtpk(w[6], w[7]);
    return r;
}

// bijective XCD swizzle for nwg % 8 == 0
__device__ __forceinline__ int xcd_swz(int lin, int nwg) {
    int cpx = nwg >> 3;
    return (lin & 7) * cpx + (lin >> 3);
}

// ---------------------------------------------------------------------------
// RMSNorm fp32 -> bf16 out: one block per row, 256 threads, C=1024
// ---------------------------------------------------------------------------
__global__ __launch_bounds__(256)
void rms_bf16(const float* __restrict__ in, const float* __restrict__ w,
              unsigned short* __restrict__ out) {
    int row = blockIdx.x;
    int n   = row % Nn;
    int seg = segof(n);
    const float* x = in + (size_t)row * Cc;
    int t = threadIdx.x;
    float4 xv = reinterpret_cast<const float4*>(x)[t];
    float ss = xv.x * xv.x + xv.y * xv.y + xv.z * xv.z + xv.w * xv.w;
#pragma unroll
    for (int off = 32; off; off >>= 1) ss += __shfl_down(ss, off, 64);
    __shared__ float red[4];
    __shared__ float s_r;
    int lane = t & 63, wid = t >> 6;
    if (lane == 0) red[wid] = ss;
    __syncthreads();
    if (t == 0) s_r = rsqrtf((red[0] + red[1] + red[2] + red[3]) * (1.0f / Cc) + 1e-6f);
    __syncthreads();
    float r = s_r;
    float4 wv = reinterpret_cast<const float4*>(w + (size_t)seg * Cc)[t];
    ushort4 ov;
    ov.x = f2bf(wv.x * xv.x * r);
    ov.y = f2bf(wv.y * xv.y * r);
    ov.z = f2bf(wv.z * xv.z * r);
    ov.w = f2bf(wv.w * xv.w * r);
    *reinterpret_cast<ushort4*>(&out[(size_t)row * Cc + t * 4]) = ov;
}

// ---------------------------------------------------------------------------
// bf16 MFMA GEMM v5: 128x128 tile, BK=32, 4 waves 2x2 (wave = 64x64, 4x4
// acc), reg-staged prefetch. B operand is read DIRECTLY from fp32 weights
// [seg][K][Nd] (8 K-strided dwords per chunk) and converted to bf16 via
// v_cvt_pk_bf16_f32 during staging — no separate pack kernel, no packed
// weight buffer. LDS fragment layout identical to the verified v4.
// OUTMODE: 0 = f32 out, 1 = bf16 out.  NZ: split-K; partial z at z*Mrows*Nd.
// ---------------------------------------------------------------------------
template <int OUTMODE, bool BIAS, int NZ>
__global__ __launch_bounds__(256, 2)
void gemm128r(const unsigned short* __restrict__ A,
              const float* __restrict__ W,
              const float* __restrict__ bias, void* __restrict__ outp,
              int K, int Nd) {
    __shared__ __align__(16) unsigned short lds[8192];   // A 8KB | B 8KB
    int bx = blockIdx.x, by = blockIdx.y, bz = (NZ > 1) ? blockIdx.z : 0;
    {
        int gx = gridDim.x, gy = gridDim.y, gz = (NZ > 1) ? gridDim.z : 1;
        int lin = bx + gx * (by + gy * bz);
        int swz = xcd_swz(lin, gx * gy * gz);
        bx = swz % gx; swz /= gx;
        by = swz % gy; bz = swz / gy;
    }
    int rb = bx * 128, cb = by;
    int seg = segof(rb % Nn);
    int tid = threadIdx.x, lane = tid & 63, wid = tid >> 6;
    int wr = wid >> 1, wc = wid & 1;
    int g = lane >> 4, c_ = lane & 15;
    const int Keff = K / NZ;
    const int nKt = Keff >> 5;
    const int kz = bz * Keff;

    // staging sources (chunks tid and tid+256); A bf16, W fp32 strided
    int mf0 = tid >> 6, lc0 = tid & 63;
    const unsigned short* pA0 =
        A + (size_t)(rb + mf0 * 16 + (lc0 & 15)) * K + kz + (lc0 >> 4) * 8;
    const unsigned short* pA1 = pA0 + (size_t)64 * K;
    const float* pW0 = W + (size_t)seg * K * Nd +
                       (size_t)(kz + (lc0 >> 4) * 8) * Nd +
                       cb * 128 + mf0 * 16 + (lc0 & 15);
    const size_t wstep = (size_t)32 * Nd;

    f32x4 acc[4][4];
#pragma unroll
    for (int m = 0; m < 4; m++)
#pragma unroll
        for (int n = 0; n < 4; n++) acc[m][n] = (f32x4){0.f, 0.f, 0.f, 0.f};

    short8v av0, av1;
    uint4 ub0, ub1;
    auto load_tile = [&]() {
        av0 = *reinterpret_cast<const short8v*>(pA0);
        av1 = *reinterpret_cast<const short8v*>(pA1);
        float w0[8], w1[8];
#pragma unroll
        for (int j = 0; j < 8; j++) {
            w0[j] = pW0[(size_t)j * Nd];
            w1[j] = pW0[(size_t)j * Nd + 64];
        }
        ub0 = pk8(w0);
        ub1 = pk8(w1);
        pA0 += 32; pA1 += 32; pW0 += wstep;
    };

    load_tile();
    for (int kt = 0; kt < nKt; ++kt) {
        __syncthreads();                        // prev iter's ds_reads done
        *reinterpret_cast<short8v*>(&lds[(size_t)tid * 8]) = av0;
        *reinterpret_cast<short8v*>(&lds[(size_t)(tid + 256) * 8]) = av1;
        *reinterpret_cast<uint4*>(&lds[4096 + (size_t)tid * 8]) = ub0;
        *reinterpret_cast<uint4*>(&lds[4096 + (size_t)(tid + 256) * 8]) = ub1;
        __syncthreads();
        if (kt + 1 < nKt) load_tile();          // prefetch under MFMA
        short8v afr[4], bfr[4];
#pragma unroll
        for (int m = 0; m < 4; m++)
            afr[m] = *reinterpret_cast<short8v*>(&lds[((wr * 4 + m) * 64 + lane) * 8]);
#pragma unroll
        for (int n = 0; n < 4; n++)
            bfr[n] = *reinterpret_cast<short8v*>(&lds[4096 + ((wc * 4 + n) * 64 + lane) * 8]);
#pragma unroll
        for (int m = 0; m < 4; m++)
#pragma unroll
            for (int n = 0; n < 4; n++)
                acc[m][n] = __builtin_amdgcn_mfma_f32_16x16x32_bf16(
                    afr[m], bfr[n], acc[m][n], 0, 0, 0);
    }

    // epilogue: C/D layout col=lane&15, row=(lane>>4)*4+r
    float* outf = (float*)outp;
    unsigned short* outh = (unsigned short*)outp;
    size_t zoff = (NZ > 1) ? (size_t)bz * Mrows * Nd : 0;
#pragma unroll
    for (int n = 0; n < 4; n++) {
        int col = cb * 128 + wc * 64 + n * 16 + c_;
        float bvv = BIAS ? bias[(size_t)seg * Nd + col] : 0.f;
#pragma unroll
        for (int m = 0; m < 4; m++) {
#pragma unroll
            for (int r = 0; r < 4; r++) {
                int row = rb + wr * 64 + m * 16 + g * 4 + r;
                float v = acc[m][n][r] + bvv;
                if (OUTMODE == 0) outf[zoff + (size_t)row * Nd + col] = v;
                else              outh[zoff + (size_t)row * Nd + col] = f2bf(v);
            }
        }
    }
}

// ---------------------------------------------------------------------------
// Fused gate+up GEMM v3: t = silu(y@gate)*(y@up), 128x128 tile, BK=32,
// dual 4x4 acc, direct fp32 weight read + cvt_pk staging. K=Cc, Nd=Ii.
// ---------------------------------------------------------------------------
__global__ __launch_bounds__(256, 2)
void gemm_gu(const unsigned short* __restrict__ A,
             const float* __restrict__ G,
             const float* __restrict__ U,
             unsigned short* __restrict__ outp) {
    __shared__ __align__(16) unsigned short lds[12288];  // A 8KB | G 8KB | U 8KB
    int bx = blockIdx.x, by = blockIdx.y;
    {
        int lin = bx + gridDim.x * by;
        int swz = xcd_swz(lin, gridDim.x * gridDim.y);
        bx = swz % gridDim.x; by = swz / gridDim.x;
    }
    int rb = bx * 128, cb = by;
    int seg = segof(rb % Nn);
    int tid = threadIdx.x, lane = tid & 63, wid = tid >> 6;
    int wr = wid >> 1, wc = wid & 1;
    int g = lane >> 4, c_ = lane & 15;

    int mf0 = tid >> 6, lc0 = tid & 63;
    const unsigned short* pA0 =
        A + (size_t)(rb + mf0 * 16 + (lc0 & 15)) * Cc + (lc0 >> 4) * 8;
    const unsigned short* pA1 = pA0 + (size_t)64 * Cc;
    size_t wofs = (size_t)seg * Cc * Ii + (size_t)((lc0 >> 4) * 8) * Ii +
                  cb * 128 + mf0 * 16 + (lc0 & 15);
    const float* pG0 = G + wofs;
    const float* pU0 = U + wofs;
    const size_t wstep = (size_t)32 * Ii;

    f32x4 accG[4][4], accU[4][4];
#pragma unroll
    for (int m = 0; m < 4; m++)
#pragma unroll
        for (int n = 0; n < 4; n++) {
            accG[m][n] = (f32x4){0.f, 0.f, 0.f, 0.f};
            accU[m][n] = (f32x4){0.f, 0.f, 0.f, 0.f};
        }

    short8v av0, av1;
    uint4 gb0, gb1, ub0, ub1;
    auto load_tile = [&]() {
        av0 = *reinterpret_cast<const short8v*>(pA0);
        av1 = *reinterpret_cast<const short8v*>(pA1);
        float g0[8], g1[8], u0[8], u1[8];
#pragma unroll
        for (int j = 0; j < 8; j++) {
            g0[j] = pG0[(size_t)j * Ii];
            g1[j] = pG0[(size_t)j * Ii + 64];
            u0[j] = pU0[(size_t)j * Ii];
            u1[j] = pU0[(size_t)j * Ii + 64];
        }
        gb0 = pk8(g0); gb1 = pk8(g1);
        ub0 = pk8(u0); ub1 = pk8(u1);
        pA0 += 32; pA1 += 32; pG0 += wstep; pU0 += wstep;
    };

    const int nKt = Cc >> 5;                    // 32
    load_tile();
    for (int kt = 0; kt < nKt; ++kt) {
        __syncthreads();
        *reinterpret_cast<short8v*>(&lds[(size_t)tid * 8]) = av0;
        *reinterpret_cast<short8v*>(&lds[(size_t)(tid + 256) * 8]) = av1;
        *reinterpret_cast<uint4*>(&lds[4096 + (size_t)tid * 8]) = gb0;
        *reinterpret_cast<uint4*>(&lds[4096 + (size_t)(tid + 256) * 8]) = gb1;
        *reinterpret_cast<uint4*>(&lds[8192 + (size_t)tid * 8]) = ub0;
        *reinterpret_cast<uint4*>(&lds[8192 + (size_t)(tid + 256) * 8]) = ub1;
        __syncthreads();
        if (kt + 1 < nKt) load_tile();
        short8v afr[4];
#pragma unroll
        for (int m = 0; m < 4; m++)
            afr[m] = *reinterpret_cast<short8v*>(&lds[((wr * 4 + m) * 64 + lane) * 8]);
        {
            short8v gfr[4];
#pragma unroll
            for (int n = 0; n < 4; n++)
                gfr[n] = *reinterpret_cast<short8v*>(&lds[4096 + ((wc * 4 + n) * 64 + lane) * 8]);
#pragma unroll
            for (int m = 0; m < 4; m++)
#pragma unroll
                for (int n = 0; n < 4; n++)
                    accG[m][n] = __builtin_amdgcn_mfma_f32_16x16x32_bf16(
                        afr[m], gfr[n], accG[m][n], 0, 0, 0);
        }
        {
            short8v ufr[4];
#pragma unroll
            for (int n = 0; n < 4; n++)
                ufr[n] = *reinterpret_cast<short8v*>(&lds[8192 + ((wc * 4 + n) * 64 + lane) * 8]);
#pragma unroll
            for (int m = 0; m < 4; m++)
#pragma unroll
                for (int n = 0; n < 4; n++)
                    accU[m][n] = __builtin_amdgcn_mfma_f32_16x16x32_bf16(
                        afr[m], ufr[n], accU[m][n], 0, 0, 0);
        }
    }

    // epilogue: t = silu(g) * u
#pragma unroll
    for (int n = 0; n < 4; n++) {
        int col = cb * 128 + wc * 64 + n * 16 + c_;
#pragma unroll
        for (int m = 0; m < 4; m++) {
#pragma unroll
            for (int r = 0; r < 4; r++) {
                int row = rb + wr * 64 + m * 16 + g * 4 + r;
                float gval = accG[m][n][r], uval = accU[m][n][r];
                float t = gval / (1.f + __expf(-gval)) * uval;
                outp[(size_t)row * Ii + col] = f2bf(t);
            }
        }
    }
}

// ---------------------------------------------------------------------------
// proj combine: h(out) = x + bias[seg] + p0 + p1   (fp32 partials)
// ---------------------------------------------------------------------------
__global__ __launch_bounds__(256)
void combine_proj(const float* __restrict__ x, const float* __restrict__ bias,
                  const float* __restrict__ p, float* __restrict__ hb) {
    int i = blockIdx.x * 256 + threadIdx.x;     // float4 index
    int base = i * 4;
    int col = base % Cc;
    int n   = (base / Cc) % Nn;
    int seg = segof(n);
    float4 a = reinterpret_cast<const float4*>(x)[i];
    float4 b = *reinterpret_cast<const float4*>(&bias[(size_t)seg * Cc + col]);
    float4 p0 = reinterpret_cast<const float4*>(p)[i];
    float4 p1 = reinterpret_cast<const float4*>(p)[i + Mrows * Cc / 4];
    float4 r;
    r.x = a.x + b.x + p0.x + p1.x;
    r.y = a.y + b.y + p0.y + p1.y;
    r.z = a.z + b.z + p0.z + p1.z;
    r.w = a.w + b.w + p0.w + p1.w;
    reinterpret_cast<float4*>(hb)[i] = r;
}

// ---------------------------------------------------------------------------
// down combine: out = h(out) + sum_z bf2f(p_z)    (bf16 partials, NZ=4)
// ---------------------------------------------------------------------------
__global__ __launch_bounds__(256)
void combine_down4(const unsigned short* __restrict__ p,
                   float* __restrict__ out) {
    int i = blockIdx.x * 256 + threadIdx.x;     // 4-elem group
    float4 a = reinterpret_cast<const float4*>(out)[i];
#pragma unroll
    for (int z = 0; z < 4; z++) {
        ushort4 u = *reinterpret_cast<const ushort4*>(&p[(size_t)z * Mrows * Cc + i * 4]);
        a.x += bf2f(u.x); a.y += bf2f(u.y); a.z += bf2f(u.z); a.w += bf2f(u.w);
    }
    reinterpret_cast<float4*>(out)[i] = a;
}

// ---------------------------------------------------------------------------
// Split qkv(bf16) + per-head q/k RMSNorm + RoPE -> bf16 Q,K,V (bh, n, dh)
// ---------------------------------------------------------------------------
__global__ __launch_bounds__(256)
void split_rope(const unsigned short* __restrict__ qkv,
                const float* __restrict__ qn_w, const float* __restrict__ kn_w,
                const int* __restrict__ pos_ids, const int* __restrict__ tpos_ids,
                unsigned short* __restrict__ Q, unsigned short* __restrict__ K,
                unsigned short* __restrict__ V) {
    int row = blockIdx.x;   // b*N + n
    int b = row / Nn, n = row % Nn;
    int seg = segof(n);
    int lane = threadIdx.x & 63, wid = threadIdx.x >> 6;
    int pos = (n < Tt) ? tpos_ids[n] : pos_ids[n - Tt];
    int j = lane & 31;
    float ang = (float)pos * exp2f(-(float)j * (13.287712379549449f / 32.f));
    float cv = cosf(ang), sv = sinf(ang);
    float qw = qn_w[seg * DH + lane], kw = kn_w[seg * DH + lane];
    for (int h = wid; h < Hh; h += 4) {
        const unsigned short* base = qkv + (size_t)row * (3 * Cc) + h * DH + lane;
        float q = bf2f(base[0]), k = bf2f(base[Cc]), v = bf2f(base[2 * Cc]);
        float qs = q * q, ks = k * k;
#pragma unroll
        for (int off = 32; off; off >>= 1) {
            qs += __shfl_xor(qs, off, 64);
            ks += __shfl_xor(ks, off, 64);
        }
        q = q * rsqrtf(qs * (1.f / DH) + 1e-6f) * qw;
        k = k * rsqrtf(ks * (1.f / DH) + 1e-6f) * kw;
        float qp = __shfl_xor(q, 32, 64);
        float kp = __shfl_xor(k, 32, 64);
        float qo = q * cv + ((lane < 32) ? -qp * sv : qp * sv);
        float ko = k * cv + ((lane < 32) ? -kp * sv : kp * sv);
        size_t oidx = ((size_t)(b * Hh + h) * Nn + n) * DH + lane;
        Q[oidx] = f2bf(qo);
        K[oidx] = f2bf(ko);
        V[oidx] = f2bf(v);
    }
}

// ---------------------------------------------------------------------------
// MFMA flash attention (unchanged — verified)
// ---------------------------------------------------------------------------
__global__ __launch_bounds__(256)
void attn_mfma(const unsigned short* __restrict__ Qg,
               const unsigned short* __restrict__ Kg,
               const unsigned short* __restrict__ Vg,
               unsigned short* __restrict__ O) {
    __shared__ __align__(16) unsigned short k_lds[64 * 64];   // 8 KB
    __shared__ __align__(16) unsigned short vt_lds[64 * 64];  // 8 KB
    __shared__ __align__(16) unsigned short p_lds[4][16 * 64];// 8 KB

    int qt = blockIdx.x;
    int bh = blockIdx.y;
    int b = bh >> 4, h = bh & 15;
    int tid = threadIdx.x, lane = tid & 63, wid = tid >> 6;
    int g = lane >> 4, c = lane & 15;

    const size_t headoff = (size_t)bh * Nn * DH;
    int q0 = qt * 64;
    bool qtext = q0 < Tt;
    int qb = qtext ? 0 : (q0 - Tt) / BSz;

    int qrow_frag = q0 + wid * 16 + c;
    short8v aq[2];
#pragma unroll
    for (int kb = 0; kb < 2; kb++)
        aq[kb] = *reinterpret_cast<const short8v*>(
            &Qg[headoff + (size_t)qrow_frag * DH + kb * 32 + g * 8]);

    unsigned short* pbuf = &p_lds[wid][0];

    f32x4 o_[4];
#pragma unroll
    for (int nb = 0; nb < 4; nb++) o_[nb] = (f32x4){0.f, 0.f, 0.f, 0.f};
    float m_[4] = {-3.4e38f, -3.4e38f, -3.4e38f, -3.4e38f};
    float l_[4] = {0.f, 0.f, 0.f, 0.f};

    int tr = tid >> 2, tc = tid & 3;

    for (int kt = 0; kt < Nn / 64; kt++) {
        int kbase = kt * 64;
        bool vis, diag = false;
        if (qtext) {
            vis = (kbase <= q0);
            diag = (kbase == q0);
        } else if (kbase < Tt) {
            vis = true;
        } else {
            int kb = (kbase - Tt) / BSz;
            vis = (qb < L1) ? (kb <= qb)
                            : ((kb < L1 && qb - L1 > kb) || kb == qb);
        }
        if (!vis) continue;

        __syncthreads();
        {
            const unsigned short* ks = &Kg[headoff + (size_t)(kbase + tr) * DH];
            const unsigned short* vs = &Vg[headoff + (size_t)(kbase + tr) * DH];
#pragma unroll
            for (int i = 0; i < 2; i++) {
                int ch = tc + i * 4;
                short8v kv = *reinterpret_cast<const short8v*>(ks + ch * 8);
                int byte = (tr * 128 + ch * 16) ^ ((tr & 7) << 4);
                *reinterpret_cast<short8v*>((char*)k_lds + byte) = kv;
                short8v vv = *reinterpret_cast<const short8v*>(vs + ch * 8);
#pragma unroll
                for (int j = 0; j < 8; j++) {
                    int dh = ch * 8 + j;
                    int vbyte = (dh * 128 + tr * 2) ^ ((dh & 7) << 4);
                    *reinterpret_cast<unsigned short*>((char*)vt_lds + vbyte) =
                        (unsigned short)vv[j];
                }
            }
        }
        __syncthreads();

        f32x4 s_[4];
#pragma unroll
        for (int nb = 0; nb < 4; nb++) s_[nb] = (f32x4){0.f, 0.f, 0.f, 0.f};
#pragma unroll
        for (int nb = 0; nb < 4; nb++) {
            int kil = nb * 16 + c;
#pragma unroll
            for (int kb = 0; kb < 2; kb++) {
                int byte = (kil * 128 + kb * 64 + g * 16) ^ ((kil & 7) << 4);
                short8v bk = *reinterpret_cast<short8v*>((char*)k_lds + byte);
                s_[nb] = __builtin_amdgcn_mfma_f32_16x16x32_bf16(aq[kb], bk, s_[nb], 0, 0, 0);
            }
        }
#pragma unroll
        for (int nb = 0; nb < 4; nb++) {
#pragma unroll
            for (int r = 0; r < 4; r++) {
                float sv = s_[nb][r] * 0.125f;
                if (diag) {
                    int qrl = wid * 16 + g * 4 + r;
                    int kcl = nb * 16 + c;
                    if (qrl < kcl) sv = -3.4e38f;
                }
                s_[nb][r] = sv;
            }
        }
#pragma unroll
        for (int r = 0; r < 4; r++) {
            float mx = fmaxf(fmaxf(s_[0][r], s_[1][r]), fmaxf(s_[2][r], s_[3][r]));
#pragma unroll
            for (int off = 1; off <= 8; off <<= 1)
                mx = fmaxf(mx, __shfl_xor(mx, off, 64));
            float mn = fmaxf(m_[r], mx);
            float es = __expf(m_[r] - mn);
            m_[r] = mn;
            float pv[4];
            float rs = 0.f;
#pragma unroll
            for (int nb = 0; nb < 4; nb++) {
                pv[nb] = __expf(s_[nb][r] - mn);
                rs += pv[nb];
            }
#pragma unroll
            for (int off = 1; off <= 8; off <<= 1)
                rs += __shfl_xor(rs, off, 64);
            l_[r] = l_[r] * es + rs;
#pragma unroll
            for (int nb = 0; nb < 4; nb++) o_[nb][r] *= es;
            int qrl = g * 4 + r;
            int swz = (qrl & 7) << 4;
#pragma unroll
            for (int nb = 0; nb < 4; nb++) {
                int byte = (qrl * 128 + (nb * 16 + c) * 2) ^ swz;
                *reinterpret_cast<unsigned short*>((char*)pbuf + byte) = f2bf(pv[nb]);
            }
        }
        short8v aP[2];
#pragma unroll
        for (int kb = 0; kb < 2; kb++) {
            int byte = (c * 128 + kb * 64 + g * 16) ^ ((c & 7) << 4);
            aP[kb] = *reinterpret_cast<short8v*>((char*)pbuf + byte);
        }
#pragma unroll
        for (int nb = 0; nb < 4; nb++) {
            int dh = nb * 16 + c;
#pragma unroll
            for (int kb = 0; kb < 2; kb++) {
                int byte = (dh * 128 + kb * 64 + g * 16) ^ ((dh & 7) << 4);
                short8v bv = *reinterpret_cast<short8v*>((char*)vt_lds + byte);
                o_[nb] = __builtin_amdgcn_mfma_f32_16x16x32_bf16(aP[kb], bv, o_[nb], 0, 0, 0);
            }
        }
    }

    float inv_[4];
#pragma unroll
    for (int r = 0; r < 4; r++) inv_[r] = 1.f / l_[r];
#pragma unroll
    for (int nb = 0; nb < 4; nb++) {
        int col = h * DH + nb * 16 + c;
#pragma unroll
        for (int r = 0; r < 4; r++) {
            int row = q0 + wid * 16 + g * 4 + r;
            O[((size_t)b * Nn + row) * Cc + col] = f2bf(o_[nb][r] * inv_[r]);
        }
    }
}

// ---------------------------------------------------------------------------
// kernel_launch
// ---------------------------------------------------------------------------
extern "C" void kernel_launch(void* const* d_in, const int* in_sizes, int n_in,
                              void* d_out, int out_size, void* d_ws, size_t ws_size,
                              hipStream_t stream) {
    const float* x        = (const float*)d_in[0];
    const int*   pos_ids  = (const int*)d_in[1];
    const int*   tpos_ids = (const int*)d_in[2];
    const float* qkv_w    = (const float*)d_in[3];
    const float* qkv_b    = (const float*)d_in[4];
    const float* proj_w   = (const float*)d_in[5];
    const float* proj_b   = (const float*)d_in[6];
    const float* qn_w     = (const float*)d_in[7];
    const float* kn_w     = (const float*)d_in[8];
    const float* ln1_w    = (const float*)d_in[9];
    const float* ln2_w    = (const float*)d_in[10];
    const float* gate_w   = (const float*)d_in[11];
    const float* up_w     = (const float*)d_in[12];
    const float* down_w   = (const float*)d_in[13];
    float* out = (float*)d_out;                 // also used as h buffer
    char*  wsb = (char*)d_ws;

    // workspace (bytes), peak 78.6 MB — no packed-weight buffers anymore
    unsigned short* P3   = (unsigned short*)(wsb);               //  5.24 MB xn/o/y
    unsigned short* qkvb = (unsigned short*)(wsb + 5242880);     // 15.73 MB
    unsigned short* Qbf  = (unsigned short*)(wsb + 20971520);    // 15.73 MB Q,K,V
    unsigned short* Kbf  = Qbf + 2621440;
    unsigned short* Vbf  = Qbf + 5242880;
    float*          Pp   = (float*)(wsb + 36700160);             // 20.97 MB proj partials
    unsigned short* Tb   = (unsigned short*)(wsb + 36700160);    // 20.97 MB t (aliases Pp)
    unsigned short* Dp   = (unsigned short*)(wsb + 57671680);    // 20.97 MB down partials

    // 1. xn = RMS(x, ln1) -> bf16 (P3)
    rms_bf16<<<Mrows, 256, 0, stream>>>(x, ln1_w, P3);
    // 2. qkv = xn @ qkv_w + qkv_b -> bf16 (direct fp32 weight read)
    gemm128r<1, true, 1><<<dim3(Mrows / 128, 24), 256, 0, stream>>>(
        P3, qkv_w, qkv_b, qkvb, Cc, 3 * Cc);
    // 3. split + q/k RMS + RoPE -> Q,K,V
    split_rope<<<Mrows, 256, 0, stream>>>(qkvb, qn_w, kn_w, pos_ids, tpos_ids,
                                          Qbf, Kbf, Vbf);
    // 4. attention -> obf (P3)
    attn_mfma<<<dim3(Nn / 64, Bb * Hh), 256, 0, stream>>>(Qbf, Kbf, Vbf, P3);
    // 5. proj split-K=2 -> fp32 partials (Pp); combine -> h in out
    gemm128r<0, false, 2><<<dim3(Mrows / 128, 8, 2), 256, 0, stream>>>(
        P3, proj_w, nullptr, Pp, Cc, Cc);
    combine_proj<<<Mrows * Cc / 1024, 256, 0, stream>>>(x, proj_b, Pp, out);
    // 6. y = RMS(h, ln2) -> bf16 (P3)
    rms_bf16<<<Mrows, 256, 0, stream>>>(out, ln2_w, P3);
    // 7. fused: t = silu(y@gate) * (y@up) -> Tb
    gemm_gu<<<dim3(Mrows / 128, 32), 256, 0, stream>>>(P3, gate_w, up_w, Tb);
    // 8. down split-K=4 -> bf16 partials (Dp); out = h + sum(p_z)
    gemm128r<1, false, 4><<<dim3(Mrows / 128, 8, 4), 256, 0, stream>>>(
        Tb, down_w, nullptr, Dp, Ii, Cc);
    combine_down4<<<Mrows * Cc / 1024, 256, 0, stream>>>(Dp, out);
}

// Round 12
// 249.009 us; speedup vs baseline: 1.2016x; 1.2016x over previous
//
#include <hip/hip_runtime.h>
#include <math.h>

// Problem constants (fixed by setup_inputs)
constexpr int Bb  = 2;
constexpr int Nn  = 1280;
constexpr int Cc  = 1024;
constexpr int Hh  = 16;
constexpr int DH  = 64;
constexpr int Ii  = 4096;
constexpr int Tt  = 256;    // text_len
constexpr int BSz = 128;    // block_size
constexpr int L1  = 4;      // len1
constexpr int Mrows = Bb * Nn;  // 2560

typedef __attribute__((ext_vector_type(8))) short short8v;
typedef __attribute__((ext_vector_type(4))) float f32x4;

__device__ __forceinline__ int segof(int n) {
    return n < Tt ? 0 : (n < Tt + L1 * BSz ? 1 : 2);
}
__device__ __forceinline__ unsigned short f2bf(float f) {
    unsigned int u = __float_as_uint(f);
    u += 0x7fffu + ((u >> 16) & 1u);        // RNE
    return (unsigned short)(u >> 16);
}
__device__ __forceinline__ float bf2f(unsigned short h) {
    return __uint_as_float(((unsigned int)h) << 16);
}

// bijective XCD swizzle for nwg % 8 == 0
__device__ __forceinline__ int xcd_swz(int lin, int nwg) {
    int cpx = nwg >> 3;
    return (lin & 7) * cpx + (lin >> 3);
}

// ---------------------------------------------------------------------------
// device bodies: RMSNorm and weight-pack (used by fat kernels + standalone)
// ---------------------------------------------------------------------------
__device__ __forceinline__ void rms_dev(const float* __restrict__ in,
                                        const float* __restrict__ w,
                                        unsigned short* __restrict__ out,
                                        int row, float* sred) {
    int n   = row % Nn;
    int seg = segof(n);
    const float* x = in + (size_t)row * Cc;
    int t = threadIdx.x;
    float4 xv = reinterpret_cast<const float4*>(x)[t];
    float ss = xv.x * xv.x + xv.y * xv.y + xv.z * xv.z + xv.w * xv.w;
#pragma unroll
    for (int off = 32; off; off >>= 1) ss += __shfl_down(ss, off, 64);
    int lane = t & 63, wid = t >> 6;
    if (lane == 0) sred[wid] = ss;
    __syncthreads();
    if (t == 0) sred[4] = rsqrtf((sred[0] + sred[1] + sred[2] + sred[3]) * (1.0f / Cc) + 1e-6f);
    __syncthreads();
    float r = sred[4];
    float4 wv = reinterpret_cast<const float4*>(w + (size_t)seg * Cc)[t];
    ushort4 ov;
    ov.x = f2bf(wv.x * xv.x * r);
    ov.y = f2bf(wv.y * xv.y * r);
    ov.z = f2bf(wv.z * xv.z * r);
    ov.w = f2bf(wv.w * xv.w * r);
    *reinterpret_cast<ushort4*>(&out[(size_t)row * Cc + t * 4]) = ov;
}

// pack fp32 [3][K][Nd] -> fragment-linear bf16 chunks; one chunk per thread
__device__ __forceinline__ void pack_dev(const float* __restrict__ W,
                                         unsigned short* __restrict__ PB,
                                         int K, int Nd, size_t idx) {
    size_t cpseg = (size_t)K * Nd / 8;
    int s = (int)(idx / cpseg);
    size_t rm = idx % cpseg;
    int lane = (int)(rm & 63);
    int fr   = (int)((rm >> 6) & 7);
    size_t tile = rm >> 9;                  // kt32*(Nd/128)+cb
    int nct = Nd >> 7;
    int cb = (int)(tile % nct);
    int kt = (int)(tile / nct);
    int col = cb * 128 + fr * 16 + (lane & 15);
    int k0  = kt * 32 + (lane >> 4) * 8;
    const float* src = W + ((size_t)s * K + k0) * Nd + col;
    unsigned short o[8];
#pragma unroll
    for (int j = 0; j < 8; j++) o[j] = f2bf(src[(size_t)j * Nd]);
    short8v v;
#pragma unroll
    for (int j = 0; j < 8; j++) v[j] = (short)o[j];
    *reinterpret_cast<short8v*>(&PB[idx * 8]) = v;
}

// ---------------------------------------------------------------------------
// standalone kernels built on the bodies
// ---------------------------------------------------------------------------
__global__ __launch_bounds__(256)
void rms_bf16(const float* __restrict__ in, const float* __restrict__ w,
              unsigned short* __restrict__ out) {
    __shared__ float sred[5];
    rms_dev(in, w, out, blockIdx.x, sred);
}

__global__ __launch_bounds__(256)
void pack_w(const float* __restrict__ W, unsigned short* __restrict__ PB,
            int K, int Nd) {
    pack_dev(W, PB, K, Nd, (size_t)blockIdx.x * 256 + threadIdx.x);
}

// fat1: rms1 (blocks [0, Mrows)) + pack_qkv (rest)
__global__ __launch_bounds__(256)
void fat1(const float* __restrict__ x, const float* __restrict__ ln1_w,
          unsigned short* __restrict__ xn,
          const float* __restrict__ qkv_w, unsigned short* __restrict__ qkv_p) {
    __shared__ float sred[5];
    int bid = blockIdx.x;
    if (bid < Mrows) {
        rms_dev(x, ln1_w, xn, bid, sred);
    } else {
        pack_dev(qkv_w, qkv_p, Cc, 3 * Cc, (size_t)(bid - Mrows) * 256 + threadIdx.x);
    }
}

// ---------------------------------------------------------------------------
// MFMA flash attention body (verified round 5-10 structure)
// ---------------------------------------------------------------------------
__device__ __forceinline__ void attn_dev(
        const unsigned short* __restrict__ Qg, const unsigned short* __restrict__ Kg,
        const unsigned short* __restrict__ Vg, unsigned short* __restrict__ O,
        int qt, int bh,
        unsigned short* k_lds, unsigned short* vt_lds, unsigned short* p_base) {
    int b = bh >> 4, h = bh & 15;
    int tid = threadIdx.x, lane = tid & 63, wid = tid >> 6;
    int g = lane >> 4, c = lane & 15;

    const size_t headoff = (size_t)bh * Nn * DH;
    int q0 = qt * 64;
    bool qtext = q0 < Tt;
    int qb = qtext ? 0 : (q0 - Tt) / BSz;

    int qrow_frag = q0 + wid * 16 + c;
    short8v aq[2];
#pragma unroll
    for (int kb = 0; kb < 2; kb++)
        aq[kb] = *reinterpret_cast<const short8v*>(
            &Qg[headoff + (size_t)qrow_frag * DH + kb * 32 + g * 8]);

    unsigned short* pbuf = p_base + wid * 1024;

    f32x4 o_[4];
#pragma unroll
    for (int nb = 0; nb < 4; nb++) o_[nb] = (f32x4){0.f, 0.f, 0.f, 0.f};
    float m_[4] = {-3.4e38f, -3.4e38f, -3.4e38f, -3.4e38f};
    float l_[4] = {0.f, 0.f, 0.f, 0.f};

    int tr = tid >> 2, tc = tid & 3;

    for (int kt = 0; kt < Nn / 64; kt++) {
        int kbase = kt * 64;
        bool vis, diag = false;
        if (qtext) {
            vis = (kbase <= q0);
            diag = (kbase == q0);
        } else if (kbase < Tt) {
            vis = true;
        } else {
            int kb = (kbase - Tt) / BSz;
            vis = (qb < L1) ? (kb <= qb)
                            : ((kb < L1 && qb - L1 > kb) || kb == qb);
        }
        if (!vis) continue;

        __syncthreads();
        {
            const unsigned short* ks = &Kg[headoff + (size_t)(kbase + tr) * DH];
            const unsigned short* vs = &Vg[headoff + (size_t)(kbase + tr) * DH];
#pragma unroll
            for (int i = 0; i < 2; i++) {
                int ch = tc + i * 4;
                short8v kv = *reinterpret_cast<const short8v*>(ks + ch * 8);
                int byte = (tr * 128 + ch * 16) ^ ((tr & 7) << 4);
                *reinterpret_cast<short8v*>((char*)k_lds + byte) = kv;
                short8v vv = *reinterpret_cast<const short8v*>(vs + ch * 8);
#pragma unroll
                for (int j = 0; j < 8; j++) {
                    int dh = ch * 8 + j;
                    int vbyte = (dh * 128 + tr * 2) ^ ((dh & 7) << 4);
                    *reinterpret_cast<unsigned short*>((char*)vt_lds + vbyte) =
                        (unsigned short)vv[j];
                }
            }
        }
        __syncthreads();

        f32x4 s_[4];
#pragma unroll
        for (int nb = 0; nb < 4; nb++) s_[nb] = (f32x4){0.f, 0.f, 0.f, 0.f};
#pragma unroll
        for (int nb = 0; nb < 4; nb++) {
            int kil = nb * 16 + c;
#pragma unroll
            for (int kb = 0; kb < 2; kb++) {
                int byte = (kil * 128 + kb * 64 + g * 16) ^ ((kil & 7) << 4);
                short8v bk = *reinterpret_cast<short8v*>((char*)k_lds + byte);
                s_[nb] = __builtin_amdgcn_mfma_f32_16x16x32_bf16(aq[kb], bk, s_[nb], 0, 0, 0);
            }
        }
#pragma unroll
        for (int nb = 0; nb < 4; nb++) {
#pragma unroll
            for (int r = 0; r < 4; r++) {
                float sv = s_[nb][r] * 0.125f;
                if (diag) {
                    int qrl = wid * 16 + g * 4 + r;
                    int kcl = nb * 16 + c;
                    if (qrl < kcl) sv = -3.4e38f;
                }
                s_[nb][r] = sv;
            }
        }
#pragma unroll
        for (int r = 0; r < 4; r++) {
            float mx = fmaxf(fmaxf(s_[0][r], s_[1][r]), fmaxf(s_[2][r], s_[3][r]));
#pragma unroll
            for (int off = 1; off <= 8; off <<= 1)
                mx = fmaxf(mx, __shfl_xor(mx, off, 64));
            float mn = fmaxf(m_[r], mx);
            float es = __expf(m_[r] - mn);
            m_[r] = mn;
            float pv[4];
            float rs = 0.f;
#pragma unroll
            for (int nb = 0; nb < 4; nb++) {
                pv[nb] = __expf(s_[nb][r] - mn);
                rs += pv[nb];
            }
#pragma unroll
            for (int off = 1; off <= 8; off <<= 1)
                rs += __shfl_xor(rs, off, 64);
            l_[r] = l_[r] * es + rs;
#pragma unroll
            for (int nb = 0; nb < 4; nb++) o_[nb][r] *= es;
            int qrl = g * 4 + r;
            int swz = (qrl & 7) << 4;
#pragma unroll
            for (int nb = 0; nb < 4; nb++) {
                int byte = (qrl * 128 + (nb * 16 + c) * 2) ^ swz;
                *reinterpret_cast<unsigned short*>((char*)pbuf + byte) = f2bf(pv[nb]);
            }
        }
        short8v aP[2];
#pragma unroll
        for (int kb = 0; kb < 2; kb++) {
            int byte = (c * 128 + kb * 64 + g * 16) ^ ((c & 7) << 4);
            aP[kb] = *reinterpret_cast<short8v*>((char*)pbuf + byte);
        }
#pragma unroll
        for (int nb = 0; nb < 4; nb++) {
            int dh = nb * 16 + c;
#pragma unroll
            for (int kb = 0; kb < 2; kb++) {
                int byte = (dh * 128 + kb * 64 + g * 16) ^ ((dh & 7) << 4);
                short8v bv = *reinterpret_cast<short8v*>((char*)vt_lds + byte);
                o_[nb] = __builtin_amdgcn_mfma_f32_16x16x32_bf16(aP[kb], bv, o_[nb], 0, 0, 0);
            }
        }
    }

    float inv_[4];
#pragma unroll
    for (int r = 0; r < 4; r++) inv_[r] = 1.f / l_[r];
#pragma unroll
    for (int nb = 0; nb < 4; nb++) {
        int col = h * DH + nb * 16 + c;
#pragma unroll
        for (int r = 0; r < 4; r++) {
            int row = q0 + wid * 16 + g * 4 + r;
            O[((size_t)b * Nn + row) * Cc + col] = f2bf(o_[nb][r] * inv_[r]);
        }
    }
}

// fat2: attn (blocks [0,640)) + pack_proj (1536) + pack_gate (6144) + pack_up (6144)
__global__ __launch_bounds__(256)
void fat2(const unsigned short* __restrict__ Qg, const unsigned short* __restrict__ Kg,
          const unsigned short* __restrict__ Vg, unsigned short* __restrict__ O,
          const float* __restrict__ proj_w, unsigned short* __restrict__ proj_p,
          const float* __restrict__ gate_w, unsigned short* __restrict__ gate_p,
          const float* __restrict__ up_w,   unsigned short* __restrict__ up_p) {
    __shared__ __align__(16) unsigned short k_lds[64 * 64];
    __shared__ __align__(16) unsigned short vt_lds[64 * 64];
    __shared__ __align__(16) unsigned short p_lds[4 * 16 * 64];
    int bid = blockIdx.x;
    if (bid < 640) {
        attn_dev(Qg, Kg, Vg, O, bid % 20, bid / 20, k_lds, vt_lds, p_lds);
        return;
    }
    bid -= 640;
    if (bid < 1536) {
        pack_dev(proj_w, proj_p, Cc, Cc, (size_t)bid * 256 + threadIdx.x);
        return;
    }
    bid -= 1536;
    if (bid < 6144) {
        pack_dev(gate_w, gate_p, Cc, Ii, (size_t)bid * 256 + threadIdx.x);
        return;
    }
    bid -= 6144;
    pack_dev(up_w, up_p, Cc, Ii, (size_t)bid * 256 + threadIdx.x);
}

// ---------------------------------------------------------------------------
// bf16 MFMA GEMM (round-10 verified): 128x128 tile, BK=32, 4 waves 2x2
// (wave = 64x64, 4x4 acc), packed-B, pointer-bumped reg-staged prefetch.
// OUTMODE: 0 = f32 out, 1 = bf16 out.  NZ: split-K; partial z at z*Mrows*Nd.
// ---------------------------------------------------------------------------
template <int OUTMODE, bool BIAS, int NZ>
__global__ __launch_bounds__(256, 2)
void gemm128r(const unsigned short* __restrict__ A,
              const unsigned short* __restrict__ PB,
              const float* __restrict__ bias, void* __restrict__ outp,
              int K, int Nd) {
    __shared__ __align__(16) unsigned short lds[8192];   // A 8KB | B 8KB
    int bx = blockIdx.x, by = blockIdx.y, bz = (NZ > 1) ? blockIdx.z : 0;
    {
        int gx = gridDim.x, gy = gridDim.y, gz = (NZ > 1) ? gridDim.z : 1;
        int lin = bx + gx * (by + gy * bz);
        int swz = xcd_swz(lin, gx * gy * gz);
        bx = swz % gx; swz /= gx;
        by = swz % gy; bz = swz / gy;
    }
    int rb = bx * 128, cb = by;
    int seg = segof(rb % Nn);
    int tid = threadIdx.x, lane = tid & 63, wid = tid >> 6;
    int wr = wid >> 1, wc = wid & 1;
    int g = lane >> 4, c_ = lane & 15;
    const int nct = Nd >> 7;
    const int Keff = K / NZ;
    const int nKt = Keff >> 5;
    const int kz = bz * Keff;
    const unsigned short* PBseg = PB + (size_t)seg * K * Nd;

    int mf0 = tid >> 6, lc0 = tid & 63;
    const unsigned short* pA0 =
        A + (size_t)(rb + mf0 * 16 + (lc0 & 15)) * K + kz + (lc0 >> 4) * 8;
    const unsigned short* pA1 = pA0 + (size_t)64 * K;
    const unsigned short* pB0 =
        PBseg + (((size_t)(kz >> 5) * nct + cb) * 8 + mf0) * 512 + (size_t)lc0 * 8;
    const unsigned short* pB1 = pB0 + 2048;
    const size_t bstep = (size_t)nct * 4096;   // shorts per K-step

    f32x4 acc[4][4];
#pragma unroll
    for (int m = 0; m < 4; m++)
#pragma unroll
        for (int n = 0; n < 4; n++) acc[m][n] = (f32x4){0.f, 0.f, 0.f, 0.f};

    short8v av[2], bv[2];
    av[0] = *reinterpret_cast<const short8v*>(pA0);
    av[1] = *reinterpret_cast<const short8v*>(pA1);
    bv[0] = *reinterpret_cast<const short8v*>(pB0);
    bv[1] = *reinterpret_cast<const short8v*>(pB1);
    pA0 += 32; pA1 += 32; pB0 += bstep; pB1 += bstep;

    for (int kt = 0; kt < nKt; ++kt) {
        __syncthreads();                        // prev iter's ds_reads done
        *reinterpret_cast<short8v*>(&lds[(size_t)tid * 8]) = av[0];
        *reinterpret_cast<short8v*>(&lds[(size_t)(tid + 256) * 8]) = av[1];
        *reinterpret_cast<short8v*>(&lds[4096 + (size_t)tid * 8]) = bv[0];
        *reinterpret_cast<short8v*>(&lds[4096 + (size_t)(tid + 256) * 8]) = bv[1];
        __syncthreads();
        if (kt + 1 < nKt) {                     // prefetch under MFMA
            av[0] = *reinterpret_cast<const short8v*>(pA0);
            av[1] = *reinterpret_cast<const short8v*>(pA1);
            bv[0] = *reinterpret_cast<const short8v*>(pB0);
            bv[1] = *reinterpret_cast<const short8v*>(pB1);
            pA0 += 32; pA1 += 32; pB0 += bstep; pB1 += bstep;
        }
        short8v afr[4], bfr[4];
#pragma unroll
        for (int m = 0; m < 4; m++)
            afr[m] = *reinterpret_cast<short8v*>(&lds[((wr * 4 + m) * 64 + lane) * 8]);
#pragma unroll
        for (int n = 0; n < 4; n++)
            bfr[n] = *reinterpret_cast<short8v*>(&lds[4096 + ((wc * 4 + n) * 64 + lane) * 8]);
#pragma unroll
        for (int m = 0; m < 4; m++)
#pragma unroll
            for (int n = 0; n < 4; n++)
                acc[m][n] = __builtin_amdgcn_mfma_f32_16x16x32_bf16(
                    afr[m], bfr[n], acc[m][n], 0, 0, 0);
    }

    float* outf = (float*)outp;
    unsigned short* outh = (unsigned short*)outp;
    size_t zoff = (NZ > 1) ? (size_t)bz * Mrows * Nd : 0;
#pragma unroll
    for (int n = 0; n < 4; n++) {
        int col = cb * 128 + wc * 64 + n * 16 + c_;
        float bvv = BIAS ? bias[(size_t)seg * Nd + col] : 0.f;
#pragma unroll
        for (int m = 0; m < 4; m++) {
#pragma unroll
            for (int r = 0; r < 4; r++) {
                int row = rb + wr * 64 + m * 16 + g * 4 + r;
                float v = acc[m][n][r] + bvv;
                if (OUTMODE == 0) outf[zoff + (size_t)row * Nd + col] = v;
                else              outh[zoff + (size_t)row * Nd + col] = f2bf(v);
            }
        }
    }
}

// ---------------------------------------------------------------------------
// Fused gate+up GEMM (round-9 verified, 66.6us): 64x128 tile, BK=32,
// 4 waves 2x2 (wave = 32x64), reg-staged prefetch. K=Cc, Nd=Ii.
// ---------------------------------------------------------------------------
__global__ __launch_bounds__(256)
void gemm_gu(const unsigned short* __restrict__ A,
             const unsigned short* __restrict__ PG,
             const unsigned short* __restrict__ PU,
             unsigned short* __restrict__ outp) {
    __shared__ __align__(16) unsigned short lds[10240];  // A 4KB | G 8KB | U 8KB
    int bx = blockIdx.x, by = blockIdx.y;
    {
        int lin = bx + gridDim.x * by;
        int swz = xcd_swz(lin, gridDim.x * gridDim.y);
        bx = swz % gridDim.x; by = swz / gridDim.x;
    }
    int rb = bx * 64, cb = by;
    int seg = segof(rb % Nn);
    int tid = threadIdx.x, lane = tid & 63, wid = tid >> 6;
    int wr = wid >> 1, wc = wid & 1;
    int g = lane >> 4, c_ = lane & 15;
    const int nct = Ii >> 7;                    // 32
    const unsigned short* PGseg = PG + (size_t)seg * Cc * Ii;
    const unsigned short* PUseg = PU + (size_t)seg * Cc * Ii;

    f32x4 accG[2][4], accU[2][4];
#pragma unroll
    for (int m = 0; m < 2; m++)
#pragma unroll
        for (int n = 0; n < 4; n++) {
            accG[m][n] = (f32x4){0.f, 0.f, 0.f, 0.f};
            accU[m][n] = (f32x4){0.f, 0.f, 0.f, 0.f};
        }

    int mf0 = tid >> 6, lc0 = tid & 63;
    const unsigned short* gA =
        &A[(size_t)(rb + mf0 * 16 + (lc0 & 15)) * Cc + (lc0 >> 4) * 8];
    short8v av, gv[2], uv[2];
    auto load_tile = [&](int kt) {
        av = *reinterpret_cast<const short8v*>(gA + kt * 32);
#pragma unroll
        for (int i = 0; i < 2; i++) {
            int c = tid + i * 256;              // 0..511
            int cf = c >> 6, lc = c & 63;
            size_t off = (((size_t)kt * nct + cb) * 8 + cf) * 64 * 8 + (size_t)lc * 8;
            gv[i] = *reinterpret_cast<const short8v*>(PGseg + off);
            uv[i] = *reinterpret_cast<const short8v*>(PUseg + off);
        }
    };

    const int nKt = Cc >> 5;                    // 32
    load_tile(0);
    for (int kt = 0; kt < nKt; ++kt) {
        __syncthreads();
        *reinterpret_cast<short8v*>(&lds[(size_t)tid * 8]) = av;
#pragma unroll
        for (int i = 0; i < 2; i++) {
            *reinterpret_cast<short8v*>(&lds[2048 + (size_t)(tid + i * 256) * 8]) = gv[i];
            *reinterpret_cast<short8v*>(&lds[6144 + (size_t)(tid + i * 256) * 8]) = uv[i];
        }
        __syncthreads();
        if (kt + 1 < nKt) load_tile(kt + 1);
        short8v afr[2], gfr[4], ufr[4];
#pragma unroll
        for (int m = 0; m < 2; m++)
            afr[m] = *reinterpret_cast<short8v*>(&lds[((wr * 2 + m) * 64 + lane) * 8]);
#pragma unroll
        for (int n = 0; n < 4; n++) {
            gfr[n] = *reinterpret_cast<short8v*>(&lds[2048 + ((wc * 4 + n) * 64 + lane) * 8]);
            ufr[n] = *reinterpret_cast<short8v*>(&lds[6144 + ((wc * 4 + n) * 64 + lane) * 8]);
        }
#pragma unroll
        for (int m = 0; m < 2; m++)
#pragma unroll
            for (int n = 0; n < 4; n++) {
                accG[m][n] = __builtin_amdgcn_mfma_f32_16x16x32_bf16(
                    afr[m], gfr[n], accG[m][n], 0, 0, 0);
                accU[m][n] = __builtin_amdgcn_mfma_f32_16x16x32_bf16(
                    afr[m], ufr[n], accU[m][n], 0, 0, 0);
            }
    }

#pragma unroll
    for (int n = 0; n < 4; n++) {
        int col = cb * 128 + wc * 64 + n * 16 + c_;
#pragma unroll
        for (int m = 0; m < 2; m++) {
#pragma unroll
            for (int r = 0; r < 4; r++) {
                int row = rb + wr * 32 + m * 16 + g * 4 + r;
                float gval = accG[m][n][r], uval = accU[m][n][r];
                float t = gval / (1.f + __expf(-gval)) * uval;
                outp[(size_t)row * Ii + col] = f2bf(t);
            }
        }
    }
}

// ---------------------------------------------------------------------------
// proj combine: h(out) = x + bias[seg] + p0 + p1   (fp32 partials)
// ---------------------------------------------------------------------------
__global__ __launch_bounds__(256)
void combine_proj(const float* __restrict__ x, const float* __restrict__ bias,
                  const float* __restrict__ p, float* __restrict__ hb) {
    int i = blockIdx.x * 256 + threadIdx.x;
    int base = i * 4;
    int col = base % Cc;
    int n   = (base / Cc) % Nn;
    int seg = segof(n);
    float4 a = reinterpret_cast<const float4*>(x)[i];
    float4 b = *reinterpret_cast<const float4*>(&bias[(size_t)seg * Cc + col]);
    float4 p0 = reinterpret_cast<const float4*>(p)[i];
    float4 p1 = reinterpret_cast<const float4*>(p)[i + Mrows * Cc / 4];
    float4 r;
    r.x = a.x + b.x + p0.x + p1.x;
    r.y = a.y + b.y + p0.y + p1.y;
    r.z = a.z + b.z + p0.z + p1.z;
    r.w = a.w + b.w + p0.w + p1.w;
    reinterpret_cast<float4*>(hb)[i] = r;
}

// ---------------------------------------------------------------------------
// down combine: out = h(out) + sum_z bf2f(p_z)    (bf16 partials, NZ=4)
// ---------------------------------------------------------------------------
__global__ __launch_bounds__(256)
void combine_down4(const unsigned short* __restrict__ p,
                   float* __restrict__ out) {
    int i = blockIdx.x * 256 + threadIdx.x;
    float4 a = reinterpret_cast<const float4*>(out)[i];
#pragma unroll
    for (int z = 0; z < 4; z++) {
        ushort4 u = *reinterpret_cast<const ushort4*>(&p[(size_t)z * Mrows * Cc + i * 4]);
        a.x += bf2f(u.x); a.y += bf2f(u.y); a.z += bf2f(u.z); a.w += bf2f(u.w);
    }
    reinterpret_cast<float4*>(out)[i] = a;
}

// ---------------------------------------------------------------------------
// Split qkv(bf16) + per-head q/k RMSNorm + RoPE -> bf16 Q,K,V (bh, n, dh)
// ---------------------------------------------------------------------------
__global__ __launch_bounds__(256)
void split_rope(const unsigned short* __restrict__ qkv,
                const float* __restrict__ qn_w, const float* __restrict__ kn_w,
                const int* __restrict__ pos_ids, const int* __restrict__ tpos_ids,
                unsigned short* __restrict__ Q, unsigned short* __restrict__ K,
                unsigned short* __restrict__ V) {
    int row = blockIdx.x;
    int b = row / Nn, n = row % Nn;
    int seg = segof(n);
    int lane = threadIdx.x & 63, wid = threadIdx.x >> 6;
    int pos = (n < Tt) ? tpos_ids[n] : pos_ids[n - Tt];
    int j = lane & 31;
    float ang = (float)pos * exp2f(-(float)j * (13.287712379549449f / 32.f));
    float cv = cosf(ang), sv = sinf(ang);
    float qw = qn_w[seg * DH + lane], kw = kn_w[seg * DH + lane];
    for (int h = wid; h < Hh; h += 4) {
        const unsigned short* base = qkv + (size_t)row * (3 * Cc) + h * DH + lane;
        float q = bf2f(base[0]), k = bf2f(base[Cc]), v = bf2f(base[2 * Cc]);
        float qs = q * q, ks = k * k;
#pragma unroll
        for (int off = 32; off; off >>= 1) {
            qs += __shfl_xor(qs, off, 64);
            ks += __shfl_xor(ks, off, 64);
        }
        q = q * rsqrtf(qs * (1.f / DH) + 1e-6f) * qw;
        k = k * rsqrtf(ks * (1.f / DH) + 1e-6f) * kw;
        float qp = __shfl_xor(q, 32, 64);
        float kp = __shfl_xor(k, 32, 64);
        float qo = q * cv + ((lane < 32) ? -qp * sv : qp * sv);
        float ko = k * cv + ((lane < 32) ? -kp * sv : kp * sv);
        size_t oidx = ((size_t)(b * Hh + h) * Nn + n) * DH + lane;
        Q[oidx] = f2bf(qo);
        K[oidx] = f2bf(ko);
        V[oidx] = f2bf(v);
    }
}

// ---------------------------------------------------------------------------
// kernel_launch
// ---------------------------------------------------------------------------
extern "C" void kernel_launch(void* const* d_in, const int* in_sizes, int n_in,
                              void* d_out, int out_size, void* d_ws, size_t ws_size,
                              hipStream_t stream) {
    const float* x        = (const float*)d_in[0];
    const int*   pos_ids  = (const int*)d_in[1];
    const int*   tpos_ids = (const int*)d_in[2];
    const float* qkv_w    = (const float*)d_in[3];
    const float* qkv_b    = (const float*)d_in[4];
    const float* proj_w   = (const float*)d_in[5];
    const float* proj_b   = (const float*)d_in[6];
    const float* qn_w     = (const float*)d_in[7];
    const float* kn_w     = (const float*)d_in[8];
    const float* ln1_w    = (const float*)d_in[9];
    const float* ln2_w    = (const float*)d_in[10];
    const float* gate_w   = (const float*)d_in[11];
    const float* up_w     = (const float*)d_in[12];
    const float* down_w   = (const float*)d_in[13];
    float* out = (float*)d_out;                 // also used as h buffer
    char*  wsb = (char*)d_ws;

    // workspace (bytes), total 82,837,504 (= round-2 proven footprint)
    // WA: qkv pack -> gate pack -> down pack
    // WB: qkvb -> up pack -> down partials
    // Tb: Q,K,V -> proj partials -> t
    // P3: xn -> attn out -> y
    // P4: proj pack
    unsigned short* WA  = (unsigned short*)(wsb);               // 25,165,824
    unsigned short* WB  = (unsigned short*)(wsb + 25165824);    // 25,165,824
    unsigned short* Tb  = (unsigned short*)(wsb + 50331648);    // 20,971,520
    unsigned short* P3  = (unsigned short*)(wsb + 71303168);    //  5,242,880
    unsigned short* P4  = (unsigned short*)(wsb + 76546048);    //  6,291,456
    unsigned short* Qbf = Tb;
    unsigned short* Kbf = Tb + 2621440;
    unsigned short* Vbf = Tb + 5242880;

    // 1. fat1: xn = RMS(x, ln1) -> P3  ||  pack qkv_w -> WA
    fat1<<<Mrows + 4608, 256, 0, stream>>>(x, ln1_w, P3, qkv_w, WA);
    // 2. qkv = xn @ qkv_w + qkv_b -> bf16 (WB)
    gemm128r<1, true, 1><<<dim3(Mrows / 128, 24), 256, 0, stream>>>(
        P3, WA, qkv_b, WB, Cc, 3 * Cc);
    // 3. split + q/k RMS + RoPE -> Q,K,V (Tb)
    split_rope<<<Mrows, 256, 0, stream>>>(WB, qn_w, kn_w, pos_ids, tpos_ids,
                                          Qbf, Kbf, Vbf);
    // 4. fat2: attn -> P3  ||  pack proj -> P4, gate -> WA, up -> WB
    fat2<<<640 + 1536 + 6144 + 6144, 256, 0, stream>>>(
        Qbf, Kbf, Vbf, P3, proj_w, P4, gate_w, WA, up_w, WB);
    // 5. proj split-K=2 -> fp32 partials (Tb); combine -> h in out
    gemm128r<0, false, 2><<<dim3(Mrows / 128, 8, 2), 256, 0, stream>>>(
        P3, P4, nullptr, (float*)Tb, Cc, Cc);
    combine_proj<<<Mrows * Cc / 1024, 256, 0, stream>>>(x, proj_b, (float*)Tb, out);
    // 6. y = RMS(h, ln2) -> P3
    rms_bf16<<<Mrows, 256, 0, stream>>>(out, ln2_w, P3);
    // 7. fused: t = silu(y@gate) * (y@up) -> Tb   (1280 blocks, round-9 gu)
    gemm_gu<<<dim3(Mrows / 64, 32), 256, 0, stream>>>(P3, WA, WB, Tb);
    // 8. pack down_w -> WA (gate dead); down split-K=4 -> bf16 partials (WB)
    pack_w<<<6144, 256, 0, stream>>>(down_w, WA, Ii, Cc);
    gemm128r<1, false, 4><<<dim3(Mrows / 128, 8, 4), 256, 0, stream>>>(
        Tb, WA, nullptr, WB, Ii, Cc);
    combine_down4<<<Mrows * Cc / 1024, 256, 0, stream>>>(WB, out);
}

// Round 13
// 247.207 us; speedup vs baseline: 1.2104x; 1.0073x over previous
//
#include <hip/hip_runtime.h>
#include <math.h>

// Problem constants (fixed by setup_inputs)
constexpr int Bb  = 2;
constexpr int Nn  = 1280;
constexpr int Cc  = 1024;
constexpr int Hh  = 16;
constexpr int DH  = 64;
constexpr int Ii  = 4096;
constexpr int Tt  = 256;    // text_len
constexpr int BSz = 128;    // block_size
constexpr int L1  = 4;      // len1
constexpr int Mrows = Bb * Nn;  // 2560

typedef __attribute__((ext_vector_type(8))) short short8v;
typedef __attribute__((ext_vector_type(4))) float f32x4;

__device__ __forceinline__ int segof(int n) {
    return n < Tt ? 0 : (n < Tt + L1 * BSz ? 1 : 2);
}
__device__ __forceinline__ unsigned short f2bf(float f) {
    unsigned int u = __float_as_uint(f);
    u += 0x7fffu + ((u >> 16) & 1u);        // RNE
    return (unsigned short)(u >> 16);
}
__device__ __forceinline__ float bf2f(unsigned short h) {
    return __uint_as_float(((unsigned int)h) << 16);
}

// bijective XCD swizzle for nwg % 8 == 0
__device__ __forceinline__ int xcd_swz(int lin, int nwg) {
    int cpx = nwg >> 3;
    return (lin & 7) * cpx + (lin >> 3);
}

// ---------------------------------------------------------------------------
// device bodies: RMSNorm and weight-pack (used by fat kernels + standalone)
// ---------------------------------------------------------------------------
__device__ __forceinline__ void rms_dev(const float* __restrict__ in,
                                        const float* __restrict__ w,
                                        unsigned short* __restrict__ out,
                                        int row, float* sred) {
    int n   = row % Nn;
    int seg = segof(n);
    const float* x = in + (size_t)row * Cc;
    int t = threadIdx.x;
    float4 xv = reinterpret_cast<const float4*>(x)[t];
    float ss = xv.x * xv.x + xv.y * xv.y + xv.z * xv.z + xv.w * xv.w;
#pragma unroll
    for (int off = 32; off; off >>= 1) ss += __shfl_down(ss, off, 64);
    int lane = t & 63, wid = t >> 6;
    if (lane == 0) sred[wid] = ss;
    __syncthreads();
    if (t == 0) sred[4] = rsqrtf((sred[0] + sred[1] + sred[2] + sred[3]) * (1.0f / Cc) + 1e-6f);
    __syncthreads();
    float r = sred[4];
    float4 wv = reinterpret_cast<const float4*>(w + (size_t)seg * Cc)[t];
    ushort4 ov;
    ov.x = f2bf(wv.x * xv.x * r);
    ov.y = f2bf(wv.y * xv.y * r);
    ov.z = f2bf(wv.z * xv.z * r);
    ov.w = f2bf(wv.w * xv.w * r);
    *reinterpret_cast<ushort4*>(&out[(size_t)row * Cc + t * 4]) = ov;
}

// pack fp32 [3][K][Nd] -> fragment-linear bf16 chunks; one chunk per thread
__device__ __forceinline__ void pack_dev(const float* __restrict__ W,
                                         unsigned short* __restrict__ PB,
                                         int K, int Nd, size_t idx) {
    size_t cpseg = (size_t)K * Nd / 8;
    int s = (int)(idx / cpseg);
    size_t rm = idx % cpseg;
    int lane = (int)(rm & 63);
    int fr   = (int)((rm >> 6) & 7);
    size_t tile = rm >> 9;                  // kt32*(Nd/128)+cb
    int nct = Nd >> 7;
    int cb = (int)(tile % nct);
    int kt = (int)(tile / nct);
    int col = cb * 128 + fr * 16 + (lane & 15);
    int k0  = kt * 32 + (lane >> 4) * 8;
    const float* src = W + ((size_t)s * K + k0) * Nd + col;
    unsigned short o[8];
#pragma unroll
    for (int j = 0; j < 8; j++) o[j] = f2bf(src[(size_t)j * Nd]);
    short8v v;
#pragma unroll
    for (int j = 0; j < 8; j++) v[j] = (short)o[j];
    *reinterpret_cast<short8v*>(&PB[idx * 8]) = v;
}

// ---------------------------------------------------------------------------
// standalone pack kernel (down weights)
// ---------------------------------------------------------------------------
__global__ __launch_bounds__(256)
void pack_w(const float* __restrict__ W, unsigned short* __restrict__ PB,
            int K, int Nd) {
    pack_dev(W, PB, K, Nd, (size_t)blockIdx.x * 256 + threadIdx.x);
}

// fat1: rms1 (blocks [0, Mrows)) + pack_qkv (rest)
__global__ __launch_bounds__(256)
void fat1(const float* __restrict__ x, const float* __restrict__ ln1_w,
          unsigned short* __restrict__ xn,
          const float* __restrict__ qkv_w, unsigned short* __restrict__ qkv_p) {
    __shared__ float sred[5];
    int bid = blockIdx.x;
    if (bid < Mrows) {
        rms_dev(x, ln1_w, xn, bid, sred);
    } else {
        pack_dev(qkv_w, qkv_p, Cc, 3 * Cc, (size_t)(bid - Mrows) * 256 + threadIdx.x);
    }
}

// ---------------------------------------------------------------------------
// MFMA flash attention body (verified round 5-12 structure)
// ---------------------------------------------------------------------------
__device__ __forceinline__ void attn_dev(
        const unsigned short* __restrict__ Qg, const unsigned short* __restrict__ Kg,
        const unsigned short* __restrict__ Vg, unsigned short* __restrict__ O,
        int qt, int bh,
        unsigned short* k_lds, unsigned short* vt_lds, unsigned short* p_base) {
    int b = bh >> 4, h = bh & 15;
    int tid = threadIdx.x, lane = tid & 63, wid = tid >> 6;
    int g = lane >> 4, c = lane & 15;

    const size_t headoff = (size_t)bh * Nn * DH;
    int q0 = qt * 64;
    bool qtext = q0 < Tt;
    int qb = qtext ? 0 : (q0 - Tt) / BSz;

    int qrow_frag = q0 + wid * 16 + c;
    short8v aq[2];
#pragma unroll
    for (int kb = 0; kb < 2; kb++)
        aq[kb] = *reinterpret_cast<const short8v*>(
            &Qg[headoff + (size_t)qrow_frag * DH + kb * 32 + g * 8]);

    unsigned short* pbuf = p_base + wid * 1024;

    f32x4 o_[4];
#pragma unroll
    for (int nb = 0; nb < 4; nb++) o_[nb] = (f32x4){0.f, 0.f, 0.f, 0.f};
    float m_[4] = {-3.4e38f, -3.4e38f, -3.4e38f, -3.4e38f};
    float l_[4] = {0.f, 0.f, 0.f, 0.f};

    int tr = tid >> 2, tc = tid & 3;

    for (int kt = 0; kt < Nn / 64; kt++) {
        int kbase = kt * 64;
        bool vis, diag = false;
        if (qtext) {
            vis = (kbase <= q0);
            diag = (kbase == q0);
        } else if (kbase < Tt) {
            vis = true;
        } else {
            int kb = (kbase - Tt) / BSz;
            vis = (qb < L1) ? (kb <= qb)
                            : ((kb < L1 && qb - L1 > kb) || kb == qb);
        }
        if (!vis) continue;

        __syncthreads();
        {
            const unsigned short* ks = &Kg[headoff + (size_t)(kbase + tr) * DH];
            const unsigned short* vs = &Vg[headoff + (size_t)(kbase + tr) * DH];
#pragma unroll
            for (int i = 0; i < 2; i++) {
                int ch = tc + i * 4;
                short8v kv = *reinterpret_cast<const short8v*>(ks + ch * 8);
                int byte = (tr * 128 + ch * 16) ^ ((tr & 7) << 4);
                *reinterpret_cast<short8v*>((char*)k_lds + byte) = kv;
                short8v vv = *reinterpret_cast<const short8v*>(vs + ch * 8);
#pragma unroll
                for (int j = 0; j < 8; j++) {
                    int dh = ch * 8 + j;
                    int vbyte = (dh * 128 + tr * 2) ^ ((dh & 7) << 4);
                    *reinterpret_cast<unsigned short*>((char*)vt_lds + vbyte) =
                        (unsigned short)vv[j];
                }
            }
        }
        __syncthreads();

        f32x4 s_[4];
#pragma unroll
        for (int nb = 0; nb < 4; nb++) s_[nb] = (f32x4){0.f, 0.f, 0.f, 0.f};
#pragma unroll
        for (int nb = 0; nb < 4; nb++) {
            int kil = nb * 16 + c;
#pragma unroll
            for (int kb = 0; kb < 2; kb++) {
                int byte = (kil * 128 + kb * 64 + g * 16) ^ ((kil & 7) << 4);
                short8v bk = *reinterpret_cast<short8v*>((char*)k_lds + byte);
                s_[nb] = __builtin_amdgcn_mfma_f32_16x16x32_bf16(aq[kb], bk, s_[nb], 0, 0, 0);
            }
        }
#pragma unroll
        for (int nb = 0; nb < 4; nb++) {
#pragma unroll
            for (int r = 0; r < 4; r++) {
                float sv = s_[nb][r] * 0.125f;
                if (diag) {
                    int qrl = wid * 16 + g * 4 + r;
                    int kcl = nb * 16 + c;
                    if (qrl < kcl) sv = -3.4e38f;
                }
                s_[nb][r] = sv;
            }
        }
#pragma unroll
        for (int r = 0; r < 4; r++) {
            float mx = fmaxf(fmaxf(s_[0][r], s_[1][r]), fmaxf(s_[2][r], s_[3][r]));
#pragma unroll
            for (int off = 1; off <= 8; off <<= 1)
                mx = fmaxf(mx, __shfl_xor(mx, off, 64));
            float mn = fmaxf(m_[r], mx);
            float es = __expf(m_[r] - mn);
            m_[r] = mn;
            float pv[4];
            float rs = 0.f;
#pragma unroll
            for (int nb = 0; nb < 4; nb++) {
                pv[nb] = __expf(s_[nb][r] - mn);
                rs += pv[nb];
            }
#pragma unroll
            for (int off = 1; off <= 8; off <<= 1)
                rs += __shfl_xor(rs, off, 64);
            l_[r] = l_[r] * es + rs;
#pragma unroll
            for (int nb = 0; nb < 4; nb++) o_[nb][r] *= es;
            int qrl = g * 4 + r;
            int swz = (qrl & 7) << 4;
#pragma unroll
            for (int nb = 0; nb < 4; nb++) {
                int byte = (qrl * 128 + (nb * 16 + c) * 2) ^ swz;
                *reinterpret_cast<unsigned short*>((char*)pbuf + byte) = f2bf(pv[nb]);
            }
        }
        short8v aP[2];
#pragma unroll
        for (int kb = 0; kb < 2; kb++) {
            int byte = (c * 128 + kb * 64 + g * 16) ^ ((c & 7) << 4);
            aP[kb] = *reinterpret_cast<short8v*>((char*)pbuf + byte);
        }
#pragma unroll
        for (int nb = 0; nb < 4; nb++) {
            int dh = nb * 16 + c;
#pragma unroll
            for (int kb = 0; kb < 2; kb++) {
                int byte = (dh * 128 + kb * 64 + g * 16) ^ ((dh & 7) << 4);
                short8v bv = *reinterpret_cast<short8v*>((char*)vt_lds + byte);
                o_[nb] = __builtin_amdgcn_mfma_f32_16x16x32_bf16(aP[kb], bv, o_[nb], 0, 0, 0);
            }
        }
    }

    float inv_[4];
#pragma unroll
    for (int r = 0; r < 4; r++) inv_[r] = 1.f / l_[r];
#pragma unroll
    for (int nb = 0; nb < 4; nb++) {
        int col = h * DH + nb * 16 + c;
#pragma unroll
        for (int r = 0; r < 4; r++) {
            int row = q0 + wid * 16 + g * 4 + r;
            O[((size_t)b * Nn + row) * Cc + col] = f2bf(o_[nb][r] * inv_[r]);
        }
    }
}

// fat2: attn (blocks [0,640)) + pack_proj (1536) + pack_gate (6144) + pack_up (6144)
__global__ __launch_bounds__(256)
void fat2(const unsigned short* __restrict__ Qg, const unsigned short* __restrict__ Kg,
          const unsigned short* __restrict__ Vg, unsigned short* __restrict__ O,
          const float* __restrict__ proj_w, unsigned short* __restrict__ proj_p,
          const float* __restrict__ gate_w, unsigned short* __restrict__ gate_p,
          const float* __restrict__ up_w,   unsigned short* __restrict__ up_p) {
    __shared__ __align__(16) unsigned short k_lds[64 * 64];
    __shared__ __align__(16) unsigned short vt_lds[64 * 64];
    __shared__ __align__(16) unsigned short p_lds[4 * 16 * 64];
    int bid = blockIdx.x;
    if (bid < 640) {
        attn_dev(Qg, Kg, Vg, O, bid % 20, bid / 20, k_lds, vt_lds, p_lds);
        return;
    }
    bid -= 640;
    if (bid < 1536) {
        pack_dev(proj_w, proj_p, Cc, Cc, (size_t)bid * 256 + threadIdx.x);
        return;
    }
    bid -= 1536;
    if (bid < 6144) {
        pack_dev(gate_w, gate_p, Cc, Ii, (size_t)bid * 256 + threadIdx.x);
        return;
    }
    bid -= 6144;
    pack_dev(up_w, up_p, Cc, Ii, (size_t)bid * 256 + threadIdx.x);
}

// ---------------------------------------------------------------------------
// bf16 MFMA GEMM (round-10 verified): 128x128 tile, BK=32, 4 waves 2x2
// (wave = 64x64, 4x4 acc), packed-B, pointer-bumped reg-staged prefetch.
// OUTMODE: 0 = f32 out, 1 = bf16 out.  NZ: split-K; partial z at z*Mrows*Nd.
// ---------------------------------------------------------------------------
template <int OUTMODE, bool BIAS, int NZ>
__global__ __launch_bounds__(256, 2)
void gemm128r(const unsigned short* __restrict__ A,
              const unsigned short* __restrict__ PB,
              const float* __restrict__ bias, void* __restrict__ outp,
              int K, int Nd) {
    __shared__ __align__(16) unsigned short lds[8192];   // A 8KB | B 8KB
    int bx = blockIdx.x, by = blockIdx.y, bz = (NZ > 1) ? blockIdx.z : 0;
    {
        int gx = gridDim.x, gy = gridDim.y, gz = (NZ > 1) ? gridDim.z : 1;
        int lin = bx + gx * (by + gy * bz);
        int swz = xcd_swz(lin, gx * gy * gz);
        bx = swz % gx; swz /= gx;
        by = swz % gy; bz = swz / gy;
    }
    int rb = bx * 128, cb = by;
    int seg = segof(rb % Nn);
    int tid = threadIdx.x, lane = tid & 63, wid = tid >> 6;
    int wr = wid >> 1, wc = wid & 1;
    int g = lane >> 4, c_ = lane & 15;
    const int nct = Nd >> 7;
    const int Keff = K / NZ;
    const int nKt = Keff >> 5;
    const int kz = bz * Keff;
    const unsigned short* PBseg = PB + (size_t)seg * K * Nd;

    int mf0 = tid >> 6, lc0 = tid & 63;
    const unsigned short* pA0 =
        A + (size_t)(rb + mf0 * 16 + (lc0 & 15)) * K + kz + (lc0 >> 4) * 8;
    const unsigned short* pA1 = pA0 + (size_t)64 * K;
    const unsigned short* pB0 =
        PBseg + (((size_t)(kz >> 5) * nct + cb) * 8 + mf0) * 512 + (size_t)lc0 * 8;
    const unsigned short* pB1 = pB0 + 2048;
    const size_t bstep = (size_t)nct * 4096;   // shorts per K-step

    f32x4 acc[4][4];
#pragma unroll
    for (int m = 0; m < 4; m++)
#pragma unroll
        for (int n = 0; n < 4; n++) acc[m][n] = (f32x4){0.f, 0.f, 0.f, 0.f};

    short8v av[2], bv[2];
    av[0] = *reinterpret_cast<const short8v*>(pA0);
    av[1] = *reinterpret_cast<const short8v*>(pA1);
    bv[0] = *reinterpret_cast<const short8v*>(pB0);
    bv[1] = *reinterpret_cast<const short8v*>(pB1);
    pA0 += 32; pA1 += 32; pB0 += bstep; pB1 += bstep;

    for (int kt = 0; kt < nKt; ++kt) {
        __syncthreads();                        // prev iter's ds_reads done
        *reinterpret_cast<short8v*>(&lds[(size_t)tid * 8]) = av[0];
        *reinterpret_cast<short8v*>(&lds[(size_t)(tid + 256) * 8]) = av[1];
        *reinterpret_cast<short8v*>(&lds[4096 + (size_t)tid * 8]) = bv[0];
        *reinterpret_cast<short8v*>(&lds[4096 + (size_t)(tid + 256) * 8]) = bv[1];
        __syncthreads();
        if (kt + 1 < nKt) {                     // prefetch under MFMA
            av[0] = *reinterpret_cast<const short8v*>(pA0);
            av[1] = *reinterpret_cast<const short8v*>(pA1);
            bv[0] = *reinterpret_cast<const short8v*>(pB0);
            bv[1] = *reinterpret_cast<const short8v*>(pB1);
            pA0 += 32; pA1 += 32; pB0 += bstep; pB1 += bstep;
        }
        short8v afr[4], bfr[4];
#pragma unroll
        for (int m = 0; m < 4; m++)
            afr[m] = *reinterpret_cast<short8v*>(&lds[((wr * 4 + m) * 64 + lane) * 8]);
#pragma unroll
        for (int n = 0; n < 4; n++)
            bfr[n] = *reinterpret_cast<short8v*>(&lds[4096 + ((wc * 4 + n) * 64 + lane) * 8]);
#pragma unroll
        for (int m = 0; m < 4; m++)
#pragma unroll
            for (int n = 0; n < 4; n++)
                acc[m][n] = __builtin_amdgcn_mfma_f32_16x16x32_bf16(
                    afr[m], bfr[n], acc[m][n], 0, 0, 0);
    }

    float* outf = (float*)outp;
    unsigned short* outh = (unsigned short*)outp;
    size_t zoff = (NZ > 1) ? (size_t)bz * Mrows * Nd : 0;
#pragma unroll
    for (int n = 0; n < 4; n++) {
        int col = cb * 128 + wc * 64 + n * 16 + c_;
        float bvv = BIAS ? bias[(size_t)seg * Nd + col] : 0.f;
#pragma unroll
        for (int m = 0; m < 4; m++) {
#pragma unroll
            for (int r = 0; r < 4; r++) {
                int row = rb + wr * 64 + m * 16 + g * 4 + r;
                float v = acc[m][n][r] + bvv;
                if (OUTMODE == 0) outf[zoff + (size_t)row * Nd + col] = v;
                else              outh[zoff + (size_t)row * Nd + col] = f2bf(v);
            }
        }
    }
}

// ---------------------------------------------------------------------------
// Fused gate+up GEMM v4: 64x128 tile, BK=32, 4 waves in 1x4 column slices
// (wave = 64 rows x 32 cols): 8 ds_read_b128 per 16 MFMA (afr reused for
// both G and U). Reg-staged prefetch identical to the verified round-9 gu.
// ---------------------------------------------------------------------------
__global__ __launch_bounds__(256)
void gemm_gu(const unsigned short* __restrict__ A,
             const unsigned short* __restrict__ PG,
             const unsigned short* __restrict__ PU,
             unsigned short* __restrict__ outp) {
    __shared__ __align__(16) unsigned short lds[10240];  // A 4KB | G 8KB | U 8KB
    int bx = blockIdx.x, by = blockIdx.y;
    {
        int lin = bx + gridDim.x * by;
        int swz = xcd_swz(lin, gridDim.x * gridDim.y);
        bx = swz % gridDim.x; by = swz / gridDim.x;
    }
    int rb = bx * 64, cb = by;
    int seg = segof(rb % Nn);
    int tid = threadIdx.x, lane = tid & 63, wid = tid >> 6;
    int g = lane >> 4, c_ = lane & 15;
    const int nct = Ii >> 7;                    // 32
    const unsigned short* PGseg = PG + (size_t)seg * Cc * Ii;
    const unsigned short* PUseg = PU + (size_t)seg * Cc * Ii;

    f32x4 accG[4][2], accU[4][2];
#pragma unroll
    for (int m = 0; m < 4; m++)
#pragma unroll
        for (int n = 0; n < 2; n++) {
            accG[m][n] = (f32x4){0.f, 0.f, 0.f, 0.f};
            accU[m][n] = (f32x4){0.f, 0.f, 0.f, 0.f};
        }

    int mf0 = tid >> 6, lc0 = tid & 63;
    const unsigned short* gA =
        &A[(size_t)(rb + mf0 * 16 + (lc0 & 15)) * Cc + (lc0 >> 4) * 8];
    short8v av, gv[2], uv[2];
    auto load_tile = [&](int kt) {
        av = *reinterpret_cast<const short8v*>(gA + kt * 32);
#pragma unroll
        for (int i = 0; i < 2; i++) {
            int c = tid + i * 256;              // 0..511
            int cf = c >> 6, lc = c & 63;
            size_t off = (((size_t)kt * nct + cb) * 8 + cf) * 64 * 8 + (size_t)lc * 8;
            gv[i] = *reinterpret_cast<const short8v*>(PGseg + off);
            uv[i] = *reinterpret_cast<const short8v*>(PUseg + off);
        }
    };

    const int nKt = Cc >> 5;                    // 32
    load_tile(0);
    for (int kt = 0; kt < nKt; ++kt) {
        __syncthreads();
        *reinterpret_cast<short8v*>(&lds[(size_t)tid * 8]) = av;
#pragma unroll
        for (int i = 0; i < 2; i++) {
            *reinterpret_cast<short8v*>(&lds[2048 + (size_t)(tid + i * 256) * 8]) = gv[i];
            *reinterpret_cast<short8v*>(&lds[6144 + (size_t)(tid + i * 256) * 8]) = uv[i];
        }
        __syncthreads();
        if (kt + 1 < nKt) load_tile(kt + 1);
        // 1x4 layout: every wave reads all 4 A-frags + its own 2 G/U col-frags
        short8v afr[4], gfr[2], ufr[2];
#pragma unroll
        for (int m = 0; m < 4; m++)
            afr[m] = *reinterpret_cast<short8v*>(&lds[((m) * 64 + lane) * 8]);
#pragma unroll
        for (int n = 0; n < 2; n++) {
            gfr[n] = *reinterpret_cast<short8v*>(&lds[2048 + ((wid * 2 + n) * 64 + lane) * 8]);
            ufr[n] = *reinterpret_cast<short8v*>(&lds[6144 + ((wid * 2 + n) * 64 + lane) * 8]);
        }
#pragma unroll
        for (int m = 0; m < 4; m++)
#pragma unroll
            for (int n = 0; n < 2; n++) {
                accG[m][n] = __builtin_amdgcn_mfma_f32_16x16x32_bf16(
                    afr[m], gfr[n], accG[m][n], 0, 0, 0);
                accU[m][n] = __builtin_amdgcn_mfma_f32_16x16x32_bf16(
                    afr[m], ufr[n], accU[m][n], 0, 0, 0);
            }
    }

    // epilogue: t = silu(g) * u ; wave writes its 64-row x 32-col slice
#pragma unroll
    for (int n = 0; n < 2; n++) {
        int col = cb * 128 + (wid * 2 + n) * 16 + c_;
#pragma unroll
        for (int m = 0; m < 4; m++) {
#pragma unroll
            for (int r = 0; r < 4; r++) {
                int row = rb + m * 16 + g * 4 + r;
                float gval = accG[m][n][r], uval = accU[m][n][r];
                float t = gval / (1.f + __expf(-gval)) * uval;
                outp[(size_t)row * Ii + col] = f2bf(t);
            }
        }
    }
}

// ---------------------------------------------------------------------------
// fused proj-combine + RMSNorm2: h = x + bias + p0 + p1 -> out (fp32),
// y = RMS(h, ln2) -> bf16. One block per row (2560 blocks, 256 thr).
// ---------------------------------------------------------------------------
__global__ __launch_bounds__(256)
void combine_rms(const float* __restrict__ x, const float* __restrict__ bias,
                 const float* __restrict__ p, const float* __restrict__ ln2_w,
                 float* __restrict__ out, unsigned short* __restrict__ y) {
    int row = blockIdx.x;
    int n   = row % Nn;
    int seg = segof(n);
    int t   = threadIdx.x;
    size_t i = (size_t)row * 256 + t;           // float4 index
    float4 a  = reinterpret_cast<const float4*>(x)[i];
    float4 b  = *reinterpret_cast<const float4*>(&bias[(size_t)seg * Cc + t * 4]);
    float4 p0 = reinterpret_cast<const float4*>(p)[i];
    float4 p1 = reinterpret_cast<const float4*>(p)[i + Mrows * Cc / 4];
    float4 h;
    h.x = a.x + b.x + p0.x + p1.x;
    h.y = a.y + b.y + p0.y + p1.y;
    h.z = a.z + b.z + p0.z + p1.z;
    h.w = a.w + b.w + p0.w + p1.w;
    reinterpret_cast<float4*>(out)[i] = h;
    float ss = h.x * h.x + h.y * h.y + h.z * h.z + h.w * h.w;
#pragma unroll
    for (int off = 32; off; off >>= 1) ss += __shfl_down(ss, off, 64);
    __shared__ float sred[5];
    int lane = t & 63, wid = t >> 6;
    if (lane == 0) sred[wid] = ss;
    __syncthreads();
    if (t == 0) sred[4] = rsqrtf((sred[0] + sred[1] + sred[2] + sred[3]) * (1.0f / Cc) + 1e-6f);
    __syncthreads();
    float r = sred[4];
    float4 wv = reinterpret_cast<const float4*>(ln2_w + (size_t)seg * Cc)[t];
    ushort4 ov;
    ov.x = f2bf(wv.x * h.x * r);
    ov.y = f2bf(wv.y * h.y * r);
    ov.z = f2bf(wv.z * h.z * r);
    ov.w = f2bf(wv.w * h.w * r);
    *reinterpret_cast<ushort4*>(&y[(size_t)row * Cc + t * 4]) = ov;
}

// ---------------------------------------------------------------------------
// down combine: out = h(out) + sum_z bf2f(p_z)    (bf16 partials, NZ=4)
// ---------------------------------------------------------------------------
__global__ __launch_bounds__(256)
void combine_down4(const unsigned short* __restrict__ p,
                   float* __restrict__ out) {
    int i = blockIdx.x * 256 + threadIdx.x;
    float4 a = reinterpret_cast<const float4*>(out)[i];
#pragma unroll
    for (int z = 0; z < 4; z++) {
        ushort4 u = *reinterpret_cast<const ushort4*>(&p[(size_t)z * Mrows * Cc + i * 4]);
        a.x += bf2f(u.x); a.y += bf2f(u.y); a.z += bf2f(u.z); a.w += bf2f(u.w);
    }
    reinterpret_cast<float4*>(out)[i] = a;
}

// ---------------------------------------------------------------------------
// Split qkv(bf16) + per-head q/k RMSNorm + RoPE -> bf16 Q,K,V (bh, n, dh)
// ---------------------------------------------------------------------------
__global__ __launch_bounds__(256)
void split_rope(const unsigned short* __restrict__ qkv,
                const float* __restrict__ qn_w, const float* __restrict__ kn_w,
                const int* __restrict__ pos_ids, const int* __restrict__ tpos_ids,
                unsigned short* __restrict__ Q, unsigned short* __restrict__ K,
                unsigned short* __restrict__ V) {
    int row = blockIdx.x;
    int b = row / Nn, n = row % Nn;
    int seg = segof(n);
    int lane = threadIdx.x & 63, wid = threadIdx.x >> 6;
    int pos = (n < Tt) ? tpos_ids[n] : pos_ids[n - Tt];
    int j = lane & 31;
    float ang = (float)pos * exp2f(-(float)j * (13.287712379549449f / 32.f));
    float cv = cosf(ang), sv = sinf(ang);
    float qw = qn_w[seg * DH + lane], kw = kn_w[seg * DH + lane];
    for (int h = wid; h < Hh; h += 4) {
        const unsigned short* base = qkv + (size_t)row * (3 * Cc) + h * DH + lane;
        float q = bf2f(base[0]), k = bf2f(base[Cc]), v = bf2f(base[2 * Cc]);
        float qs = q * q, ks = k * k;
#pragma unroll
        for (int off = 32; off; off >>= 1) {
            qs += __shfl_xor(qs, off, 64);
            ks += __shfl_xor(ks, off, 64);
        }
        q = q * rsqrtf(qs * (1.f / DH) + 1e-6f) * qw;
        k = k * rsqrtf(ks * (1.f / DH) + 1e-6f) * kw;
        float qp = __shfl_xor(q, 32, 64);
        float kp = __shfl_xor(k, 32, 64);
        float qo = q * cv + ((lane < 32) ? -qp * sv : qp * sv);
        float ko = k * cv + ((lane < 32) ? -kp * sv : kp * sv);
        size_t oidx = ((size_t)(b * Hh + h) * Nn + n) * DH + lane;
        Q[oidx] = f2bf(qo);
        K[oidx] = f2bf(ko);
        V[oidx] = f2bf(v);
    }
}

// ---------------------------------------------------------------------------
// kernel_launch
// ---------------------------------------------------------------------------
extern "C" void kernel_launch(void* const* d_in, const int* in_sizes, int n_in,
                              void* d_out, int out_size, void* d_ws, size_t ws_size,
                              hipStream_t stream) {
    const float* x        = (const float*)d_in[0];
    const int*   pos_ids  = (const int*)d_in[1];
    const int*   tpos_ids = (const int*)d_in[2];
    const float* qkv_w    = (const float*)d_in[3];
    const float* qkv_b    = (const float*)d_in[4];
    const float* proj_w   = (const float*)d_in[5];
    const float* proj_b   = (const float*)d_in[6];
    const float* qn_w     = (const float*)d_in[7];
    const float* kn_w     = (const float*)d_in[8];
    const float* ln1_w    = (const float*)d_in[9];
    const float* ln2_w    = (const float*)d_in[10];
    const float* gate_w   = (const float*)d_in[11];
    const float* up_w     = (const float*)d_in[12];
    const float* down_w   = (const float*)d_in[13];
    float* out = (float*)d_out;                 // also used as h buffer
    char*  wsb = (char*)d_ws;

    // workspace (bytes), total 82,837,504
    // WA: qkv pack -> gate pack -> down pack
    // WB: qkvb -> up pack -> down partials
    // Tb: Q,K,V -> proj partials -> t
    // P3: xn -> attn out -> y
    // P4: proj pack
    unsigned short* WA  = (unsigned short*)(wsb);               // 25,165,824
    unsigned short* WB  = (unsigned short*)(wsb + 25165824);    // 25,165,824
    unsigned short* Tb  = (unsigned short*)(wsb + 50331648);    // 20,971,520
    unsigned short* P3  = (unsigned short*)(wsb + 71303168);    //  5,242,880
    unsigned short* P4  = (unsigned short*)(wsb + 76546048);    //  6,291,456
    unsigned short* Qbf = Tb;
    unsigned short* Kbf = Tb + 2621440;
    unsigned short* Vbf = Tb + 5242880;

    // 1. fat1: xn = RMS(x, ln1) -> P3  ||  pack qkv_w -> WA
    fat1<<<Mrows + 4608, 256, 0, stream>>>(x, ln1_w, P3, qkv_w, WA);
    // 2. qkv = xn @ qkv_w + qkv_b -> bf16 (WB)
    gemm128r<1, true, 1><<<dim3(Mrows / 128, 24), 256, 0, stream>>>(
        P3, WA, qkv_b, WB, Cc, 3 * Cc);
    // 3. split + q/k RMS + RoPE -> Q,K,V (Tb)
    split_rope<<<Mrows, 256, 0, stream>>>(WB, qn_w, kn_w, pos_ids, tpos_ids,
                                          Qbf, Kbf, Vbf);
    // 4. fat2: attn -> P3  ||  pack proj -> P4, gate -> WA, up -> WB
    fat2<<<640 + 1536 + 6144 + 6144, 256, 0, stream>>>(
        Qbf, Kbf, Vbf, P3, proj_w, P4, gate_w, WA, up_w, WB);
    // 5. proj split-K=2 -> fp32 partials (Tb); fused combine+rms2 -> out, P3
    gemm128r<0, false, 2><<<dim3(Mrows / 128, 8, 2), 256, 0, stream>>>(
        P3, P4, nullptr, (float*)Tb, Cc, Cc);
    combine_rms<<<Mrows, 256, 0, stream>>>(x, proj_b, (float*)Tb, ln2_w, out, P3);
    // 6. fused: t = silu(y@gate) * (y@up) -> Tb   (1280 blocks, 1x4 waves)
    gemm_gu<<<dim3(Mrows / 64, 32), 256, 0, stream>>>(P3, WA, WB, Tb);
    // 7. pack down_w -> WA (gate dead); down split-K=4 -> bf16 partials (WB)
    pack_w<<<6144, 256, 0, stream>>>(down_w, WA, Ii, Cc);
    gemm128r<1, false, 4><<<dim3(Mrows / 128, 8, 4), 256, 0, stream>>>(
        Tb, WA, nullptr, WB, Ii, Cc);
    combine_down4<<<Mrows * Cc / 1024, 256, 0, stream>>>(WB, out);
}

// Round 14
// 245.832 us; speedup vs baseline: 1.2172x; 1.0056x over previous
//
#include <hip/hip_runtime.h>
#include <math.h>

// Problem constants (fixed by setup_inputs)
constexpr int Bb  = 2;
constexpr int Nn  = 1280;
constexpr int Cc  = 1024;
constexpr int Hh  = 16;
constexpr int DH  = 64;
constexpr int Ii  = 4096;
constexpr int Tt  = 256;    // text_len
constexpr int BSz = 128;    // block_size
constexpr int L1  = 4;      // len1
constexpr int Mrows = Bb * Nn;  // 2560

typedef __attribute__((ext_vector_type(8))) short short8v;
typedef __attribute__((ext_vector_type(4))) float f32x4;

__device__ __forceinline__ int segof(int n) {
    return n < Tt ? 0 : (n < Tt + L1 * BSz ? 1 : 2);
}
__device__ __forceinline__ unsigned short f2bf(float f) {
    unsigned int u = __float_as_uint(f);
    u += 0x7fffu + ((u >> 16) & 1u);        // RNE
    return (unsigned short)(u >> 16);
}
__device__ __forceinline__ float bf2f(unsigned short h) {
    return __uint_as_float(((unsigned int)h) << 16);
}

// bijective XCD swizzle for nwg % 8 == 0
__device__ __forceinline__ int xcd_swz(int lin, int nwg) {
    int cpx = nwg >> 3;
    return (lin & 7) * cpx + (lin >> 3);
}

// ---------------------------------------------------------------------------
// device bodies: RMSNorm and weight-pack (used by fat kernels + standalone)
// ---------------------------------------------------------------------------
__device__ __forceinline__ void rms_dev(const float* __restrict__ in,
                                        const float* __restrict__ w,
                                        unsigned short* __restrict__ out,
                                        int row, float* sred) {
    int n   = row % Nn;
    int seg = segof(n);
    const float* x = in + (size_t)row * Cc;
    int t = threadIdx.x;
    float4 xv = reinterpret_cast<const float4*>(x)[t];
    float ss = xv.x * xv.x + xv.y * xv.y + xv.z * xv.z + xv.w * xv.w;
#pragma unroll
    for (int off = 32; off; off >>= 1) ss += __shfl_down(ss, off, 64);
    int lane = t & 63, wid = t >> 6;
    if (lane == 0) sred[wid] = ss;
    __syncthreads();
    if (t == 0) sred[4] = rsqrtf((sred[0] + sred[1] + sred[2] + sred[3]) * (1.0f / Cc) + 1e-6f);
    __syncthreads();
    float r = sred[4];
    float4 wv = reinterpret_cast<const float4*>(w + (size_t)seg * Cc)[t];
    ushort4 ov;
    ov.x = f2bf(wv.x * xv.x * r);
    ov.y = f2bf(wv.y * xv.y * r);
    ov.z = f2bf(wv.z * xv.z * r);
    ov.w = f2bf(wv.w * xv.w * r);
    *reinterpret_cast<ushort4*>(&out[(size_t)row * Cc + t * 4]) = ov;
}

// pack fp32 [3][K][Nd] -> fragment-linear bf16 chunks; one chunk per thread
__device__ __forceinline__ void pack_dev(const float* __restrict__ W,
                                         unsigned short* __restrict__ PB,
                                         int K, int Nd, size_t idx) {
    size_t cpseg = (size_t)K * Nd / 8;
    int s = (int)(idx / cpseg);
    size_t rm = idx % cpseg;
    int lane = (int)(rm & 63);
    int fr   = (int)((rm >> 6) & 7);
    size_t tile = rm >> 9;                  // kt32*(Nd/128)+cb
    int nct = Nd >> 7;
    int cb = (int)(tile % nct);
    int kt = (int)(tile / nct);
    int col = cb * 128 + fr * 16 + (lane & 15);
    int k0  = kt * 32 + (lane >> 4) * 8;
    const float* src = W + ((size_t)s * K + k0) * Nd + col;
    unsigned short o[8];
#pragma unroll
    for (int j = 0; j < 8; j++) o[j] = f2bf(src[(size_t)j * Nd]);
    short8v v;
#pragma unroll
    for (int j = 0; j < 8; j++) v[j] = (short)o[j];
    *reinterpret_cast<short8v*>(&PB[idx * 8]) = v;
}

// ---------------------------------------------------------------------------
// standalone pack kernel (down weights)
// ---------------------------------------------------------------------------
__global__ __launch_bounds__(256)
void pack_w(const float* __restrict__ W, unsigned short* __restrict__ PB,
            int K, int Nd) {
    pack_dev(W, PB, K, Nd, (size_t)blockIdx.x * 256 + threadIdx.x);
}

// fat1: rms1 (blocks [0, Mrows)) + pack_qkv (rest)
__global__ __launch_bounds__(256)
void fat1(const float* __restrict__ x, const float* __restrict__ ln1_w,
          unsigned short* __restrict__ xn,
          const float* __restrict__ qkv_w, unsigned short* __restrict__ qkv_p) {
    __shared__ float sred[5];
    int bid = blockIdx.x;
    if (bid < Mrows) {
        rms_dev(x, ln1_w, xn, bid, sred);
    } else {
        pack_dev(qkv_w, qkv_p, Cc, 3 * Cc, (size_t)(bid - Mrows) * 256 + threadIdx.x);
    }
}

// ---------------------------------------------------------------------------
// MFMA flash attention body (verified round 5-13 structure)
// ---------------------------------------------------------------------------
__device__ __forceinline__ void attn_dev(
        const unsigned short* __restrict__ Qg, const unsigned short* __restrict__ Kg,
        const unsigned short* __restrict__ Vg, unsigned short* __restrict__ O,
        int qt, int bh,
        unsigned short* k_lds, unsigned short* vt_lds, unsigned short* p_base) {
    int b = bh >> 4, h = bh & 15;
    int tid = threadIdx.x, lane = tid & 63, wid = tid >> 6;
    int g = lane >> 4, c = lane & 15;

    const size_t headoff = (size_t)bh * Nn * DH;
    int q0 = qt * 64;
    bool qtext = q0 < Tt;
    int qb = qtext ? 0 : (q0 - Tt) / BSz;

    int qrow_frag = q0 + wid * 16 + c;
    short8v aq[2];
#pragma unroll
    for (int kb = 0; kb < 2; kb++)
        aq[kb] = *reinterpret_cast<const short8v*>(
            &Qg[headoff + (size_t)qrow_frag * DH + kb * 32 + g * 8]);

    unsigned short* pbuf = p_base + wid * 1024;

    f32x4 o_[4];
#pragma unroll
    for (int nb = 0; nb < 4; nb++) o_[nb] = (f32x4){0.f, 0.f, 0.f, 0.f};
    float m_[4] = {-3.4e38f, -3.4e38f, -3.4e38f, -3.4e38f};
    float l_[4] = {0.f, 0.f, 0.f, 0.f};

    int tr = tid >> 2, tc = tid & 3;

    for (int kt = 0; kt < Nn / 64; kt++) {
        int kbase = kt * 64;
        bool vis, diag = false;
        if (qtext) {
            vis = (kbase <= q0);
            diag = (kbase == q0);
        } else if (kbase < Tt) {
            vis = true;
        } else {
            int kb = (kbase - Tt) / BSz;
            vis = (qb < L1) ? (kb <= qb)
                            : ((kb < L1 && qb - L1 > kb) || kb == qb);
        }
        if (!vis) continue;

        __syncthreads();
        {
            const unsigned short* ks = &Kg[headoff + (size_t)(kbase + tr) * DH];
            const unsigned short* vs = &Vg[headoff + (size_t)(kbase + tr) * DH];
#pragma unroll
            for (int i = 0; i < 2; i++) {
                int ch = tc + i * 4;
                short8v kv = *reinterpret_cast<const short8v*>(ks + ch * 8);
                int byte = (tr * 128 + ch * 16) ^ ((tr & 7) << 4);
                *reinterpret_cast<short8v*>((char*)k_lds + byte) = kv;
                short8v vv = *reinterpret_cast<const short8v*>(vs + ch * 8);
#pragma unroll
                for (int j = 0; j < 8; j++) {
                    int dh = ch * 8 + j;
                    int vbyte = (dh * 128 + tr * 2) ^ ((dh & 7) << 4);
                    *reinterpret_cast<unsigned short*>((char*)vt_lds + vbyte) =
                        (unsigned short)vv[j];
                }
            }
        }
        __syncthreads();

        f32x4 s_[4];
#pragma unroll
        for (int nb = 0; nb < 4; nb++) s_[nb] = (f32x4){0.f, 0.f, 0.f, 0.f};
#pragma unroll
        for (int nb = 0; nb < 4; nb++) {
            int kil = nb * 16 + c;
#pragma unroll
            for (int kb = 0; kb < 2; kb++) {
                int byte = (kil * 128 + kb * 64 + g * 16) ^ ((kil & 7) << 4);
                short8v bk = *reinterpret_cast<short8v*>((char*)k_lds + byte);
                s_[nb] = __builtin_amdgcn_mfma_f32_16x16x32_bf16(aq[kb], bk, s_[nb], 0, 0, 0);
            }
        }
#pragma unroll
        for (int nb = 0; nb < 4; nb++) {
#pragma unroll
            for (int r = 0; r < 4; r++) {
                float sv = s_[nb][r] * 0.125f;
                if (diag) {
                    int qrl = wid * 16 + g * 4 + r;
                    int kcl = nb * 16 + c;
                    if (qrl < kcl) sv = -3.4e38f;
                }
                s_[nb][r] = sv;
            }
        }
#pragma unroll
        for (int r = 0; r < 4; r++) {
            float mx = fmaxf(fmaxf(s_[0][r], s_[1][r]), fmaxf(s_[2][r], s_[3][r]));
#pragma unroll
            for (int off = 1; off <= 8; off <<= 1)
                mx = fmaxf(mx, __shfl_xor(mx, off, 64));
            float mn = fmaxf(m_[r], mx);
            float es = __expf(m_[r] - mn);
            m_[r] = mn;
            float pv[4];
            float rs = 0.f;
#pragma unroll
            for (int nb = 0; nb < 4; nb++) {
                pv[nb] = __expf(s_[nb][r] - mn);
                rs += pv[nb];
            }
#pragma unroll
            for (int off = 1; off <= 8; off <<= 1)
                rs += __shfl_xor(rs, off, 64);
            l_[r] = l_[r] * es + rs;
#pragma unroll
            for (int nb = 0; nb < 4; nb++) o_[nb][r] *= es;
            int qrl = g * 4 + r;
            int swz = (qrl & 7) << 4;
#pragma unroll
            for (int nb = 0; nb < 4; nb++) {
                int byte = (qrl * 128 + (nb * 16 + c) * 2) ^ swz;
                *reinterpret_cast<unsigned short*>((char*)pbuf + byte) = f2bf(pv[nb]);
            }
        }
        short8v aP[2];
#pragma unroll
        for (int kb = 0; kb < 2; kb++) {
            int byte = (c * 128 + kb * 64 + g * 16) ^ ((c & 7) << 4);
            aP[kb] = *reinterpret_cast<short8v*>((char*)pbuf + byte);
        }
#pragma unroll
        for (int nb = 0; nb < 4; nb++) {
            int dh = nb * 16 + c;
#pragma unroll
            for (int kb = 0; kb < 2; kb++) {
                int byte = (dh * 128 + kb * 64 + g * 16) ^ ((dh & 7) << 4);
                short8v bv = *reinterpret_cast<short8v*>((char*)vt_lds + byte);
                o_[nb] = __builtin_amdgcn_mfma_f32_16x16x32_bf16(aP[kb], bv, o_[nb], 0, 0, 0);
            }
        }
    }

    float inv_[4];
#pragma unroll
    for (int r = 0; r < 4; r++) inv_[r] = 1.f / l_[r];
#pragma unroll
    for (int nb = 0; nb < 4; nb++) {
        int col = h * DH + nb * 16 + c;
#pragma unroll
        for (int r = 0; r < 4; r++) {
            int row = q0 + wid * 16 + g * 4 + r;
            O[((size_t)b * Nn + row) * Cc + col] = f2bf(o_[nb][r] * inv_[r]);
        }
    }
}

// fat2: attn (blocks [0,640)) + pack_proj (1536) + pack_gate (6144) + pack_up (6144)
__global__ __launch_bounds__(256)
void fat2(const unsigned short* __restrict__ Qg, const unsigned short* __restrict__ Kg,
          const unsigned short* __restrict__ Vg, unsigned short* __restrict__ O,
          const float* __restrict__ proj_w, unsigned short* __restrict__ proj_p,
          const float* __restrict__ gate_w, unsigned short* __restrict__ gate_p,
          const float* __restrict__ up_w,   unsigned short* __restrict__ up_p) {
    __shared__ __align__(16) unsigned short k_lds[64 * 64];
    __shared__ __align__(16) unsigned short vt_lds[64 * 64];
    __shared__ __align__(16) unsigned short p_lds[4 * 16 * 64];
    int bid = blockIdx.x;
    if (bid < 640) {
        attn_dev(Qg, Kg, Vg, O, bid % 20, bid / 20, k_lds, vt_lds, p_lds);
        return;
    }
    bid -= 640;
    if (bid < 1536) {
        pack_dev(proj_w, proj_p, Cc, Cc, (size_t)bid * 256 + threadIdx.x);
        return;
    }
    bid -= 1536;
    if (bid < 6144) {
        pack_dev(gate_w, gate_p, Cc, Ii, (size_t)bid * 256 + threadIdx.x);
        return;
    }
    bid -= 6144;
    pack_dev(up_w, up_p, Cc, Ii, (size_t)bid * 256 + threadIdx.x);
}

// ---------------------------------------------------------------------------
// bf16 MFMA GEMM v5: 128x128 tile, BK=32, 4 waves 2x2 (wave = 64x64, 4x4
// acc), packed-B, 2-DEEP register prefetch (loads for kt+2 issued at step kt
// — window ~1.5 steps covers HBM latency). Loop unrolled x2 with named
// register sets (no runtime indexing -> no scratch).
// OUTMODE: 0 = f32 out, 1 = bf16 out.  NZ: split-K; partial z at z*Mrows*Nd.
// ---------------------------------------------------------------------------
template <int OUTMODE, bool BIAS, int NZ>
__global__ __launch_bounds__(256, 2)
void gemm128r(const unsigned short* __restrict__ A,
              const unsigned short* __restrict__ PB,
              const float* __restrict__ bias, void* __restrict__ outp,
              int K, int Nd) {
    __shared__ __align__(16) unsigned short lds[8192];   // A 8KB | B 8KB
    int bx = blockIdx.x, by = blockIdx.y, bz = (NZ > 1) ? blockIdx.z : 0;
    {
        int gx = gridDim.x, gy = gridDim.y, gz = (NZ > 1) ? gridDim.z : 1;
        int lin = bx + gx * (by + gy * bz);
        int swz = xcd_swz(lin, gx * gy * gz);
        bx = swz % gx; swz /= gx;
        by = swz % gy; bz = swz / gy;
    }
    int rb = bx * 128, cb = by;
    int seg = segof(rb % Nn);
    int tid = threadIdx.x, lane = tid & 63, wid = tid >> 6;
    int wr = wid >> 1, wc = wid & 1;
    int g = lane >> 4, c_ = lane & 15;
    const int nct = Nd >> 7;
    const int Keff = K / NZ;
    const int nKt = Keff >> 5;                  // even (>= 16) for all call sites
    const int kz = bz * Keff;
    const unsigned short* PBseg = PB + (size_t)seg * K * Nd;

    int mf0 = tid >> 6, lc0 = tid & 63;
    const unsigned short* pA0 =
        A + (size_t)(rb + mf0 * 16 + (lc0 & 15)) * K + kz + (lc0 >> 4) * 8;
    const unsigned short* pA1 = pA0 + (size_t)64 * K;
    const unsigned short* pB0 =
        PBseg + (((size_t)(kz >> 5) * nct + cb) * 8 + mf0) * 512 + (size_t)lc0 * 8;
    const unsigned short* pB1 = pB0 + 2048;
    const size_t bstep = (size_t)nct * 4096;   // shorts per K-step

    f32x4 acc[4][4];
#pragma unroll
    for (int m = 0; m < 4; m++)
#pragma unroll
        for (int n = 0; n < 4; n++) acc[m][n] = (f32x4){0.f, 0.f, 0.f, 0.f};

    short8v avA0, avA1, bvA0, bvA1;             // even set
    short8v avB0, avB1, bvB0, bvB1;             // odd set
    // prologue: load kt=0 (set A) and kt=1 (set B)
    avA0 = *reinterpret_cast<const short8v*>(pA0);
    avA1 = *reinterpret_cast<const short8v*>(pA1);
    bvA0 = *reinterpret_cast<const short8v*>(pB0);
    bvA1 = *reinterpret_cast<const short8v*>(pB1);
    pA0 += 32; pA1 += 32; pB0 += bstep; pB1 += bstep;
    avB0 = *reinterpret_cast<const short8v*>(pA0);
    avB1 = *reinterpret_cast<const short8v*>(pA1);
    bvB0 = *reinterpret_cast<const short8v*>(pB0);
    bvB1 = *reinterpret_cast<const short8v*>(pB1);
    pA0 += 32; pA1 += 32; pB0 += bstep; pB1 += bstep;

    auto compute = [&]() {
        short8v afr[4], bfr[4];
#pragma unroll
        for (int m = 0; m < 4; m++)
            afr[m] = *reinterpret_cast<short8v*>(&lds[((wr * 4 + m) * 64 + lane) * 8]);
#pragma unroll
        for (int n = 0; n < 4; n++)
            bfr[n] = *reinterpret_cast<short8v*>(&lds[4096 + ((wc * 4 + n) * 64 + lane) * 8]);
#pragma unroll
        for (int m = 0; m < 4; m++)
#pragma unroll
            for (int n = 0; n < 4; n++)
                acc[m][n] = __builtin_amdgcn_mfma_f32_16x16x32_bf16(
                    afr[m], bfr[n], acc[m][n], 0, 0, 0);
    };

    for (int kt = 0; kt < nKt; kt += 2) {
        // even step (set A)
        __syncthreads();
        *reinterpret_cast<short8v*>(&lds[(size_t)tid * 8]) = avA0;
        *reinterpret_cast<short8v*>(&lds[(size_t)(tid + 256) * 8]) = avA1;
        *reinterpret_cast<short8v*>(&lds[4096 + (size_t)tid * 8]) = bvA0;
        *reinterpret_cast<short8v*>(&lds[4096 + (size_t)(tid + 256) * 8]) = bvA1;
        __syncthreads();
        if (kt + 2 < nKt) {
            avA0 = *reinterpret_cast<const short8v*>(pA0);
            avA1 = *reinterpret_cast<const short8v*>(pA1);
            bvA0 = *reinterpret_cast<const short8v*>(pB0);
            bvA1 = *reinterpret_cast<const short8v*>(pB1);
            pA0 += 32; pA1 += 32; pB0 += bstep; pB1 += bstep;
        }
        compute();
        // odd step (set B)
        __syncthreads();
        *reinterpret_cast<short8v*>(&lds[(size_t)tid * 8]) = avB0;
        *reinterpret_cast<short8v*>(&lds[(size_t)(tid + 256) * 8]) = avB1;
        *reinterpret_cast<short8v*>(&lds[4096 + (size_t)tid * 8]) = bvB0;
        *reinterpret_cast<short8v*>(&lds[4096 + (size_t)(tid + 256) * 8]) = bvB1;
        __syncthreads();
        if (kt + 3 < nKt) {
            avB0 = *reinterpret_cast<const short8v*>(pA0);
            avB1 = *reinterpret_cast<const short8v*>(pA1);
            bvB0 = *reinterpret_cast<const short8v*>(pB0);
            bvB1 = *reinterpret_cast<const short8v*>(pB1);
            pA0 += 32; pA1 += 32; pB0 += bstep; pB1 += bstep;
        }
        compute();
    }

    float* outf = (float*)outp;
    unsigned short* outh = (unsigned short*)outp;
    size_t zoff = (NZ > 1) ? (size_t)bz * Mrows * Nd : 0;
#pragma unroll
    for (int n = 0; n < 4; n++) {
        int col = cb * 128 + wc * 64 + n * 16 + c_;
        float bvv = BIAS ? bias[(size_t)seg * Nd + col] : 0.f;
#pragma unroll
        for (int m = 0; m < 4; m++) {
#pragma unroll
            for (int r = 0; r < 4; r++) {
                int row = rb + wr * 64 + m * 16 + g * 4 + r;
                float v = acc[m][n][r] + bvv;
                if (OUTMODE == 0) outf[zoff + (size_t)row * Nd + col] = v;
                else              outh[zoff + (size_t)row * Nd + col] = f2bf(v);
            }
        }
    }
}

// ---------------------------------------------------------------------------
// Fused gate+up GEMM v5: 64x128 tile, BK=32, 4 waves 1x4 (wave = 64x32 per
// operand pair), 8 ds_read_b128 per 16 MFMA, 2-DEEP register prefetch with
// pointer-bumped addresses. K=Cc, Nd=Ii.
// ---------------------------------------------------------------------------
__global__ __launch_bounds__(256)
void gemm_gu(const unsigned short* __restrict__ A,
             const unsigned short* __restrict__ PG,
             const unsigned short* __restrict__ PU,
             unsigned short* __restrict__ outp) {
    __shared__ __align__(16) unsigned short lds[10240];  // A 4KB | G 8KB | U 8KB
    int bx = blockIdx.x, by = blockIdx.y;
    {
        int lin = bx + gridDim.x * by;
        int swz = xcd_swz(lin, gridDim.x * gridDim.y);
        bx = swz % gridDim.x; by = swz / gridDim.x;
    }
    int rb = bx * 64, cb = by;
    int seg = segof(rb % Nn);
    int tid = threadIdx.x, lane = tid & 63, wid = tid >> 6;
    int g = lane >> 4, c_ = lane & 15;
    const int nct = Ii >> 7;                    // 32
    const unsigned short* PGseg = PG + (size_t)seg * Cc * Ii;
    const unsigned short* PUseg = PU + (size_t)seg * Cc * Ii;

    f32x4 accG[4][2], accU[4][2];
#pragma unroll
    for (int m = 0; m < 4; m++)
#pragma unroll
        for (int n = 0; n < 2; n++) {
            accG[m][n] = (f32x4){0.f, 0.f, 0.f, 0.f};
            accU[m][n] = (f32x4){0.f, 0.f, 0.f, 0.f};
        }

    int mf0 = tid >> 6, lc0 = tid & 63;
    const unsigned short* pA =
        A + (size_t)(rb + mf0 * 16 + (lc0 & 15)) * Cc + (lc0 >> 4) * 8;
    size_t boff = ((size_t)cb * 8 + mf0) * 512 + (size_t)lc0 * 8;
    const unsigned short* pG0 = PGseg + boff;
    const unsigned short* pG1 = pG0 + 2048;     // chunk cf+4
    const unsigned short* pU0 = PUseg + boff;
    const unsigned short* pU1 = pU0 + 2048;
    const size_t bstep = (size_t)nct * 4096;    // shorts per K-step

    short8v avA, gvA0, gvA1, uvA0, uvA1;        // even set
    short8v avB, gvB0, gvB1, uvB0, uvB1;        // odd set
    avA  = *reinterpret_cast<const short8v*>(pA);
    gvA0 = *reinterpret_cast<const short8v*>(pG0);
    gvA1 = *reinterpret_cast<const short8v*>(pG1);
    uvA0 = *reinterpret_cast<const short8v*>(pU0);
    uvA1 = *reinterpret_cast<const short8v*>(pU1);
    pA += 32; pG0 += bstep; pG1 += bstep; pU0 += bstep; pU1 += bstep;
    avB  = *reinterpret_cast<const short8v*>(pA);
    gvB0 = *reinterpret_cast<const short8v*>(pG0);
    gvB1 = *reinterpret_cast<const short8v*>(pG1);
    uvB0 = *reinterpret_cast<const short8v*>(pU0);
    uvB1 = *reinterpret_cast<const short8v*>(pU1);
    pA += 32; pG0 += bstep; pG1 += bstep; pU0 += bstep; pU1 += bstep;

    auto compute = [&]() {
        short8v afr[4], gfr[2], ufr[2];
#pragma unroll
        for (int m = 0; m < 4; m++)
            afr[m] = *reinterpret_cast<short8v*>(&lds[((m) * 64 + lane) * 8]);
#pragma unroll
        for (int n = 0; n < 2; n++) {
            gfr[n] = *reinterpret_cast<short8v*>(&lds[2048 + ((wid * 2 + n) * 64 + lane) * 8]);
            ufr[n] = *reinterpret_cast<short8v*>(&lds[6144 + ((wid * 2 + n) * 64 + lane) * 8]);
        }
#pragma unroll
        for (int m = 0; m < 4; m++)
#pragma unroll
            for (int n = 0; n < 2; n++) {
                accG[m][n] = __builtin_amdgcn_mfma_f32_16x16x32_bf16(
                    afr[m], gfr[n], accG[m][n], 0, 0, 0);
                accU[m][n] = __builtin_amdgcn_mfma_f32_16x16x32_bf16(
                    afr[m], ufr[n], accU[m][n], 0, 0, 0);
            }
    };

    const int nKt = Cc >> 5;                    // 32 (even)
    for (int kt = 0; kt < nKt; kt += 2) {
        // even step (set A)
        __syncthreads();
        *reinterpret_cast<short8v*>(&lds[(size_t)tid * 8]) = avA;
        *reinterpret_cast<short8v*>(&lds[2048 + (size_t)tid * 8]) = gvA0;
        *reinterpret_cast<short8v*>(&lds[2048 + (size_t)(tid + 256) * 8]) = gvA1;
        *reinterpret_cast<short8v*>(&lds[6144 + (size_t)tid * 8]) = uvA0;
        *reinterpret_cast<short8v*>(&lds[6144 + (size_t)(tid + 256) * 8]) = uvA1;
        __syncthreads();
        if (kt + 2 < nKt) {
            avA  = *reinterpret_cast<const short8v*>(pA);
            gvA0 = *reinterpret_cast<const short8v*>(pG0);
            gvA1 = *reinterpret_cast<const short8v*>(pG1);
            uvA0 = *reinterpret_cast<const short8v*>(pU0);
            uvA1 = *reinterpret_cast<const short8v*>(pU1);
            pA += 32; pG0 += bstep; pG1 += bstep; pU0 += bstep; pU1 += bstep;
        }
        compute();
        // odd step (set B)
        __syncthreads();
        *reinterpret_cast<short8v*>(&lds[(size_t)tid * 8]) = avB;
        *reinterpret_cast<short8v*>(&lds[2048 + (size_t)tid * 8]) = gvB0;
        *reinterpret_cast<short8v*>(&lds[2048 + (size_t)(tid + 256) * 8]) = gvB1;
        *reinterpret_cast<short8v*>(&lds[6144 + (size_t)tid * 8]) = uvB0;
        *reinterpret_cast<short8v*>(&lds[6144 + (size_t)(tid + 256) * 8]) = uvB1;
        __syncthreads();
        if (kt + 3 < nKt) {
            avB  = *reinterpret_cast<const short8v*>(pA);
            gvB0 = *reinterpret_cast<const short8v*>(pG0);
            gvB1 = *reinterpret_cast<const short8v*>(pG1);
            uvB0 = *reinterpret_cast<const short8v*>(pU0);
            uvB1 = *reinterpret_cast<const short8v*>(pU1);
            pA += 32; pG0 += bstep; pG1 += bstep; pU0 += bstep; pU1 += bstep;
        }
        compute();
    }

    // epilogue: t = silu(g) * u ; wave writes its 64-row x 32-col slice
#pragma unroll
    for (int n = 0; n < 2; n++) {
        int col = cb * 128 + (wid * 2 + n) * 16 + c_;
#pragma unroll
        for (int m = 0; m < 4; m++) {
#pragma unroll
            for (int r = 0; r < 4; r++) {
                int row = rb + m * 16 + g * 4 + r;
                float gval = accG[m][n][r], uval = accU[m][n][r];
                float t = gval / (1.f + __expf(-gval)) * uval;
                outp[(size_t)row * Ii + col] = f2bf(t);
            }
        }
    }
}

// ---------------------------------------------------------------------------
// fused proj-combine + RMSNorm2: h = x + bias + p0 + p1 -> out (fp32),
// y = RMS(h, ln2) -> bf16. One block per row (2560 blocks, 256 thr).
// ---------------------------------------------------------------------------
__global__ __launch_bounds__(256)
void combine_rms(const float* __restrict__ x, const float* __restrict__ bias,
                 const float* __restrict__ p, const float* __restrict__ ln2_w,
                 float* __restrict__ out, unsigned short* __restrict__ y) {
    int row = blockIdx.x;
    int n   = row % Nn;
    int seg = segof(n);
    int t   = threadIdx.x;
    size_t i = (size_t)row * 256 + t;           // float4 index
    float4 a  = reinterpret_cast<const float4*>(x)[i];
    float4 b  = *reinterpret_cast<const float4*>(&bias[(size_t)seg * Cc + t * 4]);
    float4 p0 = reinterpret_cast<const float4*>(p)[i];
    float4 p1 = reinterpret_cast<const float4*>(p)[i + Mrows * Cc / 4];
    float4 h;
    h.x = a.x + b.x + p0.x + p1.x;
    h.y = a.y + b.y + p0.y + p1.y;
    h.z = a.z + b.z + p0.z + p1.z;
    h.w = a.w + b.w + p0.w + p1.w;
    reinterpret_cast<float4*>(out)[i] = h;
    float ss = h.x * h.x + h.y * h.y + h.z * h.z + h.w * h.w;
#pragma unroll
    for (int off = 32; off; off >>= 1) ss += __shfl_down(ss, off, 64);
    __shared__ float sred[5];
    int lane = t & 63, wid = t >> 6;
    if (lane == 0) sred[wid] = ss;
    __syncthreads();
    if (t == 0) sred[4] = rsqrtf((sred[0] + sred[1] + sred[2] + sred[3]) * (1.0f / Cc) + 1e-6f);
    __syncthreads();
    float r = sred[4];
    float4 wv = reinterpret_cast<const float4*>(ln2_w + (size_t)seg * Cc)[t];
    ushort4 ov;
    ov.x = f2bf(wv.x * h.x * r);
    ov.y = f2bf(wv.y * h.y * r);
    ov.z = f2bf(wv.z * h.z * r);
    ov.w = f2bf(wv.w * h.w * r);
    *reinterpret_cast<ushort4*>(&y[(size_t)row * Cc + t * 4]) = ov;
}

// ---------------------------------------------------------------------------
// down combine: out = h(out) + sum_z bf2f(p_z)    (bf16 partials, NZ=4)
// ---------------------------------------------------------------------------
__global__ __launch_bounds__(256)
void combine_down4(const unsigned short* __restrict__ p,
                   float* __restrict__ out) {
    int i = blockIdx.x * 256 + threadIdx.x;
    float4 a = reinterpret_cast<const float4*>(out)[i];
#pragma unroll
    for (int z = 0; z < 4; z++) {
        ushort4 u = *reinterpret_cast<const ushort4*>(&p[(size_t)z * Mrows * Cc + i * 4]);
        a.x += bf2f(u.x); a.y += bf2f(u.y); a.z += bf2f(u.z); a.w += bf2f(u.w);
    }
    reinterpret_cast<float4*>(out)[i] = a;
}

// ---------------------------------------------------------------------------
// Split qkv(bf16) + per-head q/k RMSNorm + RoPE -> bf16 Q,K,V (bh, n, dh)
// ---------------------------------------------------------------------------
__global__ __launch_bounds__(256)
void split_rope(const unsigned short* __restrict__ qkv,
                const float* __restrict__ qn_w, const float* __restrict__ kn_w,
                const int* __restrict__ pos_ids, const int* __restrict__ tpos_ids,
                unsigned short* __restrict__ Q, unsigned short* __restrict__ K,
                unsigned short* __restrict__ V) {
    int row = blockIdx.x;
    int b = row / Nn, n = row % Nn;
    int seg = segof(n);
    int lane = threadIdx.x & 63, wid = threadIdx.x >> 6;
    int pos = (n < Tt) ? tpos_ids[n] : pos_ids[n - Tt];
    int j = lane & 31;
    float ang = (float)pos * exp2f(-(float)j * (13.287712379549449f / 32.f));
    float cv = cosf(ang), sv = sinf(ang);
    float qw = qn_w[seg * DH + lane], kw = kn_w[seg * DH + lane];
    for (int h = wid; h < Hh; h += 4) {
        const unsigned short* base = qkv + (size_t)row * (3 * Cc) + h * DH + lane;
        float q = bf2f(base[0]), k = bf2f(base[Cc]), v = bf2f(base[2 * Cc]);
        float qs = q * q, ks = k * k;
#pragma unroll
        for (int off = 32; off; off >>= 1) {
            qs += __shfl_xor(qs, off, 64);
            ks += __shfl_xor(ks, off, 64);
        }
        q = q * rsqrtf(qs * (1.f / DH) + 1e-6f) * qw;
        k = k * rsqrtf(ks * (1.f / DH) + 1e-6f) * kw;
        float qp = __shfl_xor(q, 32, 64);
        float kp = __shfl_xor(k, 32, 64);
        float qo = q * cv + ((lane < 32) ? -qp * sv : qp * sv);
        float ko = k * cv + ((lane < 32) ? -kp * sv : kp * sv);
        size_t oidx = ((size_t)(b * Hh + h) * Nn + n) * DH + lane;
        Q[oidx] = f2bf(qo);
        K[oidx] = f2bf(ko);
        V[oidx] = f2bf(v);
    }
}

// ---------------------------------------------------------------------------
// kernel_launch
// ---------------------------------------------------------------------------
extern "C" void kernel_launch(void* const* d_in, const int* in_sizes, int n_in,
                              void* d_out, int out_size, void* d_ws, size_t ws_size,
                              hipStream_t stream) {
    const float* x        = (const float*)d_in[0];
    const int*   pos_ids  = (const int*)d_in[1];
    const int*   tpos_ids = (const int*)d_in[2];
    const float* qkv_w    = (const float*)d_in[3];
    const float* qkv_b    = (const float*)d_in[4];
    const float* proj_w   = (const float*)d_in[5];
    const float* proj_b   = (const float*)d_in[6];
    const float* qn_w     = (const float*)d_in[7];
    const float* kn_w     = (const float*)d_in[8];
    const float* ln1_w    = (const float*)d_in[9];
    const float* ln2_w    = (const float*)d_in[10];
    const float* gate_w   = (const float*)d_in[11];
    const float* up_w     = (const float*)d_in[12];
    const float* down_w   = (const float*)d_in[13];
    float* out = (float*)d_out;                 // also used as h buffer
    char*  wsb = (char*)d_ws;

    // workspace (bytes), total 82,837,504
    unsigned short* WA  = (unsigned short*)(wsb);               // 25,165,824
    unsigned short* WB  = (unsigned short*)(wsb + 25165824);    // 25,165,824
    unsigned short* Tb  = (unsigned short*)(wsb + 50331648);    // 20,971,520
    unsigned short* P3  = (unsigned short*)(wsb + 71303168);    //  5,242,880
    unsigned short* P4  = (unsigned short*)(wsb + 76546048);    //  6,291,456
    unsigned short* Qbf = Tb;
    unsigned short* Kbf = Tb + 2621440;
    unsigned short* Vbf = Tb + 5242880;

    // 1. fat1: xn = RMS(x, ln1) -> P3  ||  pack qkv_w -> WA
    fat1<<<Mrows + 4608, 256, 0, stream>>>(x, ln1_w, P3, qkv_w, WA);
    // 2. qkv = xn @ qkv_w + qkv_b -> bf16 (WB)
    gemm128r<1, true, 1><<<dim3(Mrows / 128, 24), 256, 0, stream>>>(
        P3, WA, qkv_b, WB, Cc, 3 * Cc);
    // 3. split + q/k RMS + RoPE -> Q,K,V (Tb)
    split_rope<<<Mrows, 256, 0, stream>>>(WB, qn_w, kn_w, pos_ids, tpos_ids,
                                          Qbf, Kbf, Vbf);
    // 4. fat2: attn -> P3  ||  pack proj -> P4, gate -> WA, up -> WB
    fat2<<<640 + 1536 + 6144 + 6144, 256, 0, stream>>>(
        Qbf, Kbf, Vbf, P3, proj_w, P4, gate_w, WA, up_w, WB);
    // 5. proj split-K=2 -> fp32 partials (Tb); fused combine+rms2 -> out, P3
    gemm128r<0, false, 2><<<dim3(Mrows / 128, 8, 2), 256, 0, stream>>>(
        P3, P4, nullptr, (float*)Tb, Cc, Cc);
    combine_rms<<<Mrows, 256, 0, stream>>>(x, proj_b, (float*)Tb, ln2_w, out, P3);
    // 6. fused: t = silu(y@gate) * (y@up) -> Tb   (1280 blocks, 1x4 waves)
    gemm_gu<<<dim3(Mrows / 64, 32), 256, 0, stream>>>(P3, WA, WB, Tb);
    // 7. pack down_w -> WA (gate dead); down split-K=4 -> bf16 partials (WB)
    pack_w<<<6144, 256, 0, stream>>>(down_w, WA, Ii, Cc);
    gemm128r<1, false, 4><<<dim3(Mrows / 128, 8, 4), 256, 0, stream>>>(
        Tb, WA, nullptr, WB, Ii, Cc);
    combine_down4<<<Mrows * Cc / 1024, 256, 0, stream>>>(WB, out);
}

// Round 15
// 242.119 us; speedup vs baseline: 1.2358x; 1.0153x over previous
//
#include <hip/hip_runtime.h>
#include <math.h>

// Problem constants (fixed by setup_inputs)
constexpr int Bb  = 2;
constexpr int Nn  = 1280;
constexpr int Cc  = 1024;
constexpr int Hh  = 16;
constexpr int DH  = 64;
constexpr int Ii  = 4096;
constexpr int Tt  = 256;    // text_len
constexpr int BSz = 128;    // block_size
constexpr int L1  = 4;      // len1
constexpr int Mrows = Bb * Nn;  // 2560

typedef __attribute__((ext_vector_type(8))) short short8v;
typedef __attribute__((ext_vector_type(4))) float f32x4;

__device__ __forceinline__ int segof(int n) {
    return n < Tt ? 0 : (n < Tt + L1 * BSz ? 1 : 2);
}
__device__ __forceinline__ unsigned short f2bf(float f) {
    unsigned int u = __float_as_uint(f);
    u += 0x7fffu + ((u >> 16) & 1u);        // RNE
    return (unsigned short)(u >> 16);
}
__device__ __forceinline__ float bf2f(unsigned short h) {
    return __uint_as_float(((unsigned int)h) << 16);
}

// bijective XCD swizzle for nwg % 8 == 0
__device__ __forceinline__ int xcd_swz(int lin, int nwg) {
    int cpx = nwg >> 3;
    return (lin & 7) * cpx + (lin >> 3);
}

// ---------------------------------------------------------------------------
// device bodies: RMSNorm and weight-pack (used by fat kernels + standalone)
// ---------------------------------------------------------------------------
__device__ __forceinline__ void rms_dev(const float* __restrict__ in,
                                        const float* __restrict__ w,
                                        unsigned short* __restrict__ out,
                                        int row, float* sred) {
    int n   = row % Nn;
    int seg = segof(n);
    const float* x = in + (size_t)row * Cc;
    int t = threadIdx.x;
    float4 xv = reinterpret_cast<const float4*>(x)[t];
    float ss = xv.x * xv.x + xv.y * xv.y + xv.z * xv.z + xv.w * xv.w;
#pragma unroll
    for (int off = 32; off; off >>= 1) ss += __shfl_down(ss, off, 64);
    int lane = t & 63, wid = t >> 6;
    if (lane == 0) sred[wid] = ss;
    __syncthreads();
    if (t == 0) sred[4] = rsqrtf((sred[0] + sred[1] + sred[2] + sred[3]) * (1.0f / Cc) + 1e-6f);
    __syncthreads();
    float r = sred[4];
    float4 wv = reinterpret_cast<const float4*>(w + (size_t)seg * Cc)[t];
    ushort4 ov;
    ov.x = f2bf(wv.x * xv.x * r);
    ov.y = f2bf(wv.y * xv.y * r);
    ov.z = f2bf(wv.z * xv.z * r);
    ov.w = f2bf(wv.w * xv.w * r);
    *reinterpret_cast<ushort4*>(&out[(size_t)row * Cc + t * 4]) = ov;
}

// pack fp32 [3][K][Nd] -> fragment-linear bf16 chunks; one chunk per thread
__device__ __forceinline__ void pack_dev(const float* __restrict__ W,
                                         unsigned short* __restrict__ PB,
                                         int K, int Nd, size_t idx) {
    size_t cpseg = (size_t)K * Nd / 8;
    int s = (int)(idx / cpseg);
    size_t rm = idx % cpseg;
    int lane = (int)(rm & 63);
    int fr   = (int)((rm >> 6) & 7);
    size_t tile = rm >> 9;                  // kt32*(Nd/128)+cb
    int nct = Nd >> 7;
    int cb = (int)(tile % nct);
    int kt = (int)(tile / nct);
    int col = cb * 128 + fr * 16 + (lane & 15);
    int k0  = kt * 32 + (lane >> 4) * 8;
    const float* src = W + ((size_t)s * K + k0) * Nd + col;
    unsigned short o[8];
#pragma unroll
    for (int j = 0; j < 8; j++) o[j] = f2bf(src[(size_t)j * Nd]);
    short8v v;
#pragma unroll
    for (int j = 0; j < 8; j++) v[j] = (short)o[j];
    *reinterpret_cast<short8v*>(&PB[idx * 8]) = v;
}

// ---------------------------------------------------------------------------
// standalone pack kernel (down weights)
// ---------------------------------------------------------------------------
__global__ __launch_bounds__(256)
void pack_w(const float* __restrict__ W, unsigned short* __restrict__ PB,
            int K, int Nd) {
    pack_dev(W, PB, K, Nd, (size_t)blockIdx.x * 256 + threadIdx.x);
}

// fat1: rms1 (blocks [0, Mrows)) + pack_qkv (rest)
__global__ __launch_bounds__(256)
void fat1(const float* __restrict__ x, const float* __restrict__ ln1_w,
          unsigned short* __restrict__ xn,
          const float* __restrict__ qkv_w, unsigned short* __restrict__ qkv_p) {
    __shared__ float sred[5];
    int bid = blockIdx.x;
    if (bid < Mrows) {
        rms_dev(x, ln1_w, xn, bid, sred);
    } else {
        pack_dev(qkv_w, qkv_p, Cc, 3 * Cc, (size_t)(bid - Mrows) * 256 + threadIdx.x);
    }
}

// ---------------------------------------------------------------------------
// MFMA flash attention body (verified round 5-14 structure) + T5 setprio
// around MFMA clusters (fat2 co-schedules attn with pack waves -> role split)
// ---------------------------------------------------------------------------
__device__ __forceinline__ void attn_dev(
        const unsigned short* __restrict__ Qg, const unsigned short* __restrict__ Kg,
        const unsigned short* __restrict__ Vg, unsigned short* __restrict__ O,
        int qt, int bh,
        unsigned short* k_lds, unsigned short* vt_lds, unsigned short* p_base) {
    int b = bh >> 4, h = bh & 15;
    int tid = threadIdx.x, lane = tid & 63, wid = tid >> 6;
    int g = lane >> 4, c = lane & 15;

    const size_t headoff = (size_t)bh * Nn * DH;
    int q0 = qt * 64;
    bool qtext = q0 < Tt;
    int qb = qtext ? 0 : (q0 - Tt) / BSz;

    int qrow_frag = q0 + wid * 16 + c;
    short8v aq[2];
#pragma unroll
    for (int kb = 0; kb < 2; kb++)
        aq[kb] = *reinterpret_cast<const short8v*>(
            &Qg[headoff + (size_t)qrow_frag * DH + kb * 32 + g * 8]);

    unsigned short* pbuf = p_base + wid * 1024;

    f32x4 o_[4];
#pragma unroll
    for (int nb = 0; nb < 4; nb++) o_[nb] = (f32x4){0.f, 0.f, 0.f, 0.f};
    float m_[4] = {-3.4e38f, -3.4e38f, -3.4e38f, -3.4e38f};
    float l_[4] = {0.f, 0.f, 0.f, 0.f};

    int tr = tid >> 2, tc = tid & 3;

    for (int kt = 0; kt < Nn / 64; kt++) {
        int kbase = kt * 64;
        bool vis, diag = false;
        if (qtext) {
            vis = (kbase <= q0);
            diag = (kbase == q0);
        } else if (kbase < Tt) {
            vis = true;
        } else {
            int kb = (kbase - Tt) / BSz;
            vis = (qb < L1) ? (kb <= qb)
                            : ((kb < L1 && qb - L1 > kb) || kb == qb);
        }
        if (!vis) continue;

        __syncthreads();
        {
            const unsigned short* ks = &Kg[headoff + (size_t)(kbase + tr) * DH];
            const unsigned short* vs = &Vg[headoff + (size_t)(kbase + tr) * DH];
#pragma unroll
            for (int i = 0; i < 2; i++) {
                int ch = tc + i * 4;
                short8v kv = *reinterpret_cast<const short8v*>(ks + ch * 8);
                int byte = (tr * 128 + ch * 16) ^ ((tr & 7) << 4);
                *reinterpret_cast<short8v*>((char*)k_lds + byte) = kv;
                short8v vv = *reinterpret_cast<const short8v*>(vs + ch * 8);
#pragma unroll
                for (int j = 0; j < 8; j++) {
                    int dh = ch * 8 + j;
                    int vbyte = (dh * 128 + tr * 2) ^ ((dh & 7) << 4);
                    *reinterpret_cast<unsigned short*>((char*)vt_lds + vbyte) =
                        (unsigned short)vv[j];
                }
            }
        }
        __syncthreads();

        f32x4 s_[4];
#pragma unroll
        for (int nb = 0; nb < 4; nb++) s_[nb] = (f32x4){0.f, 0.f, 0.f, 0.f};
        __builtin_amdgcn_s_setprio(1);
#pragma unroll
        for (int nb = 0; nb < 4; nb++) {
            int kil = nb * 16 + c;
#pragma unroll
            for (int kb = 0; kb < 2; kb++) {
                int byte = (kil * 128 + kb * 64 + g * 16) ^ ((kil & 7) << 4);
                short8v bk = *reinterpret_cast<short8v*>((char*)k_lds + byte);
                s_[nb] = __builtin_amdgcn_mfma_f32_16x16x32_bf16(aq[kb], bk, s_[nb], 0, 0, 0);
            }
        }
        __builtin_amdgcn_s_setprio(0);
#pragma unroll
        for (int nb = 0; nb < 4; nb++) {
#pragma unroll
            for (int r = 0; r < 4; r++) {
                float sv = s_[nb][r] * 0.125f;
                if (diag) {
                    int qrl = wid * 16 + g * 4 + r;
                    int kcl = nb * 16 + c;
                    if (qrl < kcl) sv = -3.4e38f;
                }
                s_[nb][r] = sv;
            }
        }
#pragma unroll
        for (int r = 0; r < 4; r++) {
            float mx = fmaxf(fmaxf(s_[0][r], s_[1][r]), fmaxf(s_[2][r], s_[3][r]));
#pragma unroll
            for (int off = 1; off <= 8; off <<= 1)
                mx = fmaxf(mx, __shfl_xor(mx, off, 64));
            float mn = fmaxf(m_[r], mx);
            float es = __expf(m_[r] - mn);
            m_[r] = mn;
            float pv[4];
            float rs = 0.f;
#pragma unroll
            for (int nb = 0; nb < 4; nb++) {
                pv[nb] = __expf(s_[nb][r] - mn);
                rs += pv[nb];
            }
#pragma unroll
            for (int off = 1; off <= 8; off <<= 1)
                rs += __shfl_xor(rs, off, 64);
            l_[r] = l_[r] * es + rs;
#pragma unroll
            for (int nb = 0; nb < 4; nb++) o_[nb][r] *= es;
            int qrl = g * 4 + r;
            int swz = (qrl & 7) << 4;
#pragma unroll
            for (int nb = 0; nb < 4; nb++) {
                int byte = (qrl * 128 + (nb * 16 + c) * 2) ^ swz;
                *reinterpret_cast<unsigned short*>((char*)pbuf + byte) = f2bf(pv[nb]);
            }
        }
        short8v aP[2];
#pragma unroll
        for (int kb = 0; kb < 2; kb++) {
            int byte = (c * 128 + kb * 64 + g * 16) ^ ((c & 7) << 4);
            aP[kb] = *reinterpret_cast<short8v*>((char*)pbuf + byte);
        }
        __builtin_amdgcn_s_setprio(1);
#pragma unroll
        for (int nb = 0; nb < 4; nb++) {
            int dh = nb * 16 + c;
#pragma unroll
            for (int kb = 0; kb < 2; kb++) {
                int byte = (dh * 128 + kb * 64 + g * 16) ^ ((dh & 7) << 4);
                short8v bv = *reinterpret_cast<short8v*>((char*)vt_lds + byte);
                o_[nb] = __builtin_amdgcn_mfma_f32_16x16x32_bf16(aP[kb], bv, o_[nb], 0, 0, 0);
            }
        }
        __builtin_amdgcn_s_setprio(0);
    }

    float inv_[4];
#pragma unroll
    for (int r = 0; r < 4; r++) inv_[r] = 1.f / l_[r];
#pragma unroll
    for (int nb = 0; nb < 4; nb++) {
        int col = h * DH + nb * 16 + c;
#pragma unroll
        for (int r = 0; r < 4; r++) {
            int row = q0 + wid * 16 + g * 4 + r;
            O[((size_t)b * Nn + row) * Cc + col] = f2bf(o_[nb][r] * inv_[r]);
        }
    }
}

// fat2: attn (blocks [0,640)) + pack_proj (1536) + pack_gate (6144) + pack_up (6144)
__global__ __launch_bounds__(256)
void fat2(const unsigned short* __restrict__ Qg, const unsigned short* __restrict__ Kg,
          const unsigned short* __restrict__ Vg, unsigned short* __restrict__ O,
          const float* __restrict__ proj_w, unsigned short* __restrict__ proj_p,
          const float* __restrict__ gate_w, unsigned short* __restrict__ gate_p,
          const float* __restrict__ up_w,   unsigned short* __restrict__ up_p) {
    __shared__ __align__(16) unsigned short k_lds[64 * 64];
    __shared__ __align__(16) unsigned short vt_lds[64 * 64];
    __shared__ __align__(16) unsigned short p_lds[4 * 16 * 64];
    int bid = blockIdx.x;
    if (bid < 640) {
        attn_dev(Qg, Kg, Vg, O, bid % 20, bid / 20, k_lds, vt_lds, p_lds);
        return;
    }
    bid -= 640;
    if (bid < 1536) {
        pack_dev(proj_w, proj_p, Cc, Cc, (size_t)bid * 256 + threadIdx.x);
        return;
    }
    bid -= 1536;
    if (bid < 6144) {
        pack_dev(gate_w, gate_p, Cc, Ii, (size_t)bid * 256 + threadIdx.x);
        return;
    }
    bid -= 6144;
    pack_dev(up_w, up_p, Cc, Ii, (size_t)bid * 256 + threadIdx.x);
}

// ---------------------------------------------------------------------------
// bf16 MFMA GEMM (round-14, kept): 128x128 tile, BK=32, 4 waves 2x2
// (wave = 64x64, 4x4 acc), packed-B, 2-DEEP register prefetch, x2 unroll
// with named register sets.
// OUTMODE: 0 = f32 out, 1 = bf16 out.  NZ: split-K; partial z at z*Mrows*Nd.
// ---------------------------------------------------------------------------
template <int OUTMODE, bool BIAS, int NZ>
__global__ __launch_bounds__(256, 2)
void gemm128r(const unsigned short* __restrict__ A,
              const unsigned short* __restrict__ PB,
              const float* __restrict__ bias, void* __restrict__ outp,
              int K, int Nd) {
    __shared__ __align__(16) unsigned short lds[8192];   // A 8KB | B 8KB
    int bx = blockIdx.x, by = blockIdx.y, bz = (NZ > 1) ? blockIdx.z : 0;
    {
        int gx = gridDim.x, gy = gridDim.y, gz = (NZ > 1) ? gridDim.z : 1;
        int lin = bx + gx * (by + gy * bz);
        int swz = xcd_swz(lin, gx * gy * gz);
        bx = swz % gx; swz /= gx;
        by = swz % gy; bz = swz / gy;
    }
    int rb = bx * 128, cb = by;
    int seg = segof(rb % Nn);
    int tid = threadIdx.x, lane = tid & 63, wid = tid >> 6;
    int wr = wid >> 1, wc = wid & 1;
    int g = lane >> 4, c_ = lane & 15;
    const int nct = Nd >> 7;
    const int Keff = K / NZ;
    const int nKt = Keff >> 5;                  // even for all call sites
    const int kz = bz * Keff;
    const unsigned short* PBseg = PB + (size_t)seg * K * Nd;

    int mf0 = tid >> 6, lc0 = tid & 63;
    const unsigned short* pA0 =
        A + (size_t)(rb + mf0 * 16 + (lc0 & 15)) * K + kz + (lc0 >> 4) * 8;
    const unsigned short* pA1 = pA0 + (size_t)64 * K;
    const unsigned short* pB0 =
        PBseg + (((size_t)(kz >> 5) * nct + cb) * 8 + mf0) * 512 + (size_t)lc0 * 8;
    const unsigned short* pB1 = pB0 + 2048;
    const size_t bstep = (size_t)nct * 4096;   // shorts per K-step

    f32x4 acc[4][4];
#pragma unroll
    for (int m = 0; m < 4; m++)
#pragma unroll
        for (int n = 0; n < 4; n++) acc[m][n] = (f32x4){0.f, 0.f, 0.f, 0.f};

    short8v avA0, avA1, bvA0, bvA1;             // even set
    short8v avB0, avB1, bvB0, bvB1;             // odd set
    avA0 = *reinterpret_cast<const short8v*>(pA0);
    avA1 = *reinterpret_cast<const short8v*>(pA1);
    bvA0 = *reinterpret_cast<const short8v*>(pB0);
    bvA1 = *reinterpret_cast<const short8v*>(pB1);
    pA0 += 32; pA1 += 32; pB0 += bstep; pB1 += bstep;
    avB0 = *reinterpret_cast<const short8v*>(pA0);
    avB1 = *reinterpret_cast<const short8v*>(pA1);
    bvB0 = *reinterpret_cast<const short8v*>(pB0);
    bvB1 = *reinterpret_cast<const short8v*>(pB1);
    pA0 += 32; pA1 += 32; pB0 += bstep; pB1 += bstep;

    auto compute = [&]() {
        short8v afr[4], bfr[4];
#pragma unroll
        for (int m = 0; m < 4; m++)
            afr[m] = *reinterpret_cast<short8v*>(&lds[((wr * 4 + m) * 64 + lane) * 8]);
#pragma unroll
        for (int n = 0; n < 4; n++)
            bfr[n] = *reinterpret_cast<short8v*>(&lds[4096 + ((wc * 4 + n) * 64 + lane) * 8]);
#pragma unroll
        for (int m = 0; m < 4; m++)
#pragma unroll
            for (int n = 0; n < 4; n++)
                acc[m][n] = __builtin_amdgcn_mfma_f32_16x16x32_bf16(
                    afr[m], bfr[n], acc[m][n], 0, 0, 0);
    };

    for (int kt = 0; kt < nKt; kt += 2) {
        __syncthreads();
        *reinterpret_cast<short8v*>(&lds[(size_t)tid * 8]) = avA0;
        *reinterpret_cast<short8v*>(&lds[(size_t)(tid + 256) * 8]) = avA1;
        *reinterpret_cast<short8v*>(&lds[4096 + (size_t)tid * 8]) = bvA0;
        *reinterpret_cast<short8v*>(&lds[4096 + (size_t)(tid + 256) * 8]) = bvA1;
        __syncthreads();
        if (kt + 2 < nKt) {
            avA0 = *reinterpret_cast<const short8v*>(pA0);
            avA1 = *reinterpret_cast<const short8v*>(pA1);
            bvA0 = *reinterpret_cast<const short8v*>(pB0);
            bvA1 = *reinterpret_cast<const short8v*>(pB1);
            pA0 += 32; pA1 += 32; pB0 += bstep; pB1 += bstep;
        }
        compute();
        __syncthreads();
        *reinterpret_cast<short8v*>(&lds[(size_t)tid * 8]) = avB0;
        *reinterpret_cast<short8v*>(&lds[(size_t)(tid + 256) * 8]) = avB1;
        *reinterpret_cast<short8v*>(&lds[4096 + (size_t)tid * 8]) = bvB0;
        *reinterpret_cast<short8v*>(&lds[4096 + (size_t)(tid + 256) * 8]) = bvB1;
        __syncthreads();
        if (kt + 3 < nKt) {
            avB0 = *reinterpret_cast<const short8v*>(pA0);
            avB1 = *reinterpret_cast<const short8v*>(pA1);
            bvB0 = *reinterpret_cast<const short8v*>(pB0);
            bvB1 = *reinterpret_cast<const short8v*>(pB1);
            pA0 += 32; pA1 += 32; pB0 += bstep; pB1 += bstep;
        }
        compute();
    }

    float* outf = (float*)outp;
    unsigned short* outh = (unsigned short*)outp;
    size_t zoff = (NZ > 1) ? (size_t)bz * Mrows * Nd : 0;
#pragma unroll
    for (int n = 0; n < 4; n++) {
        int col = cb * 128 + wc * 64 + n * 16 + c_;
        float bvv = BIAS ? bias[(size_t)seg * Nd + col] : 0.f;
#pragma unroll
        for (int m = 0; m < 4; m++) {
#pragma unroll
            for (int r = 0; r < 4; r++) {
                int row = rb + wr * 64 + m * 16 + g * 4 + r;
                float v = acc[m][n][r] + bvv;
                if (OUTMODE == 0) outf[zoff + (size_t)row * Nd + col] = v;
                else              outh[zoff + (size_t)row * Nd + col] = f2bf(v);
            }
        }
    }
}

// ---------------------------------------------------------------------------
// Fused gate+up GEMM (round-12 exact, measured 66.0us): 64x128 tile, BK=32,
// 4 waves 2x2 (wave = 32x64), 1-deep reg-staged prefetch. K=Cc, Nd=Ii.
// ---------------------------------------------------------------------------
__global__ __launch_bounds__(256)
void gemm_gu(const unsigned short* __restrict__ A,
             const unsigned short* __restrict__ PG,
             const unsigned short* __restrict__ PU,
             unsigned short* __restrict__ outp) {
    __shared__ __align__(16) unsigned short lds[10240];  // A 4KB | G 8KB | U 8KB
    int bx = blockIdx.x, by = blockIdx.y;
    {
        int lin = bx + gridDim.x * by;
        int swz = xcd_swz(lin, gridDim.x * gridDim.y);
        bx = swz % gridDim.x; by = swz / gridDim.x;
    }
    int rb = bx * 64, cb = by;
    int seg = segof(rb % Nn);
    int tid = threadIdx.x, lane = tid & 63, wid = tid >> 6;
    int wr = wid >> 1, wc = wid & 1;
    int g = lane >> 4, c_ = lane & 15;
    const int nct = Ii >> 7;                    // 32
    const unsigned short* PGseg = PG + (size_t)seg * Cc * Ii;
    const unsigned short* PUseg = PU + (size_t)seg * Cc * Ii;

    f32x4 accG[2][4], accU[2][4];
#pragma unroll
    for (int m = 0; m < 2; m++)
#pragma unroll
        for (int n = 0; n < 4; n++) {
            accG[m][n] = (f32x4){0.f, 0.f, 0.f, 0.f};
            accU[m][n] = (f32x4){0.f, 0.f, 0.f, 0.f};
        }

    int mf0 = tid >> 6, lc0 = tid & 63;
    const unsigned short* gA =
        &A[(size_t)(rb + mf0 * 16 + (lc0 & 15)) * Cc + (lc0 >> 4) * 8];
    short8v av, gv[2], uv[2];
    auto load_tile = [&](int kt) {
        av = *reinterpret_cast<const short8v*>(gA + kt * 32);
#pragma unroll
        for (int i = 0; i < 2; i++) {
            int c = tid + i * 256;              // 0..511
            int cf = c >> 6, lc = c & 63;
            size_t off = (((size_t)kt * nct + cb) * 8 + cf) * 64 * 8 + (size_t)lc * 8;
            gv[i] = *reinterpret_cast<const short8v*>(PGseg + off);
            uv[i] = *reinterpret_cast<const short8v*>(PUseg + off);
        }
    };

    const int nKt = Cc >> 5;                    // 32
    load_tile(0);
    for (int kt = 0; kt < nKt; ++kt) {
        __syncthreads();
        *reinterpret_cast<short8v*>(&lds[(size_t)tid * 8]) = av;
#pragma unroll
        for (int i = 0; i < 2; i++) {
            *reinterpret_cast<short8v*>(&lds[2048 + (size_t)(tid + i * 256) * 8]) = gv[i];
            *reinterpret_cast<short8v*>(&lds[6144 + (size_t)(tid + i * 256) * 8]) = uv[i];
        }
        __syncthreads();
        if (kt + 1 < nKt) load_tile(kt + 1);
        short8v afr[2], gfr[4], ufr[4];
#pragma unroll
        for (int m = 0; m < 2; m++)
            afr[m] = *reinterpret_cast<short8v*>(&lds[((wr * 2 + m) * 64 + lane) * 8]);
#pragma unroll
        for (int n = 0; n < 4; n++) {
            gfr[n] = *reinterpret_cast<short8v*>(&lds[2048 + ((wc * 4 + n) * 64 + lane) * 8]);
            ufr[n] = *reinterpret_cast<short8v*>(&lds[6144 + ((wc * 4 + n) * 64 + lane) * 8]);
        }
#pragma unroll
        for (int m = 0; m < 2; m++)
#pragma unroll
            for (int n = 0; n < 4; n++) {
                accG[m][n] = __builtin_amdgcn_mfma_f32_16x16x32_bf16(
                    afr[m], gfr[n], accG[m][n], 0, 0, 0);
                accU[m][n] = __builtin_amdgcn_mfma_f32_16x16x32_bf16(
                    afr[m], ufr[n], accU[m][n], 0, 0, 0);
            }
    }

#pragma unroll
    for (int n = 0; n < 4; n++) {
        int col = cb * 128 + wc * 64 + n * 16 + c_;
#pragma unroll
        for (int m = 0; m < 2; m++) {
#pragma unroll
            for (int r = 0; r < 4; r++) {
                int row = rb + wr * 32 + m * 16 + g * 4 + r;
                float gval = accG[m][n][r], uval = accU[m][n][r];
                float t = gval / (1.f + __expf(-gval)) * uval;
                outp[(size_t)row * Ii + col] = f2bf(t);
            }
        }
    }
}

// ---------------------------------------------------------------------------
// fused proj-combine + RMSNorm2: h = x + bias + sum_z bf2f(p_z) (4 bf16
// partials) -> out (fp32); y = RMS(h, ln2) -> bf16. One block per row.
// ---------------------------------------------------------------------------
__global__ __launch_bounds__(256)
void combine_rms(const float* __restrict__ x, const float* __restrict__ bias,
                 const unsigned short* __restrict__ p, const float* __restrict__ ln2_w,
                 float* __restrict__ out, unsigned short* __restrict__ y) {
    int row = blockIdx.x;
    int n   = row % Nn;
    int seg = segof(n);
    int t   = threadIdx.x;
    size_t i = (size_t)row * 256 + t;           // float4 index
    float4 a  = reinterpret_cast<const float4*>(x)[i];
    float4 b  = *reinterpret_cast<const float4*>(&bias[(size_t)seg * Cc + t * 4]);
    float4 h;
    h.x = a.x + b.x; h.y = a.y + b.y; h.z = a.z + b.z; h.w = a.w + b.w;
#pragma unroll
    for (int z = 0; z < 4; z++) {
        ushort4 u = *reinterpret_cast<const ushort4*>(&p[(size_t)z * Mrows * Cc + i * 4]);
        h.x += bf2f(u.x); h.y += bf2f(u.y); h.z += bf2f(u.z); h.w += bf2f(u.w);
    }
    reinterpret_cast<float4*>(out)[i] = h;
    float ss = h.x * h.x + h.y * h.y + h.z * h.z + h.w * h.w;
#pragma unroll
    for (int off = 32; off; off >>= 1) ss += __shfl_down(ss, off, 64);
    __shared__ float sred[5];
    int lane = t & 63, wid = t >> 6;
    if (lane == 0) sred[wid] = ss;
    __syncthreads();
    if (t == 0) sred[4] = rsqrtf((sred[0] + sred[1] + sred[2] + sred[3]) * (1.0f / Cc) + 1e-6f);
    __syncthreads();
    float r = sred[4];
    float4 wv = reinterpret_cast<const float4*>(ln2_w + (size_t)seg * Cc)[t];
    ushort4 ov;
    ov.x = f2bf(wv.x * h.x * r);
    ov.y = f2bf(wv.y * h.y * r);
    ov.z = f2bf(wv.z * h.z * r);
    ov.w = f2bf(wv.w * h.w * r);
    *reinterpret_cast<ushort4*>(&y[(size_t)row * Cc + t * 4]) = ov;
}

// ---------------------------------------------------------------------------
// down combine: out = h(out) + sum_z bf2f(p_z)    (bf16 partials, NZ=4)
// ---------------------------------------------------------------------------
__global__ __launch_bounds__(256)
void combine_down4(const unsigned short* __restrict__ p,
                   float* __restrict__ out) {
    int i = blockIdx.x * 256 + threadIdx.x;
    float4 a = reinterpret_cast<const float4*>(out)[i];
#pragma unroll
    for (int z = 0; z < 4; z++) {
        ushort4 u = *reinterpret_cast<const ushort4*>(&p[(size_t)z * Mrows * Cc + i * 4]);
        a.x += bf2f(u.x); a.y += bf2f(u.y); a.z += bf2f(u.z); a.w += bf2f(u.w);
    }
    reinterpret_cast<float4*>(out)[i] = a;
}

// ---------------------------------------------------------------------------
// Split qkv(bf16) + per-head q/k RMSNorm + RoPE -> bf16 Q,K,V (bh, n, dh)
// ---------------------------------------------------------------------------
__global__ __launch_bounds__(256)
void split_rope(const unsigned short* __restrict__ qkv,
                const float* __restrict__ qn_w, const float* __restrict__ kn_w,
                const int* __restrict__ pos_ids, const int* __restrict__ tpos_ids,
                unsigned short* __restrict__ Q, unsigned short* __restrict__ K,
                unsigned short* __restrict__ V) {
    int row = blockIdx.x;
    int b = row / Nn, n = row % Nn;
    int seg = segof(n);
    int lane = threadIdx.x & 63, wid = threadIdx.x >> 6;
    int pos = (n < Tt) ? tpos_ids[n] : pos_ids[n - Tt];
    int j = lane & 31;
    float ang = (float)pos * exp2f(-(float)j * (13.287712379549449f / 32.f));
    float cv = cosf(ang), sv = sinf(ang);
    float qw = qn_w[seg * DH + lane], kw = kn_w[seg * DH + lane];
    for (int h = wid; h < Hh; h += 4) {
        const unsigned short* base = qkv + (size_t)row * (3 * Cc) + h * DH + lane;
        float q = bf2f(base[0]), k = bf2f(base[Cc]), v = bf2f(base[2 * Cc]);
        float qs = q * q, ks = k * k;
#pragma unroll
        for (int off = 32; off; off >>= 1) {
            qs += __shfl_xor(qs, off, 64);
            ks += __shfl_xor(ks, off, 64);
        }
        q = q * rsqrtf(qs * (1.f / DH) + 1e-6f) * qw;
        k = k * rsqrtf(ks * (1.f / DH) + 1e-6f) * kw;
        float qp = __shfl_xor(q, 32, 64);
        float kp = __shfl_xor(k, 32, 64);
        float qo = q * cv + ((lane < 32) ? -qp * sv : qp * sv);
        float ko = k * cv + ((lane < 32) ? -kp * sv : kp * sv);
        size_t oidx = ((size_t)(b * Hh + h) * Nn + n) * DH + lane;
        Q[oidx] = f2bf(qo);
        K[oidx] = f2bf(ko);
        V[oidx] = f2bf(v);
    }
}

// ---------------------------------------------------------------------------
// kernel_launch
// ---------------------------------------------------------------------------
extern "C" void kernel_launch(void* const* d_in, const int* in_sizes, int n_in,
                              void* d_out, int out_size, void* d_ws, size_t ws_size,
                              hipStream_t stream) {
    const float* x        = (const float*)d_in[0];
    const int*   pos_ids  = (const int*)d_in[1];
    const int*   tpos_ids = (const int*)d_in[2];
    const float* qkv_w    = (const float*)d_in[3];
    const float* qkv_b    = (const float*)d_in[4];
    const float* proj_w   = (const float*)d_in[5];
    const float* proj_b   = (const float*)d_in[6];
    const float* qn_w     = (const float*)d_in[7];
    const float* kn_w     = (const float*)d_in[8];
    const float* ln1_w    = (const float*)d_in[9];
    const float* ln2_w    = (const float*)d_in[10];
    const float* gate_w   = (const float*)d_in[11];
    const float* up_w     = (const float*)d_in[12];
    const float* down_w   = (const float*)d_in[13];
    float* out = (float*)d_out;                 // also used as h buffer
    char*  wsb = (char*)d_ws;

    // workspace (bytes), total 82,837,504
    unsigned short* WA  = (unsigned short*)(wsb);               // 25,165,824
    unsigned short* WB  = (unsigned short*)(wsb + 25165824);    // 25,165,824
    unsigned short* Tb  = (unsigned short*)(wsb + 50331648);    // 20,971,520
    unsigned short* P3  = (unsigned short*)(wsb + 71303168);    //  5,242,880
    unsigned short* P4  = (unsigned short*)(wsb + 76546048);    //  6,291,456
    unsigned short* Qbf = Tb;
    unsigned short* Kbf = Tb + 2621440;
    unsigned short* Vbf = Tb + 5242880;

    // 1. fat1: xn = RMS(x, ln1) -> P3  ||  pack qkv_w -> WA
    fat1<<<Mrows + 4608, 256, 0, stream>>>(x, ln1_w, P3, qkv_w, WA);
    // 2. qkv = xn @ qkv_w + qkv_b -> bf16 (WB)
    gemm128r<1, true, 1><<<dim3(Mrows / 128, 24), 256, 0, stream>>>(
        P3, WA, qkv_b, WB, Cc, 3 * Cc);
    // 3. split + q/k RMS + RoPE -> Q,K,V (Tb)
    split_rope<<<Mrows, 256, 0, stream>>>(WB, qn_w, kn_w, pos_ids, tpos_ids,
                                          Qbf, Kbf, Vbf);
    // 4. fat2: attn -> P3  ||  pack proj -> P4, gate -> WA, up -> WB
    fat2<<<640 + 1536 + 6144 + 6144, 256, 0, stream>>>(
        Qbf, Kbf, Vbf, P3, proj_w, P4, gate_w, WA, up_w, WB);
    // 5. proj split-K=4 -> bf16 partials (Tb, 21.0MB); fused combine+rms2
    gemm128r<1, false, 4><<<dim3(Mrows / 128, 8, 4), 256, 0, stream>>>(
        P3, P4, nullptr, Tb, Cc, Cc);
    combine_rms<<<Mrows, 256, 0, stream>>>(x, proj_b, Tb, ln2_w, out, P3);
    // 6. fused: t = silu(y@gate) * (y@up) -> Tb   (1280 blocks, R12 gu)
    gemm_gu<<<dim3(Mrows / 64, 32), 256, 0, stream>>>(P3, WA, WB, Tb);
    // 7. pack down_w -> WA (gate dead); down split-K=4 -> bf16 partials (WB)
    pack_w<<<6144, 256, 0, stream>>>(down_w, WA, Ii, Cc);
    gemm128r<1, false, 4><<<dim3(Mrows / 128, 8, 4), 256, 0, stream>>>(
        Tb, WA, nullptr, WB, Ii, Cc);
    combine_down4<<<Mrows * Cc / 1024, 256, 0, stream>>>(WB, out);
}

// Round 16
// 233.727 us; speedup vs baseline: 1.2802x; 1.0359x over previous
//
#include <hip/hip_runtime.h>
#include <math.h>

// Problem constants (fixed by setup_inputs)
constexpr int Bb  = 2;
constexpr int Nn  = 1280;
constexpr int Cc  = 1024;
constexpr int Hh  = 16;
constexpr int DH  = 64;
constexpr int Ii  = 4096;
constexpr int Tt  = 256;    // text_len
constexpr int BSz = 128;    // block_size
constexpr int L1  = 4;      // len1
constexpr int Mrows = Bb * Nn;  // 2560

typedef __attribute__((ext_vector_type(8))) short short8v;
typedef __attribute__((ext_vector_type(4))) float f32x4;

__device__ __forceinline__ int segof(int n) {
    return n < Tt ? 0 : (n < Tt + L1 * BSz ? 1 : 2);
}
__device__ __forceinline__ unsigned short f2bf(float f) {
    unsigned int u = __float_as_uint(f);
    u += 0x7fffu + ((u >> 16) & 1u);        // RNE
    return (unsigned short)(u >> 16);
}
__device__ __forceinline__ float bf2f(unsigned short h) {
    return __uint_as_float(((unsigned int)h) << 16);
}

// bijective XCD swizzle for nwg % 8 == 0
__device__ __forceinline__ int xcd_swz(int lin, int nwg) {
    int cpx = nwg >> 3;
    return (lin & 7) * cpx + (lin >> 3);
}

// ---------------------------------------------------------------------------
// device bodies: RMSNorm and weight-pack
// ---------------------------------------------------------------------------
__device__ __forceinline__ void rms_dev(const float* __restrict__ in,
                                        const float* __restrict__ w,
                                        unsigned short* __restrict__ out,
                                        int row, float* sred) {
    int n   = row % Nn;
    int seg = segof(n);
    const float* x = in + (size_t)row * Cc;
    int t = threadIdx.x;
    float4 xv = reinterpret_cast<const float4*>(x)[t];
    float ss = xv.x * xv.x + xv.y * xv.y + xv.z * xv.z + xv.w * xv.w;
#pragma unroll
    for (int off = 32; off; off >>= 1) ss += __shfl_down(ss, off, 64);
    int lane = t & 63, wid = t >> 6;
    if (lane == 0) sred[wid] = ss;
    __syncthreads();
    if (t == 0) sred[4] = rsqrtf((sred[0] + sred[1] + sred[2] + sred[3]) * (1.0f / Cc) + 1e-6f);
    __syncthreads();
    float r = sred[4];
    float4 wv = reinterpret_cast<const float4*>(w + (size_t)seg * Cc)[t];
    ushort4 ov;
    ov.x = f2bf(wv.x * xv.x * r);
    ov.y = f2bf(wv.y * xv.y * r);
    ov.z = f2bf(wv.z * xv.z * r);
    ov.w = f2bf(wv.w * xv.w * r);
    *reinterpret_cast<ushort4*>(&out[(size_t)row * Cc + t * 4]) = ov;
}

// pack fp32 [3][K][Nd] -> fragment-linear bf16 chunks; one chunk per thread
__device__ __forceinline__ void pack_dev(const float* __restrict__ W,
                                         unsigned short* __restrict__ PB,
                                         int K, int Nd, size_t idx) {
    size_t cpseg = (size_t)K * Nd / 8;
    int s = (int)(idx / cpseg);
    size_t rm = idx % cpseg;
    int lane = (int)(rm & 63);
    int fr   = (int)((rm >> 6) & 7);
    size_t tile = rm >> 9;                  // kt32*(Nd/128)+cb
    int nct = Nd >> 7;
    int cb = (int)(tile % nct);
    int kt = (int)(tile / nct);
    int col = cb * 128 + fr * 16 + (lane & 15);
    int k0  = kt * 32 + (lane >> 4) * 8;
    const float* src = W + ((size_t)s * K + k0) * Nd + col;
    unsigned short o[8];
#pragma unroll
    for (int j = 0; j < 8; j++) o[j] = f2bf(src[(size_t)j * Nd]);
    short8v v;
#pragma unroll
    for (int j = 0; j < 8; j++) v[j] = (short)o[j];
    *reinterpret_cast<short8v*>(&PB[idx * 8]) = v;
}

// ---------------------------------------------------------------------------
// standalone pack kernel (down weights)
// ---------------------------------------------------------------------------
__global__ __launch_bounds__(256)
void pack_w(const float* __restrict__ W, unsigned short* __restrict__ PB,
            int K, int Nd) {
    pack_dev(W, PB, K, Nd, (size_t)blockIdx.x * 256 + threadIdx.x);
}

// fat1: rms1 [0,Mrows) + pack_qkv [Mrows, Mrows+4608) + rope table (160 blocks)
__global__ __launch_bounds__(256)
void fat1(const float* __restrict__ x, const float* __restrict__ ln1_w,
          unsigned short* __restrict__ xn,
          const float* __restrict__ qkv_w, unsigned short* __restrict__ qkv_p,
          const int* __restrict__ pos_ids, const int* __restrict__ tpos_ids,
          float2* __restrict__ tab) {
    __shared__ float sred[5];
    int bid = blockIdx.x;
    if (bid < Mrows) {
        rms_dev(x, ln1_w, xn, bid, sred);
        return;
    }
    bid -= Mrows;
    if (bid < 4608) {
        pack_dev(qkv_w, qkv_p, Cc, 3 * Cc, (size_t)bid * 256 + threadIdx.x);
        return;
    }
    bid -= 4608;
    // rope table: tab[n*32 + j] = (cos, sin) of (pos(n), j)
    int idx = bid * 256 + threadIdx.x;          // 0..40959
    int n = idx >> 5, j = idx & 31;
    int pos = (n < Tt) ? tpos_ids[n] : pos_ids[n - Tt];
    float ang = (float)pos * exp2f(-(float)j * (13.287712379549449f / 32.f));
    tab[idx] = make_float2(cosf(ang), sinf(ang));
}

// ---------------------------------------------------------------------------
// MFMA flash attention body (verified) + T5 setprio around MFMA clusters
// ---------------------------------------------------------------------------
__device__ __forceinline__ void attn_dev(
        const unsigned short* __restrict__ Qg, const unsigned short* __restrict__ Kg,
        const unsigned short* __restrict__ Vg, unsigned short* __restrict__ O,
        int qt, int bh,
        unsigned short* k_lds, unsigned short* vt_lds, unsigned short* p_base) {
    int b = bh >> 4, h = bh & 15;
    int tid = threadIdx.x, lane = tid & 63, wid = tid >> 6;
    int g = lane >> 4, c = lane & 15;

    const size_t headoff = (size_t)bh * Nn * DH;
    int q0 = qt * 64;
    bool qtext = q0 < Tt;
    int qb = qtext ? 0 : (q0 - Tt) / BSz;

    int qrow_frag = q0 + wid * 16 + c;
    short8v aq[2];
#pragma unroll
    for (int kb = 0; kb < 2; kb++)
        aq[kb] = *reinterpret_cast<const short8v*>(
            &Qg[headoff + (size_t)qrow_frag * DH + kb * 32 + g * 8]);

    unsigned short* pbuf = p_base + wid * 1024;

    f32x4 o_[4];
#pragma unroll
    for (int nb = 0; nb < 4; nb++) o_[nb] = (f32x4){0.f, 0.f, 0.f, 0.f};
    float m_[4] = {-3.4e38f, -3.4e38f, -3.4e38f, -3.4e38f};
    float l_[4] = {0.f, 0.f, 0.f, 0.f};

    int tr = tid >> 2, tc = tid & 3;

    for (int kt = 0; kt < Nn / 64; kt++) {
        int kbase = kt * 64;
        bool vis, diag = false;
        if (qtext) {
            vis = (kbase <= q0);
            diag = (kbase == q0);
        } else if (kbase < Tt) {
            vis = true;
        } else {
            int kb = (kbase - Tt) / BSz;
            vis = (qb < L1) ? (kb <= qb)
                            : ((kb < L1 && qb - L1 > kb) || kb == qb);
        }
        if (!vis) continue;

        __syncthreads();
        {
            const unsigned short* ks = &Kg[headoff + (size_t)(kbase + tr) * DH];
            const unsigned short* vs = &Vg[headoff + (size_t)(kbase + tr) * DH];
#pragma unroll
            for (int i = 0; i < 2; i++) {
                int ch = tc + i * 4;
                short8v kv = *reinterpret_cast<const short8v*>(ks + ch * 8);
                int byte = (tr * 128 + ch * 16) ^ ((tr & 7) << 4);
                *reinterpret_cast<short8v*>((char*)k_lds + byte) = kv;
                short8v vv = *reinterpret_cast<const short8v*>(vs + ch * 8);
#pragma unroll
                for (int j = 0; j < 8; j++) {
                    int dh = ch * 8 + j;
                    int vbyte = (dh * 128 + tr * 2) ^ ((dh & 7) << 4);
                    *reinterpret_cast<unsigned short*>((char*)vt_lds + vbyte) =
                        (unsigned short)vv[j];
                }
            }
        }
        __syncthreads();

        f32x4 s_[4];
#pragma unroll
        for (int nb = 0; nb < 4; nb++) s_[nb] = (f32x4){0.f, 0.f, 0.f, 0.f};
        __builtin_amdgcn_s_setprio(1);
#pragma unroll
        for (int nb = 0; nb < 4; nb++) {
            int kil = nb * 16 + c;
#pragma unroll
            for (int kb = 0; kb < 2; kb++) {
                int byte = (kil * 128 + kb * 64 + g * 16) ^ ((kil & 7) << 4);
                short8v bk = *reinterpret_cast<short8v*>((char*)k_lds + byte);
                s_[nb] = __builtin_amdgcn_mfma_f32_16x16x32_bf16(aq[kb], bk, s_[nb], 0, 0, 0);
            }
        }
        __builtin_amdgcn_s_setprio(0);
#pragma unroll
        for (int nb = 0; nb < 4; nb++) {
#pragma unroll
            for (int r = 0; r < 4; r++) {
                float sv = s_[nb][r] * 0.125f;
                if (diag) {
                    int qrl = wid * 16 + g * 4 + r;
                    int kcl = nb * 16 + c;
                    if (qrl < kcl) sv = -3.4e38f;
                }
                s_[nb][r] = sv;
            }
        }
#pragma unroll
        for (int r = 0; r < 4; r++) {
            float mx = fmaxf(fmaxf(s_[0][r], s_[1][r]), fmaxf(s_[2][r], s_[3][r]));
#pragma unroll
            for (int off = 1; off <= 8; off <<= 1)
                mx = fmaxf(mx, __shfl_xor(mx, off, 64));
            float mn = fmaxf(m_[r], mx);
            float es = __expf(m_[r] - mn);
            m_[r] = mn;
            float pv[4];
            float rs = 0.f;
#pragma unroll
            for (int nb = 0; nb < 4; nb++) {
                pv[nb] = __expf(s_[nb][r] - mn);
                rs += pv[nb];
            }
#pragma unroll
            for (int off = 1; off <= 8; off <<= 1)
                rs += __shfl_xor(rs, off, 64);
            l_[r] = l_[r] * es + rs;
#pragma unroll
            for (int nb = 0; nb < 4; nb++) o_[nb][r] *= es;
            int qrl = g * 4 + r;
            int swz = (qrl & 7) << 4;
#pragma unroll
            for (int nb = 0; nb < 4; nb++) {
                int byte = (qrl * 128 + (nb * 16 + c) * 2) ^ swz;
                *reinterpret_cast<unsigned short*>((char*)pbuf + byte) = f2bf(pv[nb]);
            }
        }
        short8v aP[2];
#pragma unroll
        for (int kb = 0; kb < 2; kb++) {
            int byte = (c * 128 + kb * 64 + g * 16) ^ ((c & 7) << 4);
            aP[kb] = *reinterpret_cast<short8v*>((char*)pbuf + byte);
        }
        __builtin_amdgcn_s_setprio(1);
#pragma unroll
        for (int nb = 0; nb < 4; nb++) {
            int dh = nb * 16 + c;
#pragma unroll
            for (int kb = 0; kb < 2; kb++) {
                int byte = (dh * 128 + kb * 64 + g * 16) ^ ((dh & 7) << 4);
                short8v bv = *reinterpret_cast<short8v*>((char*)vt_lds + byte);
                o_[nb] = __builtin_amdgcn_mfma_f32_16x16x32_bf16(aP[kb], bv, o_[nb], 0, 0, 0);
            }
        }
        __builtin_amdgcn_s_setprio(0);
    }

    float inv_[4];
#pragma unroll
    for (int r = 0; r < 4; r++) inv_[r] = 1.f / l_[r];
#pragma unroll
    for (int nb = 0; nb < 4; nb++) {
        int col = h * DH + nb * 16 + c;
#pragma unroll
        for (int r = 0; r < 4; r++) {
            int row = q0 + wid * 16 + g * 4 + r;
            O[((size_t)b * Nn + row) * Cc + col] = f2bf(o_[nb][r] * inv_[r]);
        }
    }
}

// fat2: attn [0,640) + pack_proj (1536) + pack_gate (6144) + pack_up (6144)
__global__ __launch_bounds__(256)
void fat2(const unsigned short* __restrict__ Qg, const unsigned short* __restrict__ Kg,
          const unsigned short* __restrict__ Vg, unsigned short* __restrict__ O,
          const float* __restrict__ proj_w, unsigned short* __restrict__ proj_p,
          const float* __restrict__ gate_w, unsigned short* __restrict__ gate_p,
          const float* __restrict__ up_w,   unsigned short* __restrict__ up_p) {
    __shared__ __align__(16) unsigned short k_lds[64 * 64];
    __shared__ __align__(16) unsigned short vt_lds[64 * 64];
    __shared__ __align__(16) unsigned short p_lds[4 * 16 * 64];
    int bid = blockIdx.x;
    if (bid < 640) {
        attn_dev(Qg, Kg, Vg, O, bid % 20, bid / 20, k_lds, vt_lds, p_lds);
        return;
    }
    bid -= 640;
    if (bid < 1536) {
        pack_dev(proj_w, proj_p, Cc, Cc, (size_t)bid * 256 + threadIdx.x);
        return;
    }
    bid -= 1536;
    if (bid < 6144) {
        pack_dev(gate_w, gate_p, Cc, Ii, (size_t)bid * 256 + threadIdx.x);
        return;
    }
    bid -= 6144;
    pack_dev(up_w, up_p, Cc, Ii, (size_t)bid * 256 + threadIdx.x);
}

// ---------------------------------------------------------------------------
// bf16 MFMA GEMM (round-14 verified): 128x128 tile, BK=32, 4 waves 2x2,
// packed-B, 2-DEEP register prefetch, x2 unroll with named register sets.
// OUTMODE: 0 = f32 out, 1 = bf16 out.  NZ: split-K; partial z at z*Mrows*Nd.
// ---------------------------------------------------------------------------
template <int OUTMODE, bool BIAS, int NZ>
__global__ __launch_bounds__(256, 2)
void gemm128r(const unsigned short* __restrict__ A,
              const unsigned short* __restrict__ PB,
              const float* __restrict__ bias, void* __restrict__ outp,
              int K, int Nd) {
    __shared__ __align__(16) unsigned short lds[8192];   // A 8KB | B 8KB
    int bx = blockIdx.x, by = blockIdx.y, bz = (NZ > 1) ? blockIdx.z : 0;
    {
        int gx = gridDim.x, gy = gridDim.y, gz = (NZ > 1) ? gridDim.z : 1;
        int lin = bx + gx * (by + gy * bz);
        int swz = xcd_swz(lin, gx * gy * gz);
        bx = swz % gx; swz /= gx;
        by = swz % gy; bz = swz / gy;
    }
    int rb = bx * 128, cb = by;
    int seg = segof(rb % Nn);
    int tid = threadIdx.x, lane = tid & 63, wid = tid >> 6;
    int wr = wid >> 1, wc = wid & 1;
    int g = lane >> 4, c_ = lane & 15;
    const int nct = Nd >> 7;
    const int Keff = K / NZ;
    const int nKt = Keff >> 5;
    const int kz = bz * Keff;
    const unsigned short* PBseg = PB + (size_t)seg * K * Nd;

    int mf0 = tid >> 6, lc0 = tid & 63;
    const unsigned short* pA0 =
        A + (size_t)(rb + mf0 * 16 + (lc0 & 15)) * K + kz + (lc0 >> 4) * 8;
    const unsigned short* pA1 = pA0 + (size_t)64 * K;
    const unsigned short* pB0 =
        PBseg + (((size_t)(kz >> 5) * nct + cb) * 8 + mf0) * 512 + (size_t)lc0 * 8;
    const unsigned short* pB1 = pB0 + 2048;
    const size_t bstep = (size_t)nct * 4096;   // shorts per K-step

    f32x4 acc[4][4];
#pragma unroll
    for (int m = 0; m < 4; m++)
#pragma unroll
        for (int n = 0; n < 4; n++) acc[m][n] = (f32x4){0.f, 0.f, 0.f, 0.f};

    short8v avA0, avA1, bvA0, bvA1;
    short8v avB0, avB1, bvB0, bvB1;
    avA0 = *reinterpret_cast<const short8v*>(pA0);
    avA1 = *reinterpret_cast<const short8v*>(pA1);
    bvA0 = *reinterpret_cast<const short8v*>(pB0);
    bvA1 = *reinterpret_cast<const short8v*>(pB1);
    pA0 += 32; pA1 += 32; pB0 += bstep; pB1 += bstep;
    avB0 = *reinterpret_cast<const short8v*>(pA0);
    avB1 = *reinterpret_cast<const short8v*>(pA1);
    bvB0 = *reinterpret_cast<const short8v*>(pB0);
    bvB1 = *reinterpret_cast<const short8v*>(pB1);
    pA0 += 32; pA1 += 32; pB0 += bstep; pB1 += bstep;

    auto compute = [&]() {
        short8v afr[4], bfr[4];
#pragma unroll
        for (int m = 0; m < 4; m++)
            afr[m] = *reinterpret_cast<short8v*>(&lds[((wr * 4 + m) * 64 + lane) * 8]);
#pragma unroll
        for (int n = 0; n < 4; n++)
            bfr[n] = *reinterpret_cast<short8v*>(&lds[4096 + ((wc * 4 + n) * 64 + lane) * 8]);
#pragma unroll
        for (int m = 0; m < 4; m++)
#pragma unroll
            for (int n = 0; n < 4; n++)
                acc[m][n] = __builtin_amdgcn_mfma_f32_16x16x32_bf16(
                    afr[m], bfr[n], acc[m][n], 0, 0, 0);
    };

    for (int kt = 0; kt < nKt; kt += 2) {
        __syncthreads();
        *reinterpret_cast<short8v*>(&lds[(size_t)tid * 8]) = avA0;
        *reinterpret_cast<short8v*>(&lds[(size_t)(tid + 256) * 8]) = avA1;
        *reinterpret_cast<short8v*>(&lds[4096 + (size_t)tid * 8]) = bvA0;
        *reinterpret_cast<short8v*>(&lds[4096 + (size_t)(tid + 256) * 8]) = bvA1;
        __syncthreads();
        if (kt + 2 < nKt) {
            avA0 = *reinterpret_cast<const short8v*>(pA0);
            avA1 = *reinterpret_cast<const short8v*>(pA1);
            bvA0 = *reinterpret_cast<const short8v*>(pB0);
            bvA1 = *reinterpret_cast<const short8v*>(pB1);
            pA0 += 32; pA1 += 32; pB0 += bstep; pB1 += bstep;
        }
        compute();
        __syncthreads();
        *reinterpret_cast<short8v*>(&lds[(size_t)tid * 8]) = avB0;
        *reinterpret_cast<short8v*>(&lds[(size_t)(tid + 256) * 8]) = avB1;
        *reinterpret_cast<short8v*>(&lds[4096 + (size_t)tid * 8]) = bvB0;
        *reinterpret_cast<short8v*>(&lds[4096 + (size_t)(tid + 256) * 8]) = bvB1;
        __syncthreads();
        if (kt + 3 < nKt) {
            avB0 = *reinterpret_cast<const short8v*>(pA0);
            avB1 = *reinterpret_cast<const short8v*>(pA1);
            bvB0 = *reinterpret_cast<const short8v*>(pB0);
            bvB1 = *reinterpret_cast<const short8v*>(pB1);
            pA0 += 32; pA1 += 32; pB0 += bstep; pB1 += bstep;
        }
        compute();
    }

    float* outf = (float*)outp;
    unsigned short* outh = (unsigned short*)outp;
    size_t zoff = (NZ > 1) ? (size_t)bz * Mrows * Nd : 0;
#pragma unroll
    for (int n = 0; n < 4; n++) {
        int col = cb * 128 + wc * 64 + n * 16 + c_;
        float bvv = BIAS ? bias[(size_t)seg * Nd + col] : 0.f;
#pragma unroll
        for (int m = 0; m < 4; m++) {
#pragma unroll
            for (int r = 0; r < 4; r++) {
                int row = rb + wr * 64 + m * 16 + g * 4 + r;
                float v = acc[m][n][r] + bvv;
                if (OUTMODE == 0) outf[zoff + (size_t)row * Nd + col] = v;
                else              outh[zoff + (size_t)row * Nd + col] = f2bf(v);
            }
        }
    }
}

// ---------------------------------------------------------------------------
// qkv GEMM with FUSED split + q/k RMSNorm + RoPE epilogue.
// Main loop identical to gemm128r (NZ=1, K=Cc, Nd=3*Cc). Each wave's 64-col
// slice = one (three,h): three = colbase>>10, h = (colbase&1023)>>6.
// RMS over Dh=64: 4 local terms + shfl_xor{1,2,4,8} across the 16-lane
// c-group (same row). RoPE pairs dh<->dh+-32 = acc[m][n]<->acc[m][n+-2]
// (same lane); cos/sin from precomputed table tab[nrow*32+j].
// ---------------------------------------------------------------------------
__global__ __launch_bounds__(256, 2)
void gemm_qkv(const unsigned short* __restrict__ A,
              const unsigned short* __restrict__ PB,
              const float* __restrict__ bias,
              const float* __restrict__ qn_w, const float* __restrict__ kn_w,
              const float2* __restrict__ tab,
              unsigned short* __restrict__ Q, unsigned short* __restrict__ K,
              unsigned short* __restrict__ V) {
    __shared__ __align__(16) unsigned short lds[8192];
    const int Kd = Cc, Nd = 3 * Cc;
    int bx = blockIdx.x, by = blockIdx.y;
    {
        int lin = bx + gridDim.x * by;
        int swz = xcd_swz(lin, gridDim.x * gridDim.y);
        bx = swz % gridDim.x; by = swz / gridDim.x;
    }
    int rb = bx * 128, cb = by;
    int seg = segof(rb % Nn);
    int tid = threadIdx.x, lane = tid & 63, wid = tid >> 6;
    int wr = wid >> 1, wc = wid & 1;
    int g = lane >> 4, c_ = lane & 15;
    const int nct = Nd >> 7;                    // 24
    const int nKt = Kd >> 5;                    // 32
    const unsigned short* PBseg = PB + (size_t)seg * Kd * Nd;

    int mf0 = tid >> 6, lc0 = tid & 63;
    const unsigned short* pA0 =
        A + (size_t)(rb + mf0 * 16 + (lc0 & 15)) * Kd + (lc0 >> 4) * 8;
    const unsigned short* pA1 = pA0 + (size_t)64 * Kd;
    const unsigned short* pB0 =
        PBseg + (((size_t)cb) * 8 + mf0) * 512 + (size_t)lc0 * 8;
    const unsigned short* pB1 = pB0 + 2048;
    const size_t bstep = (size_t)nct * 4096;

    f32x4 acc[4][4];
#pragma unroll
    for (int m = 0; m < 4; m++)
#pragma unroll
        for (int n = 0; n < 4; n++) acc[m][n] = (f32x4){0.f, 0.f, 0.f, 0.f};

    short8v avA0, avA1, bvA0, bvA1;
    short8v avB0, avB1, bvB0, bvB1;
    avA0 = *reinterpret_cast<const short8v*>(pA0);
    avA1 = *reinterpret_cast<const short8v*>(pA1);
    bvA0 = *reinterpret_cast<const short8v*>(pB0);
    bvA1 = *reinterpret_cast<const short8v*>(pB1);
    pA0 += 32; pA1 += 32; pB0 += bstep; pB1 += bstep;
    avB0 = *reinterpret_cast<const short8v*>(pA0);
    avB1 = *reinterpret_cast<const short8v*>(pA1);
    bvB0 = *reinterpret_cast<const short8v*>(pB0);
    bvB1 = *reinterpret_cast<const short8v*>(pB1);
    pA0 += 32; pA1 += 32; pB0 += bstep; pB1 += bstep;

    auto compute = [&]() {
        short8v afr[4], bfr[4];
#pragma unroll
        for (int m = 0; m < 4; m++)
            afr[m] = *reinterpret_cast<short8v*>(&lds[((wr * 4 + m) * 64 + lane) * 8]);
#pragma unroll
        for (int n = 0; n < 4; n++)
            bfr[n] = *reinterpret_cast<short8v*>(&lds[4096 + ((wc * 4 + n) * 64 + lane) * 8]);
#pragma unroll
        for (int m = 0; m < 4; m++)
#pragma unroll
            for (int n = 0; n < 4; n++)
                acc[m][n] = __builtin_amdgcn_mfma_f32_16x16x32_bf16(
                    afr[m], bfr[n], acc[m][n], 0, 0, 0);
    };

    for (int kt = 0; kt < nKt; kt += 2) {
        __syncthreads();
        *reinterpret_cast<short8v*>(&lds[(size_t)tid * 8]) = avA0;
        *reinterpret_cast<short8v*>(&lds[(size_t)(tid + 256) * 8]) = avA1;
        *reinterpret_cast<short8v*>(&lds[4096 + (size_t)tid * 8]) = bvA0;
        *reinterpret_cast<short8v*>(&lds[4096 + (size_t)(tid + 256) * 8]) = bvA1;
        __syncthreads();
        if (kt + 2 < nKt) {
            avA0 = *reinterpret_cast<const short8v*>(pA0);
            avA1 = *reinterpret_cast<const short8v*>(pA1);
            bvA0 = *reinterpret_cast<const short8v*>(pB0);
            bvA1 = *reinterpret_cast<const short8v*>(pB1);
            pA0 += 32; pA1 += 32; pB0 += bstep; pB1 += bstep;
        }
        compute();
        __syncthreads();
        *reinterpret_cast<short8v*>(&lds[(size_t)tid * 8]) = avB0;
        *reinterpret_cast<short8v*>(&lds[(size_t)(tid + 256) * 8]) = avB1;
        *reinterpret_cast<short8v*>(&lds[4096 + (size_t)tid * 8]) = bvB0;
        *reinterpret_cast<short8v*>(&lds[4096 + (size_t)(tid + 256) * 8]) = bvB1;
        __syncthreads();
        if (kt + 3 < nKt) {
            avB0 = *reinterpret_cast<const short8v*>(pA0);
            avB1 = *reinterpret_cast<const short8v*>(pA1);
            bvB0 = *reinterpret_cast<const short8v*>(pB0);
            bvB1 = *reinterpret_cast<const short8v*>(pB1);
            pA0 += 32; pA1 += 32; pB0 += bstep; pB1 += bstep;
        }
        compute();
    }

    // ---- fused epilogue ----
    int colbase = cb * 128 + wc * 64;           // 64-aligned -> one (three, h)
    int three = colbase >> 10;
    int h = (colbase & 1023) >> 6;
    float bv[4];
#pragma unroll
    for (int n = 0; n < 4; n++)
        bv[n] = bias[(size_t)seg * (3 * Cc) + colbase + n * 16 + c_];

    if (three == 2) {                           // V: plain bf16 store
#pragma unroll
        for (int m = 0; m < 4; m++) {
#pragma unroll
            for (int r = 0; r < 4; r++) {
                int grow = rb + wr * 64 + m * 16 + g * 4 + r;
                int b = (grow >= Nn) ? 1 : 0;
                int nrow = grow - b * Nn;
                size_t base = ((size_t)(b * Hh + h) * Nn + nrow) * DH;
#pragma unroll
                for (int n = 0; n < 4; n++)
                    V[base + n * 16 + c_] = f2bf(acc[m][n][r] + bv[n]);
            }
        }
        return;
    }

    // Q or K: per-row RMS over 64 cols + RoPE
    const float* nwp = (three == 0 ? qn_w : kn_w) + (size_t)seg * DH;
    float nwv[4];
#pragma unroll
    for (int n = 0; n < 4; n++) nwv[n] = nwp[n * 16 + c_];
    unsigned short* outT = (three == 0) ? Q : K;

#pragma unroll
    for (int m = 0; m < 4; m++) {
#pragma unroll
        for (int r = 0; r < 4; r++) {
            int grow = rb + wr * 64 + m * 16 + g * 4 + r;
            int b = (grow >= Nn) ? 1 : 0;
            int nrow = grow - b * Nn;
            float val[4];
#pragma unroll
            for (int n = 0; n < 4; n++) val[n] = acc[m][n][r] + bv[n];
            float ss = val[0] * val[0] + val[1] * val[1] +
                       val[2] * val[2] + val[3] * val[3];
#pragma unroll
            for (int off = 1; off <= 8; off <<= 1)
                ss += __shfl_xor(ss, off, 64);
            float rn = rsqrtf(ss * (1.f / DH) + 1e-6f);
#pragma unroll
            for (int n = 0; n < 4; n++) val[n] *= rn * nwv[n];
            size_t base = ((size_t)(b * Hh + h) * Nn + nrow) * DH;
#pragma unroll
            for (int n = 0; n < 2; n++) {       // rope pairs n <-> n+2
                int j = n * 16 + c_;            // dh < 32 -> j = dh
                float2 cs = tab[(size_t)nrow * 32 + j];
                float lo = val[n] * cs.x - val[n + 2] * cs.y;
                float hi = val[n + 2] * cs.x + val[n] * cs.y;
                outT[base + n * 16 + c_]        = f2bf(lo);
                outT[base + (n + 2) * 16 + c_]  = f2bf(hi);
            }
        }
    }
}

// ---------------------------------------------------------------------------
// Fused gate+up GEMM (round-12 exact, 66.0us): 64x128 tile, BK=32,
// 4 waves 2x2 (wave = 32x64), 1-deep reg-staged prefetch. K=Cc, Nd=Ii.
// ---------------------------------------------------------------------------
__global__ __launch_bounds__(256)
void gemm_gu(const unsigned short* __restrict__ A,
             const unsigned short* __restrict__ PG,
             const unsigned short* __restrict__ PU,
             unsigned short* __restrict__ outp) {
    __shared__ __align__(16) unsigned short lds[10240];  // A 4KB | G 8KB | U 8KB
    int bx = blockIdx.x, by = blockIdx.y;
    {
        int lin = bx + gridDim.x * by;
        int swz = xcd_swz(lin, gridDim.x * gridDim.y);
        bx = swz % gridDim.x; by = swz / gridDim.x;
    }
    int rb = bx * 64, cb = by;
    int seg = segof(rb % Nn);
    int tid = threadIdx.x, lane = tid & 63, wid = tid >> 6;
    int wr = wid >> 1, wc = wid & 1;
    int g = lane >> 4, c_ = lane & 15;
    const int nct = Ii >> 7;                    // 32
    const unsigned short* PGseg = PG + (size_t)seg * Cc * Ii;
    const unsigned short* PUseg = PU + (size_t)seg * Cc * Ii;

    f32x4 accG[2][4], accU[2][4];
#pragma unroll
    for (int m = 0; m < 2; m++)
#pragma unroll
        for (int n = 0; n < 4; n++) {
            accG[m][n] = (f32x4){0.f, 0.f, 0.f, 0.f};
            accU[m][n] = (f32x4){0.f, 0.f, 0.f, 0.f};
        }

    int mf0 = tid >> 6, lc0 = tid & 63;
    const unsigned short* gA =
        &A[(size_t)(rb + mf0 * 16 + (lc0 & 15)) * Cc + (lc0 >> 4) * 8];
    short8v av, gv[2], uv[2];
    auto load_tile = [&](int kt) {
        av = *reinterpret_cast<const short8v*>(gA + kt * 32);
#pragma unroll
        for (int i = 0; i < 2; i++) {
            int c = tid + i * 256;              // 0..511
            int cf = c >> 6, lc = c & 63;
            size_t off = (((size_t)kt * nct + cb) * 8 + cf) * 64 * 8 + (size_t)lc * 8;
            gv[i] = *reinterpret_cast<const short8v*>(PGseg + off);
            uv[i] = *reinterpret_cast<const short8v*>(PUseg + off);
        }
    };

    const int nKt = Cc >> 5;                    // 32
    load_tile(0);
    for (int kt = 0; kt < nKt; ++kt) {
        __syncthreads();
        *reinterpret_cast<short8v*>(&lds[(size_t)tid * 8]) = av;
#pragma unroll
        for (int i = 0; i < 2; i++) {
            *reinterpret_cast<short8v*>(&lds[2048 + (size_t)(tid + i * 256) * 8]) = gv[i];
            *reinterpret_cast<short8v*>(&lds[6144 + (size_t)(tid + i * 256) * 8]) = uv[i];
        }
        __syncthreads();
        if (kt + 1 < nKt) load_tile(kt + 1);
        short8v afr[2], gfr[4], ufr[4];
#pragma unroll
        for (int m = 0; m < 2; m++)
            afr[m] = *reinterpret_cast<short8v*>(&lds[((wr * 2 + m) * 64 + lane) * 8]);
#pragma unroll
        for (int n = 0; n < 4; n++) {
            gfr[n] = *reinterpret_cast<short8v*>(&lds[2048 + ((wc * 4 + n) * 64 + lane) * 8]);
            ufr[n] = *reinterpret_cast<short8v*>(&lds[6144 + ((wc * 4 + n) * 64 + lane) * 8]);
        }
#pragma unroll
        for (int m = 0; m < 2; m++)
#pragma unroll
            for (int n = 0; n < 4; n++) {
                accG[m][n] = __builtin_amdgcn_mfma_f32_16x16x32_bf16(
                    afr[m], gfr[n], accG[m][n], 0, 0, 0);
                accU[m][n] = __builtin_amdgcn_mfma_f32_16x16x32_bf16(
                    afr[m], ufr[n], accU[m][n], 0, 0, 0);
            }
    }

#pragma unroll
    for (int n = 0; n < 4; n++) {
        int col = cb * 128 + wc * 64 + n * 16 + c_;
#pragma unroll
        for (int m = 0; m < 2; m++) {
#pragma unroll
            for (int r = 0; r < 4; r++) {
                int row = rb + wr * 32 + m * 16 + g * 4 + r;
                float gval = accG[m][n][r], uval = accU[m][n][r];
                float t = gval / (1.f + __expf(-gval)) * uval;
                outp[(size_t)row * Ii + col] = f2bf(t);
            }
        }
    }
}

// ---------------------------------------------------------------------------
// fused proj-combine + RMSNorm2: h = x + bias + sum_z bf2f(p_z) -> out;
// y = RMS(h, ln2) -> bf16. One block per row.
// ---------------------------------------------------------------------------
__global__ __launch_bounds__(256)
void combine_rms(const float* __restrict__ x, const float* __restrict__ bias,
                 const unsigned short* __restrict__ p, const float* __restrict__ ln2_w,
                 float* __restrict__ out, unsigned short* __restrict__ y) {
    int row = blockIdx.x;
    int n   = row % Nn;
    int seg = segof(n);
    int t   = threadIdx.x;
    size_t i = (size_t)row * 256 + t;
    float4 a  = reinterpret_cast<const float4*>(x)[i];
    float4 b  = *reinterpret_cast<const float4*>(&bias[(size_t)seg * Cc + t * 4]);
    float4 h;
    h.x = a.x + b.x; h.y = a.y + b.y; h.z = a.z + b.z; h.w = a.w + b.w;
#pragma unroll
    for (int z = 0; z < 4; z++) {
        ushort4 u = *reinterpret_cast<const ushort4*>(&p[(size_t)z * Mrows * Cc + i * 4]);
        h.x += bf2f(u.x); h.y += bf2f(u.y); h.z += bf2f(u.z); h.w += bf2f(u.w);
    }
    reinterpret_cast<float4*>(out)[i] = h;
    float ss = h.x * h.x + h.y * h.y + h.z * h.z + h.w * h.w;
#pragma unroll
    for (int off = 32; off; off >>= 1) ss += __shfl_down(ss, off, 64);
    __shared__ float sred[5];
    int lane = t & 63, wid = t >> 6;
    if (lane == 0) sred[wid] = ss;
    __syncthreads();
    if (t == 0) sred[4] = rsqrtf((sred[0] + sred[1] + sred[2] + sred[3]) * (1.0f / Cc) + 1e-6f);
    __syncthreads();
    float r = sred[4];
    float4 wv = reinterpret_cast<const float4*>(ln2_w + (size_t)seg * Cc)[t];
    ushort4 ov;
    ov.x = f2bf(wv.x * h.x * r);
    ov.y = f2bf(wv.y * h.y * r);
    ov.z = f2bf(wv.z * h.z * r);
    ov.w = f2bf(wv.w * h.w * r);
    *reinterpret_cast<ushort4*>(&y[(size_t)row * Cc + t * 4]) = ov;
}

// ---------------------------------------------------------------------------
// down combine: out = h(out) + sum_z bf2f(p_z)    (bf16 partials, NZ=4)
// ---------------------------------------------------------------------------
__global__ __launch_bounds__(256)
void combine_down4(const unsigned short* __restrict__ p,
                   float* __restrict__ out) {
    int i = blockIdx.x * 256 + threadIdx.x;
    float4 a = reinterpret_cast<const float4*>(out)[i];
#pragma unroll
    for (int z = 0; z < 4; z++) {
        ushort4 u = *reinterpret_cast<const ushort4*>(&p[(size_t)z * Mrows * Cc + i * 4]);
        a.x += bf2f(u.x); a.y += bf2f(u.y); a.z += bf2f(u.z); a.w += bf2f(u.w);
    }
    reinterpret_cast<float4*>(out)[i] = a;
}

// ---------------------------------------------------------------------------
// kernel_launch
// ---------------------------------------------------------------------------
extern "C" void kernel_launch(void* const* d_in, const int* in_sizes, int n_in,
                              void* d_out, int out_size, void* d_ws, size_t ws_size,
                              hipStream_t stream) {
    const float* x        = (const float*)d_in[0];
    const int*   pos_ids  = (const int*)d_in[1];
    const int*   tpos_ids = (const int*)d_in[2];
    const float* qkv_w    = (const float*)d_in[3];
    const float* qkv_b    = (const float*)d_in[4];
    const float* proj_w   = (const float*)d_in[5];
    const float* proj_b   = (const float*)d_in[6];
    const float* qn_w     = (const float*)d_in[7];
    const float* kn_w     = (const float*)d_in[8];
    const float* ln1_w    = (const float*)d_in[9];
    const float* ln2_w    = (const float*)d_in[10];
    const float* gate_w   = (const float*)d_in[11];
    const float* up_w     = (const float*)d_in[12];
    const float* down_w   = (const float*)d_in[13];
    float* out = (float*)d_out;                 // also used as h buffer
    char*  wsb = (char*)d_ws;

    // workspace (bytes), total 82,837,504
    // WA: qkv pack -> gate pack -> down pack
    // WB: up pack / down partials
    // Tb: Q,K,V -> proj partials -> t
    // P3: xn -> attn out -> y
    // P4: rope table (327KB) -> proj pack
    unsigned short* WA  = (unsigned short*)(wsb);               // 25,165,824
    unsigned short* WB  = (unsigned short*)(wsb + 25165824);    // 25,165,824
    unsigned short* Tb  = (unsigned short*)(wsb + 50331648);    // 20,971,520
    unsigned short* P3  = (unsigned short*)(wsb + 71303168);    //  5,242,880
    unsigned short* P4  = (unsigned short*)(wsb + 76546048);    //  6,291,456
    unsigned short* Qbf = Tb;
    unsigned short* Kbf = Tb + 2621440;
    unsigned short* Vbf = Tb + 5242880;
    float2*         tab = (float2*)P4;

    // 1. fat1: xn = RMS(x, ln1) -> P3 || pack qkv_w -> WA || rope table -> P4
    fat1<<<Mrows + 4608 + 160, 256, 0, stream>>>(x, ln1_w, P3, qkv_w, WA,
                                                 pos_ids, tpos_ids, tab);
    // 2. qkv GEMM + fused split/RMS/RoPE -> Q,K,V (Tb)
    gemm_qkv<<<dim3(Mrows / 128, 24), 256, 0, stream>>>(
        P3, WA, qkv_b, qn_w, kn_w, tab, Qbf, Kbf, Vbf);
    // 3. fat2: attn -> P3  ||  pack proj -> P4, gate -> WA, up -> WB
    fat2<<<640 + 1536 + 6144 + 6144, 256, 0, stream>>>(
        Qbf, Kbf, Vbf, P3, proj_w, P4, gate_w, WA, up_w, WB);
    // 4. proj split-K=4 -> bf16 partials (Tb); fused combine+rms2
    gemm128r<1, false, 4><<<dim3(Mrows / 128, 8, 4), 256, 0, stream>>>(
        P3, P4, nullptr, Tb, Cc, Cc);
    combine_rms<<<Mrows, 256, 0, stream>>>(x, proj_b, Tb, ln2_w, out, P3);
    // 5. fused: t = silu(y@gate) * (y@up) -> Tb
    gemm_gu<<<dim3(Mrows / 64, 32), 256, 0, stream>>>(P3, WA, WB, Tb);
    // 6. pack down_w -> WA; down split-K=4 -> bf16 partials (WB)
    pack_w<<<6144, 256, 0, stream>>>(down_w, WA, Ii, Cc);
    gemm128r<1, false, 4><<<dim3(Mrows / 128, 8, 4), 256, 0, stream>>>(
        Tb, WA, nullptr, WB, Ii, Cc);
    combine_down4<<<Mrows * Cc / 1024, 256, 0, stream>>>(WB, out);
}